// Round 3
// baseline (952.073 us; speedup 1.0000x reference)
//
#include <hip/hip_runtime.h>
#include <math.h>

#define DIM 2048
#define NROWS 4096            // B*S
#define WN (DIM*DIM)
#define HEADS 16
#define HDIM 128
#define SEQ 2048

typedef __attribute__((ext_vector_type(8))) short short8;
typedef __attribute__((ext_vector_type(8))) _Float16 half8;
typedef __attribute__((ext_vector_type(4))) float floatx4;
typedef __attribute__((ext_vector_type(4))) int intx4;

__device__ __forceinline__ float bf2f(unsigned short u) {
  return __uint_as_float(((unsigned)u) << 16);
}
__device__ __forceinline__ unsigned short f2bf(float f) {
  unsigned x = __float_as_uint(f);
  x += 0x7FFFu + ((x >> 16) & 1u);   // RTNE
  return (unsigned short)(x >> 16);
}
__device__ __forceinline__ unsigned short f2h(float f) {
  _Float16 h = (_Float16)f;
  return __builtin_bit_cast(unsigned short, h);
}
__device__ __forceinline__ float h2f(unsigned short u) {
  _Float16 h = __builtin_bit_cast(_Float16, u);
  return (float)h;
}

// async global->LDS, 16B per lane; lds base must be wave-uniform (HW scatters lane i at +i*16)
__device__ __forceinline__ void gload_lds16(const void* g, void* l) {
  __builtin_amdgcn_global_load_lds(
      (const __attribute__((address_space(1))) unsigned int*)g,
      (__attribute__((address_space(3))) unsigned int*)l, 16, 0, 0);
}

__device__ __forceinline__ float blockReduceSum(float v, float* red) {
  int tid = threadIdx.x;
  red[tid] = v; __syncthreads();
  for (int s = 128; s > 0; s >>= 1) {
    if (tid < s) red[tid] += red[tid + s];
    __syncthreads();
  }
  float r = red[0]; __syncthreads();
  return r;
}
__device__ __forceinline__ float blockReduceMax(float v, float* red) {
  int tid = threadIdx.x;
  red[tid] = v; __syncthreads();
  for (int s = 128; s > 0; s >>= 1) {
    if (tid < s) red[tid] = fmaxf(red[tid], red[tid + s]);
    __syncthreads();
  }
  float r = red[0]; __syncthreads();
  return r;
}

__device__ __forceinline__ const float* pick_w(const float* a, const float* b,
                                               const float* c, const float* d, int i) {
  return i == 0 ? a : i == 1 ? b : i == 2 ? c : d;
}

// ---------------- weight stats ----------------
__global__ __launch_bounds__(256) void w_abs_partial(
    const float* w0, const float* w1, const float* w2, const float* w3, float* part)
{
  const float4* w4 = (const float4*)pick_w(w0, w1, w2, w3, blockIdx.y);
  float s = 0.f;
  for (int i = blockIdx.x * 256 + threadIdx.x; i < WN / 4; i += 1024 * 256) {
    float4 v = w4[i];
    s += fabsf(v.x) + fabsf(v.y) + fabsf(v.z) + fabsf(v.w);
  }
  __shared__ float red[256];
  float t = blockReduceSum(s, red);
  if (threadIdx.x == 0) part[blockIdx.y * 1024 + blockIdx.x] = t;
}

__global__ __launch_bounds__(256) void w_delta_final(const float* part, float* stats)
{
  float s = 0.f;
  for (int i = threadIdx.x; i < 1024; i += 256) s += part[blockIdx.x * 1024 + i];
  __shared__ float red[256];
  float t = blockReduceSum(s, red);
  if (threadIdx.x == 0) stats[blockIdx.x] = 0.7f * (t / (float)WN);
}

__device__ __forceinline__ signed char tq(float v, float delta) {
  if (fabsf(v) > delta) return (v > 0.f) ? (signed char)1 : (signed char)-1;
  return (signed char)0;
}

// fused: ternary-quantize weights (int8 {-1,0,1}) AND accumulate alpha partials
__global__ __launch_bounds__(256) void w_maskquant(
    const float* w0, const float* w1, const float* w2, const float* w3,
    const float* stats, float* part2, signed char* tern)
{
  int wi = blockIdx.y;
  const float4* w4 = (const float4*)pick_w(w0, w1, w2, w3, wi);
  float delta = stats[wi];
  char4* out = (char4*)(tern + (size_t)wi * WN);
  float s = 0.f, cnt = 0.f;
  for (int i = blockIdx.x * 256 + threadIdx.x; i < WN / 4; i += 1024 * 256) {
    float4 v = w4[i];
    char4 o;
    float a;
    a = fabsf(v.x); if (a > delta) { s += a; cnt += 1.f; } o.x = tq(v.x, delta);
    a = fabsf(v.y); if (a > delta) { s += a; cnt += 1.f; } o.y = tq(v.y, delta);
    a = fabsf(v.z); if (a > delta) { s += a; cnt += 1.f; } o.z = tq(v.z, delta);
    a = fabsf(v.w); if (a > delta) { s += a; cnt += 1.f; } o.w = tq(v.w, delta);
    out[i] = o;
  }
  __shared__ float red[256];
  float ts = blockReduceSum(s, red);
  float tc = blockReduceSum(cnt, red);
  if (threadIdx.x == 0) {
    part2[((size_t)blockIdx.y * 1024 + blockIdx.x) * 2]     = ts;
    part2[((size_t)blockIdx.y * 1024 + blockIdx.x) * 2 + 1] = tc;
  }
}

__global__ __launch_bounds__(256) void w_alpha_final(const float* part2, float* stats)
{
  float s = 0.f, c = 0.f;
  for (int i = threadIdx.x; i < 1024; i += 256) {
    s += part2[((size_t)blockIdx.x * 1024 + i) * 2];
    c += part2[((size_t)blockIdx.x * 1024 + i) * 2 + 1];
  }
  __shared__ float red[256];
  float ts = blockReduceSum(s, red);
  float tc = blockReduceSum(c, red);
  if (threadIdx.x == 0) stats[4 + blockIdx.x] = ts / fmaxf(tc, 1.f);
}

// ---------------- fused LN for q/k/v ----------------
__global__ __launch_bounds__(256) void ln_absmax3(
    const float* __restrict__ x,
    const float* __restrict__ g0, const float* __restrict__ b0,
    const float* __restrict__ g1, const float* __restrict__ b1,
    const float* __restrict__ g2, const float* __restrict__ b2,
    unsigned* __restrict__ ambits)
{
  const int row = blockIdx.x, tid = threadIdx.x;
  const float* xr = x + (size_t)row * DIM;
  float4 a0 = *(const float4*)(xr + tid * 4);
  float4 a1 = *(const float4*)(xr + 1024 + tid * 4);
  float s  = a0.x + a0.y + a0.z + a0.w + a1.x + a1.y + a1.z + a1.w;
  float sq = a0.x*a0.x + a0.y*a0.y + a0.z*a0.z + a0.w*a0.w
           + a1.x*a1.x + a1.y*a1.y + a1.z*a1.z + a1.w*a1.w;
  __shared__ float red[256];
  float ts = blockReduceSum(s, red);
  float tqq = blockReduceSum(sq, red);
  float mu = ts * (1.f / DIM);
  float var = tqq * (1.f / DIM) - mu * mu;
  float rstd = 1.f / sqrtf(var + 1e-5f);
  float yn[8];
  yn[0] = (a0.x - mu) * rstd; yn[1] = (a0.y - mu) * rstd;
  yn[2] = (a0.z - mu) * rstd; yn[3] = (a0.w - mu) * rstd;
  yn[4] = (a1.x - mu) * rstd; yn[5] = (a1.y - mu) * rstd;
  yn[6] = (a1.z - mu) * rstd; yn[7] = (a1.w - mu) * rstd;
  const float* gs[3] = {g0, g1, g2};
  const float* bs[3] = {b0, b1, b2};
  #pragma unroll
  for (int p = 0; p < 3; ++p) {
    float4 gg0 = *(const float4*)(gs[p] + tid * 4);
    float4 gg1 = *(const float4*)(gs[p] + 1024 + tid * 4);
    float4 bb0 = *(const float4*)(bs[p] + tid * 4);
    float4 bb1 = *(const float4*)(bs[p] + 1024 + tid * 4);
    float m = fabsf(yn[0] * gg0.x + bb0.x);
    m = fmaxf(m, fabsf(yn[1] * gg0.y + bb0.y));
    m = fmaxf(m, fabsf(yn[2] * gg0.z + bb0.z));
    m = fmaxf(m, fabsf(yn[3] * gg0.w + bb0.w));
    m = fmaxf(m, fabsf(yn[4] * gg1.x + bb1.x));
    m = fmaxf(m, fabsf(yn[5] * gg1.y + bb1.y));
    m = fmaxf(m, fabsf(yn[6] * gg1.z + bb1.z));
    m = fmaxf(m, fabsf(yn[7] * gg1.w + bb1.w));
    float bm = blockReduceMax(m, red);
    if (tid == 0) atomicMax(ambits + p, __float_as_uint(bm));
  }
}

__global__ __launch_bounds__(256) void ln_quant3(
    const float* __restrict__ x,
    const float* __restrict__ g0, const float* __restrict__ b0,
    const float* __restrict__ g1, const float* __restrict__ b1,
    const float* __restrict__ g2, const float* __restrict__ b2,
    const unsigned* __restrict__ ambits,
    signed char* __restrict__ xq0, signed char* __restrict__ xq1,
    signed char* __restrict__ xq2)
{
  const int row = blockIdx.x, tid = threadIdx.x;
  const float* xr = x + (size_t)row * DIM;
  float4 a0 = *(const float4*)(xr + tid * 4);
  float4 a1 = *(const float4*)(xr + 1024 + tid * 4);
  float s  = a0.x + a0.y + a0.z + a0.w + a1.x + a1.y + a1.z + a1.w;
  float sq = a0.x*a0.x + a0.y*a0.y + a0.z*a0.z + a0.w*a0.w
           + a1.x*a1.x + a1.y*a1.y + a1.z*a1.z + a1.w*a1.w;
  __shared__ float red[256];
  float ts = blockReduceSum(s, red);
  float tqq = blockReduceSum(sq, red);
  float mu = ts * (1.f / DIM);
  float var = tqq * (1.f / DIM) - mu * mu;
  float rstd = 1.f / sqrtf(var + 1e-5f);
  float yn[8];
  yn[0] = (a0.x - mu) * rstd; yn[1] = (a0.y - mu) * rstd;
  yn[2] = (a0.z - mu) * rstd; yn[3] = (a0.w - mu) * rstd;
  yn[4] = (a1.x - mu) * rstd; yn[5] = (a1.y - mu) * rstd;
  yn[6] = (a1.z - mu) * rstd; yn[7] = (a1.w - mu) * rstd;
  const float* gs[3] = {g0, g1, g2};
  const float* bs[3] = {b0, b1, b2};
  signed char* outs[3] = {xq0, xq1, xq2};
  #pragma unroll
  for (int p = 0; p < 3; ++p) {
    float4 gg0 = *(const float4*)(gs[p] + tid * 4);
    float4 gg1 = *(const float4*)(gs[p] + 1024 + tid * 4);
    float4 bb0 = *(const float4*)(bs[p] + tid * 4);
    float4 bb1 = *(const float4*)(bs[p] + 1024 + tid * 4);
    float y[8];
    y[0] = yn[0] * gg0.x + bb0.x; y[1] = yn[1] * gg0.y + bb0.y;
    y[2] = yn[2] * gg0.z + bb0.z; y[3] = yn[3] * gg0.w + bb0.w;
    y[4] = yn[4] * gg1.x + bb1.x; y[5] = yn[5] * gg1.y + bb1.y;
    y[6] = yn[6] * gg1.z + bb1.z; y[7] = yn[7] * gg1.w + bb1.w;
    float sc = 127.f / fmaxf(__uint_as_float(ambits[p]), 1e-5f);
    signed char o[8];
    #pragma unroll
    for (int j = 0; j < 8; ++j) {
      float qv = rintf(y[j] * sc);
      qv = fminf(fmaxf(qv, -128.f), 127.f);
      o[j] = (signed char)(int)qv;
    }
    char4 q0; q0.x = o[0]; q0.y = o[1]; q0.z = o[2]; q0.w = o[3];
    char4 q1; q1.x = o[4]; q1.y = o[5]; q1.z = o[6]; q1.w = o[7];
    *(char4*)(outs[p] + (size_t)row * DIM + tid * 4) = q0;
    *(char4*)(outs[p] + (size_t)row * DIM + 1024 + tid * 4) = q1;
  }
}

// ---------------- single-tensor LN (for the o projection) ----------------
template<int MODE>
__global__ __launch_bounds__(256) void ln_kernel(
    const float* __restrict__ x, const float* __restrict__ g, const float* __restrict__ bias,
    unsigned* __restrict__ ambits, signed char* __restrict__ xq)
{
  const int row = blockIdx.x, tid = threadIdx.x;
  const float* xr = x + (size_t)row * DIM;
  float4 a0 = *(const float4*)(xr + tid * 4);
  float4 a1 = *(const float4*)(xr + 1024 + tid * 4);
  float s  = a0.x + a0.y + a0.z + a0.w + a1.x + a1.y + a1.z + a1.w;
  float sq = a0.x*a0.x + a0.y*a0.y + a0.z*a0.z + a0.w*a0.w
           + a1.x*a1.x + a1.y*a1.y + a1.z*a1.z + a1.w*a1.w;
  __shared__ float red[256];
  float ts = blockReduceSum(s, red);
  float tqq = blockReduceSum(sq, red);
  float mu = ts * (1.f / DIM);
  float var = tqq * (1.f / DIM) - mu * mu;
  float rstd = 1.f / sqrtf(var + 1e-5f);
  float4 g0 = *(const float4*)(g + tid * 4);
  float4 g1 = *(const float4*)(g + 1024 + tid * 4);
  float4 b0 = *(const float4*)(bias + tid * 4);
  float4 b1 = *(const float4*)(bias + 1024 + tid * 4);
  float y[8];
  y[0] = (a0.x - mu) * rstd * g0.x + b0.x;
  y[1] = (a0.y - mu) * rstd * g0.y + b0.y;
  y[2] = (a0.z - mu) * rstd * g0.z + b0.z;
  y[3] = (a0.w - mu) * rstd * g0.w + b0.w;
  y[4] = (a1.x - mu) * rstd * g1.x + b1.x;
  y[5] = (a1.y - mu) * rstd * g1.y + b1.y;
  y[6] = (a1.z - mu) * rstd * g1.z + b1.z;
  y[7] = (a1.w - mu) * rstd * g1.w + b1.w;
  if (MODE == 0) {
    float m = 0.f;
    #pragma unroll
    for (int j = 0; j < 8; ++j) m = fmaxf(m, fabsf(y[j]));
    float bm = blockReduceMax(m, red);
    if (tid == 0) atomicMax(ambits, __float_as_uint(bm));
  } else {
    float sc = 127.f / fmaxf(__uint_as_float(*ambits), 1e-5f);
    signed char o[8];
    #pragma unroll
    for (int j = 0; j < 8; ++j) {
      float qv = rintf(y[j] * sc);
      qv = fminf(fmaxf(qv, -128.f), 127.f);
      o[j] = (signed char)(int)qv;
    }
    char4 q0; q0.x = o[0]; q0.y = o[1]; q0.z = o[2]; q0.w = o[3];
    char4 q1; q1.x = o[4]; q1.y = o[5]; q1.z = o[6]; q1.w = o[7];
    *(char4*)(xq + (size_t)row * DIM + tid * 4) = q0;
    *(char4*)(xq + (size_t)row * DIM + 1024 + tid * 4) = q1;
  }
}

// ---------------- int8 quantized GEMM, m97 structure: global_load_lds staging ----------------
// A: int8 activations [-128,127]; Bt: ternary int8 {-1,0,1} (row = output column).
// mfma_i32_16x16x64_i8: 2x K per instr vs bf16, exact i32 accumulation.
// OMODE: 0 = fp32 out, 1 = fp16 out
template<int OMODE>
__global__ __launch_bounds__(256) void gemm_bt(
    const signed char* __restrict__ A, const signed char* __restrict__ Bt,
    void* __restrict__ Cp0, const float* __restrict__ stats, int wi)
{
  const int tid = threadIdx.x;
  const int lane = tid & 63;
  const int w = tid >> 6;
  const int wm = w >> 1, wn = w & 1;
  const int quad = lane >> 4, l16 = lane & 15;
  const int bm = blockIdx.x * 128, bn = blockIdx.y * 128;

  // unpadded, contiguous row-major [128][128] i8 — required by global_load_lds lane scatter
  __shared__ __align__(16) signed char As[128 * 128];
  __shared__ __align__(16) signed char Bs[128 * 128];

  // per-chunk geometry: chunk c (1 KiB) = rows c*8..c*8+8; lane i -> row c*8+(i>>3), col (i&7)*16
  const int srow_off = lane >> 3;        // 0..7
  const int scol     = (lane & 7) * 16;  // bytes

  intx4 acc[4][4];
  #pragma unroll
  for (int i = 0; i < 4; ++i)
    #pragma unroll
    for (int j = 0; j < 4; ++j) acc[i][j] = {0, 0, 0, 0};

  for (int k0 = 0; k0 < DIM; k0 += 128) {
    #pragma unroll
    for (int i = 0; i < 4; ++i) {
      int c = i * 4 + w;                 // wave-uniform chunk id, 16 chunks = 128 rows
      int row = c * 8 + srow_off;
      gload_lds16(A  + (size_t)(bm + row) * DIM + k0 + scol, &As[c * 1024]);
      gload_lds16(Bt + (size_t)(bn + row) * DIM + k0 + scol, &Bs[c * 1024]);
    }
    __syncthreads();
    #pragma unroll
    for (int kc = 0; kc < 2; ++kc) {
      intx4 af[4], bf[4];
      #pragma unroll
      for (int i = 0; i < 4; ++i)
        af[i] = *(const intx4*)&As[(wm * 64 + i * 16 + l16) * 128 + kc * 64 + quad * 16];
      #pragma unroll
      for (int j = 0; j < 4; ++j)
        bf[j] = *(const intx4*)&Bs[(wn * 64 + j * 16 + l16) * 128 + kc * 64 + quad * 16];
      #pragma unroll
      for (int i = 0; i < 4; ++i)
        #pragma unroll
        for (int j = 0; j < 4; ++j)
          acc[i][j] = __builtin_amdgcn_mfma_i32_16x16x64_i8(af[i], bf[j], acc[i][j], 0, 0, 0);
    }
    __syncthreads();
  }

  const unsigned* am = (const unsigned*)(stats + 8);
  float scale = stats[4 + wi] * fmaxf(__uint_as_float(am[wi]), 1e-5f) * (1.f / 127.f);
  #pragma unroll
  for (int i = 0; i < 4; ++i)
    #pragma unroll
    for (int j = 0; j < 4; ++j)
      #pragma unroll
      for (int r = 0; r < 4; ++r) {
        int m = bm + wm * 64 + i * 16 + quad * 4 + r;
        int n = bn + wn * 64 + j * 16 + l16;
        size_t idx = (size_t)m * DIM + n;
        float v = (float)acc[i][j][r] * scale;
        if (OMODE == 0) ((float*)Cp0)[idx] = v;
        else            ((unsigned short*)Cp0)[idx] = f2h(v);
      }
}

// ---------------- rope (fp16; angle = head_index * inv; q gets (1/sqrt(128))*log2e folded) ----------------
__global__ __launch_bounds__(256) void rope_kernel(unsigned short* q, unsigned short* k)
{
  const float SC = 0.12751741769011063f;   // (1/sqrt(128)) * log2(e)
  int idx = blockIdx.x * 256 + threadIdx.x;
  int p = idx & 63;
  int h = (idx >> 6) & (HEADS - 1);
  int r = idx >> 10;
  float inv = exp2f((float)p * -0.20762050593046f);  // 10000^(-p/64)
  float ang = (float)h * inv;
  float sn, cs;
  __sincosf(ang, &sn, &cs);
  size_t base = (size_t)r * DIM + h * HDIM + 2 * p;
  {
    float a = h2f(q[base]), b = h2f(q[base + 1]);
    q[base]     = f2h((a * cs - b * sn) * SC);
    q[base + 1] = f2h((a * sn + b * cs) * SC);
  }
  {
    float a = h2f(k[base]), b = h2f(k[base + 1]);
    k[base]     = f2h(a * cs - b * sn);
    k[base + 1] = f2h(a * sn + b * cs);
  }
}

// ---------------- transpose V: [b*S+s][h*128+d] -> [(b*16+h)*128+d][s] ----------------
__global__ __launch_bounds__(256) void transpose_v(
    const unsigned short* __restrict__ vin, unsigned short* __restrict__ vout)
{
  __shared__ __align__(16) unsigned short t[64][72];
  const int tid = threadIdx.x;
  const int c0 = blockIdx.x * 64, r0 = blockIdx.y * 64;
  #pragma unroll
  for (int c = 0; c < 2; ++c) {
    int idx = c * 256 + tid;
    int row = idx >> 3, cb = (idx & 7) << 3;
    *(uint4*)&t[row][cb] = *(const uint4*)(vin + (size_t)(r0 + row) * DIM + c0 + cb);
  }
  __syncthreads();
  const int b = r0 >> 11, s0 = r0 & (SEQ - 1);
  const int h = c0 >> 7, d0 = c0 & (HDIM - 1);
  #pragma unroll
  for (int c = 0; c < 2; ++c) {
    int idx = c * 256 + tid;
    int drow = idx >> 3, sb = (idx & 7) << 3;
    union { unsigned short u[8]; uint4 v; } pk;
    #pragma unroll
    for (int j = 0; j < 8; ++j) pk.u[j] = t[sb + j][drow];
    *(uint4*)(vout + (size_t)((b * HEADS + h) * HDIM + d0 + drow) * SEQ + s0 + sb) = pk.v;
  }
}

// ---------------- flash attention: QBLK=64, 4 blocks/CU, XOR-swizzled LDS ----------------
// Q pre-scaled by (1/sqrt(128))*log2(e); softmax in exp2 domain; T13 defer-rescale.
// Grid (SEQ/64, B*H) = 1024 blocks; LDS 40960 B = exactly 160KiB/4 -> 4 blocks/CU.
// All LDS tiles unpadded, swizzled with byte ^= ((row&7)<<4) on BOTH write and read
// (reg-staged both sides, so the involution is consistent; kills row-stride conflicts).
__global__ __launch_bounds__(256, 4) void flash_attn(
    const unsigned short* __restrict__ qf, const unsigned short* __restrict__ kf,
    const unsigned short* __restrict__ vt, float* __restrict__ o)
{
  const int tid = threadIdx.x;
  const int lane = tid & 63;
  const int w = tid >> 6;
  const int quad = lane >> 4;
  const int l16 = lane & 15;
  const int qt = blockIdx.x;
  const int bh = blockIdx.y;
  const int b = bh >> 4;
  const int h = bh & 15;

  __shared__ __align__(16) char Ks[64 * 256];     // [key t][d] halves, swizzled (16384 B)
  __shared__ __align__(16) char Vs[128 * 128];    // [d][t] halves, swizzled (16384 B)
  __shared__ __align__(16) char Ps[4][16 * 128];  // per-wave [q][t] halves, swizzled (8192 B)

  // Q fragment (B-operand): wave owns 16 q-rows
  const size_t qbase = ((size_t)(b * SEQ + qt * 64 + w * 16 + l16)) * DIM + h * HDIM;
  short8 qa[4];
  #pragma unroll
  for (int kc = 0; kc < 4; ++kc)
    qa[kc] = *(const short8*)(qf + qbase + kc * 32 + quad * 8);

  float m_q = -INFINITY;
  float l_q = 0.f;
  floatx4 accO[8];                      // O^T: rows d=dt*16+quad*4+r, col q = l16
  #pragma unroll
  for (int i = 0; i < 8; ++i) accO[i] = {0.f, 0.f, 0.f, 0.f};

  const unsigned short* kg = kf + (size_t)(b * SEQ) * DIM + h * HDIM;
  const unsigned short* vg = vt + (size_t)bh * HDIM * SEQ;

  // register prefetch buffers (one K/V tile per block iteration)
  uint4 kreg[4], vreg[4];
  #pragma unroll
  for (int i = 0; i < 4; ++i) {
    int idx = i * 256 + tid;
    kreg[i] = *(const uint4*)(kg + (size_t)(idx >> 4) * DIM + (idx & 15) * 8);
    vreg[i] = *(const uint4*)(vg + (size_t)(idx >> 3) * SEQ + (idx & 7) * 8);
  }

  for (int kt = 0; kt < SEQ / 64; ++kt) {
    __syncthreads();                    // prior tile's LDS reads complete
    #pragma unroll
    for (int i = 0; i < 4; ++i) {
      int idx = i * 256 + tid;
      int kr = idx >> 4;
      *(uint4*)&Ks[(kr * 256 + (idx & 15) * 16) ^ ((kr & 7) << 4)] = kreg[i];
      int vr = idx >> 3;
      *(uint4*)&Vs[(vr * 128 + (idx & 7) * 16) ^ ((vr & 7) << 4)] = vreg[i];
    }
    __syncthreads();
    if (kt + 1 < SEQ / 64) {            // issue next tile's loads; latency hidden by compute
      #pragma unroll
      for (int i = 0; i < 4; ++i) {
        int idx = i * 256 + tid;
        kreg[i] = *(const uint4*)(kg + (size_t)((kt + 1) * 64 + (idx >> 4)) * DIM + (idx & 15) * 8);
        vreg[i] = *(const uint4*)(vg + (size_t)(idx >> 3) * SEQ + (kt + 1) * 64 + (idx & 7) * 8);
      }
    }

    // S^T = K Q'^T : lane q = l16, keys t = jt*16 + quad*4 + r
    float sreg[4][4];
    #pragma unroll
    for (int jt = 0; jt < 4; ++jt) {
      floatx4 a0 = {0.f, 0.f, 0.f, 0.f};
      #pragma unroll
      for (int kc = 0; kc < 4; ++kc) {
        int kr = jt * 16 + l16;
        short8 kb = *(const short8*)&Ks[(kr * 256 + kc * 64 + quad * 16) ^ ((kr & 7) << 4)];
        a0 = __builtin_amdgcn_mfma_f32_16x16x32_f16(
            __builtin_bit_cast(half8, kb), __builtin_bit_cast(half8, qa[kc]), a0, 0, 0, 0);
      }
      #pragma unroll
      for (int r = 0; r < 4; ++r) sreg[jt][r] = a0[r];
    }

    // per-lane online softmax (exp2 domain); T13 defer-rescale
    float mx = sreg[0][0];
    #pragma unroll
    for (int jt = 0; jt < 4; ++jt)
      #pragma unroll
      for (int r = 0; r < 4; ++r) mx = fmaxf(mx, sreg[jt][r]);
    mx = fmaxf(mx, __shfl_xor(mx, 16));
    mx = fmaxf(mx, __shfl_xor(mx, 32));
    int need = !__all(mx <= m_q + 8.f);   // wave-uniform
    float mnew, alpha;
    if (need) {
      mnew = fmaxf(m_q, mx);
      alpha = exp2f(m_q - mnew);
      m_q = mnew;
    } else {
      mnew = m_q;
      alpha = 1.f;
    }
    float ssum = 0.f;
    #pragma unroll
    for (int jt = 0; jt < 4; ++jt) {
      ushort4 pk;
      float p0 = exp2f(sreg[jt][0] - mnew);
      float p1 = exp2f(sreg[jt][1] - mnew);
      float p2 = exp2f(sreg[jt][2] - mnew);
      float p3 = exp2f(sreg[jt][3] - mnew);
      pk.x = f2h(p0); pk.y = f2h(p1); pk.z = f2h(p2); pk.w = f2h(p3);
      ssum += (p0 + p1) + (p2 + p3);
      *(ushort4*)&Ps[w][(l16 * 128 + jt * 32 + quad * 8) ^ ((l16 & 7) << 4)] = pk;
    }
    ssum += __shfl_xor(ssum, 16);
    ssum += __shfl_xor(ssum, 32);
    l_q = l_q * alpha + ssum;
    if (need) {
      #pragma unroll
      for (int dt = 0; dt < 8; ++dt)
        #pragma unroll
        for (int r = 0; r < 4; ++r) accO[dt][r] *= alpha;
    }

    // O^T = O^T + V^T P^T
    #pragma unroll
    for (int kc = 0; kc < 2; ++kc) {
      short8 pf = *(const short8*)&Ps[w][(l16 * 128 + kc * 64 + quad * 16) ^ ((l16 & 7) << 4)];
      #pragma unroll
      for (int dt = 0; dt < 8; ++dt) {
        int vr = dt * 16 + l16;
        short8 vf = *(const short8*)&Vs[(vr * 128 + kc * 64 + quad * 16) ^ ((vr & 7) << 4)];
        accO[dt] = __builtin_amdgcn_mfma_f32_16x16x32_f16(
            __builtin_bit_cast(half8, vf), __builtin_bit_cast(half8, pf), accO[dt], 0, 0, 0);
      }
    }
  }

  // epilogue: float4 stores, 16B per lane
  float invl = 1.0f / l_q;
  const size_t obase = (size_t)(b * SEQ + qt * 64 + w * 16 + l16) * DIM + h * HDIM;
  #pragma unroll
  for (int dt = 0; dt < 8; ++dt) {
    float4 ov;
    ov.x = accO[dt][0] * invl; ov.y = accO[dt][1] * invl;
    ov.z = accO[dt][2] * invl; ov.w = accO[dt][3] * invl;
    *(float4*)(o + obase + dt * 16 + quad * 4) = ov;
  }
}

// ---------------- host ----------------
extern "C" void kernel_launch(void* const* d_in, const int* in_sizes, int n_in,
                              void* d_out, int out_size, void* d_ws, size_t ws_size,
                              hipStream_t stream)
{
  (void)in_sizes; (void)n_in; (void)out_size; (void)ws_size;
  const float* x = (const float*)d_in[0];
  const float* w[4]; const float* g[4]; const float* bb[4];
  for (int i = 0; i < 4; ++i) {
    w[i]  = (const float*)d_in[1 + 3 * i];
    g[i]  = (const float*)d_in[2 + 3 * i];
    bb[i] = (const float*)d_in[3 + 3 * i];
  }

  char* base = (char*)d_ws;
  size_t off = 0;
  auto alloc = [&](size_t bytes) {
    char* p = base + off;
    off += (bytes + 255) & ~(size_t)255;
    return p;
  };
  const size_t ACTH = (size_t)NROWS * DIM * 2;  // 16-bit activation buffer (16 MB)
  const size_t ACT8 = (size_t)NROWS * DIM;      // 8-bit activation buffer (8 MB)
  float* stats          = (float*)alloc(64);
  float* part1          = (float*)alloc(4 * 1024 * sizeof(float));
  float* part2          = (float*)alloc(4 * 1024 * 2 * sizeof(float));
  signed char* tern     = (signed char*)alloc((size_t)4 * WN);
  signed char* xq0      = (signed char*)alloc(ACT8);
  signed char* xq1      = (signed char*)alloc(ACT8);
  signed char* xq2      = (signed char*)alloc(ACT8);
  unsigned short* qh    = (unsigned short*)alloc(ACTH);
  unsigned short* kh    = (unsigned short*)alloc(ACTH);
  unsigned short* vb    = (unsigned short*)alloc(ACTH);
  unsigned short* vtb   = (unsigned short*)alloc(ACTH);
  float* oat            = (float*)alloc((size_t)NROWS * DIM * sizeof(float));
  signed char* xqo = xq0;              // overlay: xq0 dead after the q GEMM
  unsigned* ambits = (unsigned*)(stats + 8);

  hipMemsetAsync(stats, 0, 64, stream);

  dim3 b256(256);
  w_abs_partial<<<dim3(1024, 4), b256, 0, stream>>>(w[0], w[1], w[2], w[3], part1);
  w_delta_final<<<4, b256, 0, stream>>>(part1, stats);
  w_maskquant<<<dim3(1024, 4), b256, 0, stream>>>(w[0], w[1], w[2], w[3], stats, part2, tern);
  w_alpha_final<<<4, b256, 0, stream>>>(part2, stats);

  ln_absmax3<<<NROWS, b256, 0, stream>>>(x, g[0], bb[0], g[1], bb[1], g[2], bb[2], ambits);
  ln_quant3<<<NROWS, b256, 0, stream>>>(x, g[0], bb[0], g[1], bb[1], g[2], bb[2], ambits,
                                        xq0, xq1, xq2);

  dim3 ggrid(NROWS / 128, DIM / 128);
  gemm_bt<1><<<ggrid, b256, 0, stream>>>(xq0, tern + (size_t)0 * WN, qh, stats, 0);
  gemm_bt<1><<<ggrid, b256, 0, stream>>>(xq1, tern + (size_t)1 * WN, kh, stats, 1);
  gemm_bt<1><<<ggrid, b256, 0, stream>>>(xq2, tern + (size_t)2 * WN, vb, stats, 2);

  rope_kernel<<<NROWS * 1024 / 256, b256, 0, stream>>>(qh, kh);
  transpose_v<<<dim3(DIM / 64, NROWS / 64), b256, 0, stream>>>(vb, vtb);
  flash_attn<<<dim3(SEQ / 64, 32), b256, 0, stream>>>(qh, kh, vtb, oat);

  ln_kernel<0><<<NROWS, b256, 0, stream>>>(oat, g[3], bb[3], ambits + 3, nullptr);
  ln_kernel<1><<<NROWS, b256, 0, stream>>>(oat, g[3], bb[3], ambits + 3, xqo);
  gemm_bt<0><<<ggrid, b256, 0, stream>>>(xqo, tern + (size_t)3 * WN, (float*)d_out, stats, 3);
}

// Round 4
// 931.461 us; speedup vs baseline: 1.0221x; 1.0221x over previous
//
#include <hip/hip_runtime.h>
#include <math.h>

#define DIM 2048
#define NROWS 4096            // B*S
#define WN (DIM*DIM)
#define HEADS 16
#define HDIM 128
#define SEQ 2048

typedef __attribute__((ext_vector_type(8))) short short8;
typedef __attribute__((ext_vector_type(8))) _Float16 half8;
typedef __attribute__((ext_vector_type(4))) float floatx4;
typedef __attribute__((ext_vector_type(4))) int intx4;

__device__ __forceinline__ float bf2f(unsigned short u) {
  return __uint_as_float(((unsigned)u) << 16);
}
__device__ __forceinline__ unsigned short f2bf(float f) {
  unsigned x = __float_as_uint(f);
  x += 0x7FFFu + ((x >> 16) & 1u);   // RTNE
  return (unsigned short)(x >> 16);
}
__device__ __forceinline__ unsigned short f2h(float f) {
  _Float16 h = (_Float16)f;
  return __builtin_bit_cast(unsigned short, h);
}
__device__ __forceinline__ float h2f(unsigned short u) {
  _Float16 h = __builtin_bit_cast(_Float16, u);
  return (float)h;
}

// async global->LDS, 16B per lane; lds base must be wave-uniform (HW scatters lane i at +i*16)
__device__ __forceinline__ void gload_lds16(const void* g, void* l) {
  __builtin_amdgcn_global_load_lds(
      (const __attribute__((address_space(1))) unsigned int*)g,
      (__attribute__((address_space(3))) unsigned int*)l, 16, 0, 0);
}

__device__ __forceinline__ float blockReduceSum(float v, float* red) {
  int tid = threadIdx.x;
  red[tid] = v; __syncthreads();
  for (int s = 128; s > 0; s >>= 1) {
    if (tid < s) red[tid] += red[tid + s];
    __syncthreads();
  }
  float r = red[0]; __syncthreads();
  return r;
}
__device__ __forceinline__ float blockReduceMax(float v, float* red) {
  int tid = threadIdx.x;
  red[tid] = v; __syncthreads();
  for (int s = 128; s > 0; s >>= 1) {
    if (tid < s) red[tid] = fmaxf(red[tid], red[tid + s]);
    __syncthreads();
  }
  float r = red[0]; __syncthreads();
  return r;
}

__device__ __forceinline__ const float* pick_w(const float* a, const float* b,
                                               const float* c, const float* d, int i) {
  return i == 0 ? a : i == 1 ? b : i == 2 ? c : d;
}

// ---------------- weight stats ----------------
__global__ __launch_bounds__(256) void w_abs_partial(
    const float* w0, const float* w1, const float* w2, const float* w3, float* part)
{
  const float4* w4 = (const float4*)pick_w(w0, w1, w2, w3, blockIdx.y);
  float s = 0.f;
  for (int i = blockIdx.x * 256 + threadIdx.x; i < WN / 4; i += 1024 * 256) {
    float4 v = w4[i];
    s += fabsf(v.x) + fabsf(v.y) + fabsf(v.z) + fabsf(v.w);
  }
  __shared__ float red[256];
  float t = blockReduceSum(s, red);
  if (threadIdx.x == 0) part[blockIdx.y * 1024 + blockIdx.x] = t;
}

__global__ __launch_bounds__(256) void w_delta_final(const float* part, float* stats)
{
  float s = 0.f;
  for (int i = threadIdx.x; i < 1024; i += 256) s += part[blockIdx.x * 1024 + i];
  __shared__ float red[256];
  float t = blockReduceSum(s, red);
  if (threadIdx.x == 0) stats[blockIdx.x] = 0.7f * (t / (float)WN);
}

__device__ __forceinline__ signed char tq(float v, float delta) {
  if (fabsf(v) > delta) return (v > 0.f) ? (signed char)1 : (signed char)-1;
  return (signed char)0;
}

// fused: ternary-quantize weights (int8 {-1,0,1}) AND accumulate alpha partials
__global__ __launch_bounds__(256) void w_maskquant(
    const float* w0, const float* w1, const float* w2, const float* w3,
    const float* stats, float* part2, signed char* tern)
{
  int wi = blockIdx.y;
  const float4* w4 = (const float4*)pick_w(w0, w1, w2, w3, wi);
  float delta = stats[wi];
  char4* out = (char4*)(tern + (size_t)wi * WN);
  float s = 0.f, cnt = 0.f;
  for (int i = blockIdx.x * 256 + threadIdx.x; i < WN / 4; i += 1024 * 256) {
    float4 v = w4[i];
    char4 o;
    float a;
    a = fabsf(v.x); if (a > delta) { s += a; cnt += 1.f; } o.x = tq(v.x, delta);
    a = fabsf(v.y); if (a > delta) { s += a; cnt += 1.f; } o.y = tq(v.y, delta);
    a = fabsf(v.z); if (a > delta) { s += a; cnt += 1.f; } o.z = tq(v.z, delta);
    a = fabsf(v.w); if (a > delta) { s += a; cnt += 1.f; } o.w = tq(v.w, delta);
    out[i] = o;
  }
  __shared__ float red[256];
  float ts = blockReduceSum(s, red);
  float tc = blockReduceSum(cnt, red);
  if (threadIdx.x == 0) {
    part2[((size_t)blockIdx.y * 1024 + blockIdx.x) * 2]     = ts;
    part2[((size_t)blockIdx.y * 1024 + blockIdx.x) * 2 + 1] = tc;
  }
}

__global__ __launch_bounds__(256) void w_alpha_final(const float* part2, float* stats)
{
  float s = 0.f, c = 0.f;
  for (int i = threadIdx.x; i < 1024; i += 256) {
    s += part2[((size_t)blockIdx.x * 1024 + i) * 2];
    c += part2[((size_t)blockIdx.x * 1024 + i) * 2 + 1];
  }
  __shared__ float red[256];
  float ts = blockReduceSum(s, red);
  float tc = blockReduceSum(c, red);
  if (threadIdx.x == 0) stats[4 + blockIdx.x] = ts / fmaxf(tc, 1.f);
}

// ---------------- fused LN for q/k/v ----------------
__global__ __launch_bounds__(256) void ln_absmax3(
    const float* __restrict__ x,
    const float* __restrict__ g0, const float* __restrict__ b0,
    const float* __restrict__ g1, const float* __restrict__ b1,
    const float* __restrict__ g2, const float* __restrict__ b2,
    unsigned* __restrict__ ambits)
{
  const int row = blockIdx.x, tid = threadIdx.x;
  const float* xr = x + (size_t)row * DIM;
  float4 a0 = *(const float4*)(xr + tid * 4);
  float4 a1 = *(const float4*)(xr + 1024 + tid * 4);
  float s  = a0.x + a0.y + a0.z + a0.w + a1.x + a1.y + a1.z + a1.w;
  float sq = a0.x*a0.x + a0.y*a0.y + a0.z*a0.z + a0.w*a0.w
           + a1.x*a1.x + a1.y*a1.y + a1.z*a1.z + a1.w*a1.w;
  __shared__ float red[256];
  float ts = blockReduceSum(s, red);
  float tqq = blockReduceSum(sq, red);
  float mu = ts * (1.f / DIM);
  float var = tqq * (1.f / DIM) - mu * mu;
  float rstd = 1.f / sqrtf(var + 1e-5f);
  float yn[8];
  yn[0] = (a0.x - mu) * rstd; yn[1] = (a0.y - mu) * rstd;
  yn[2] = (a0.z - mu) * rstd; yn[3] = (a0.w - mu) * rstd;
  yn[4] = (a1.x - mu) * rstd; yn[5] = (a1.y - mu) * rstd;
  yn[6] = (a1.z - mu) * rstd; yn[7] = (a1.w - mu) * rstd;
  const float* gs[3] = {g0, g1, g2};
  const float* bs[3] = {b0, b1, b2};
  #pragma unroll
  for (int p = 0; p < 3; ++p) {
    float4 gg0 = *(const float4*)(gs[p] + tid * 4);
    float4 gg1 = *(const float4*)(gs[p] + 1024 + tid * 4);
    float4 bb0 = *(const float4*)(bs[p] + tid * 4);
    float4 bb1 = *(const float4*)(bs[p] + 1024 + tid * 4);
    float m = fabsf(yn[0] * gg0.x + bb0.x);
    m = fmaxf(m, fabsf(yn[1] * gg0.y + bb0.y));
    m = fmaxf(m, fabsf(yn[2] * gg0.z + bb0.z));
    m = fmaxf(m, fabsf(yn[3] * gg0.w + bb0.w));
    m = fmaxf(m, fabsf(yn[4] * gg1.x + bb1.x));
    m = fmaxf(m, fabsf(yn[5] * gg1.y + bb1.y));
    m = fmaxf(m, fabsf(yn[6] * gg1.z + bb1.z));
    m = fmaxf(m, fabsf(yn[7] * gg1.w + bb1.w));
    float bm = blockReduceMax(m, red);
    if (tid == 0) atomicMax(ambits + p, __float_as_uint(bm));
  }
}

__global__ __launch_bounds__(256) void ln_quant3(
    const float* __restrict__ x,
    const float* __restrict__ g0, const float* __restrict__ b0,
    const float* __restrict__ g1, const float* __restrict__ b1,
    const float* __restrict__ g2, const float* __restrict__ b2,
    const unsigned* __restrict__ ambits,
    signed char* __restrict__ xq0, signed char* __restrict__ xq1,
    signed char* __restrict__ xq2)
{
  const int row = blockIdx.x, tid = threadIdx.x;
  const float* xr = x + (size_t)row * DIM;
  float4 a0 = *(const float4*)(xr + tid * 4);
  float4 a1 = *(const float4*)(xr + 1024 + tid * 4);
  float s  = a0.x + a0.y + a0.z + a0.w + a1.x + a1.y + a1.z + a1.w;
  float sq = a0.x*a0.x + a0.y*a0.y + a0.z*a0.z + a0.w*a0.w
           + a1.x*a1.x + a1.y*a1.y + a1.z*a1.z + a1.w*a1.w;
  __shared__ float red[256];
  float ts = blockReduceSum(s, red);
  float tqq = blockReduceSum(sq, red);
  float mu = ts * (1.f / DIM);
  float var = tqq * (1.f / DIM) - mu * mu;
  float rstd = 1.f / sqrtf(var + 1e-5f);
  float yn[8];
  yn[0] = (a0.x - mu) * rstd; yn[1] = (a0.y - mu) * rstd;
  yn[2] = (a0.z - mu) * rstd; yn[3] = (a0.w - mu) * rstd;
  yn[4] = (a1.x - mu) * rstd; yn[5] = (a1.y - mu) * rstd;
  yn[6] = (a1.z - mu) * rstd; yn[7] = (a1.w - mu) * rstd;
  const float* gs[3] = {g0, g1, g2};
  const float* bs[3] = {b0, b1, b2};
  signed char* outs[3] = {xq0, xq1, xq2};
  #pragma unroll
  for (int p = 0; p < 3; ++p) {
    float4 gg0 = *(const float4*)(gs[p] + tid * 4);
    float4 gg1 = *(const float4*)(gs[p] + 1024 + tid * 4);
    float4 bb0 = *(const float4*)(bs[p] + tid * 4);
    float4 bb1 = *(const float4*)(bs[p] + 1024 + tid * 4);
    float y[8];
    y[0] = yn[0] * gg0.x + bb0.x; y[1] = yn[1] * gg0.y + bb0.y;
    y[2] = yn[2] * gg0.z + bb0.z; y[3] = yn[3] * gg0.w + bb0.w;
    y[4] = yn[4] * gg1.x + bb1.x; y[5] = yn[5] * gg1.y + bb1.y;
    y[6] = yn[6] * gg1.z + bb1.z; y[7] = yn[7] * gg1.w + bb1.w;
    float sc = 127.f / fmaxf(__uint_as_float(ambits[p]), 1e-5f);
    signed char o[8];
    #pragma unroll
    for (int j = 0; j < 8; ++j) {
      float qv = rintf(y[j] * sc);
      qv = fminf(fmaxf(qv, -128.f), 127.f);
      o[j] = (signed char)(int)qv;
    }
    char4 q0; q0.x = o[0]; q0.y = o[1]; q0.z = o[2]; q0.w = o[3];
    char4 q1; q1.x = o[4]; q1.y = o[5]; q1.z = o[6]; q1.w = o[7];
    *(char4*)(outs[p] + (size_t)row * DIM + tid * 4) = q0;
    *(char4*)(outs[p] + (size_t)row * DIM + 1024 + tid * 4) = q1;
  }
}

// ---------------- single-tensor LN (for the o projection) ----------------
template<int MODE>
__global__ __launch_bounds__(256) void ln_kernel(
    const float* __restrict__ x, const float* __restrict__ g, const float* __restrict__ bias,
    unsigned* __restrict__ ambits, signed char* __restrict__ xq)
{
  const int row = blockIdx.x, tid = threadIdx.x;
  const float* xr = x + (size_t)row * DIM;
  float4 a0 = *(const float4*)(xr + tid * 4);
  float4 a1 = *(const float4*)(xr + 1024 + tid * 4);
  float s  = a0.x + a0.y + a0.z + a0.w + a1.x + a1.y + a1.z + a1.w;
  float sq = a0.x*a0.x + a0.y*a0.y + a0.z*a0.z + a0.w*a0.w
           + a1.x*a1.x + a1.y*a1.y + a1.z*a1.z + a1.w*a1.w;
  __shared__ float red[256];
  float ts = blockReduceSum(s, red);
  float tqq = blockReduceSum(sq, red);
  float mu = ts * (1.f / DIM);
  float var = tqq * (1.f / DIM) - mu * mu;
  float rstd = 1.f / sqrtf(var + 1e-5f);
  float4 g0 = *(const float4*)(g + tid * 4);
  float4 g1 = *(const float4*)(g + 1024 + tid * 4);
  float4 b0 = *(const float4*)(bias + tid * 4);
  float4 b1 = *(const float4*)(bias + 1024 + tid * 4);
  float y[8];
  y[0] = (a0.x - mu) * rstd * g0.x + b0.x;
  y[1] = (a0.y - mu) * rstd * g0.y + b0.y;
  y[2] = (a0.z - mu) * rstd * g0.z + b0.z;
  y[3] = (a0.w - mu) * rstd * g0.w + b0.w;
  y[4] = (a1.x - mu) * rstd * g1.x + b1.x;
  y[5] = (a1.y - mu) * rstd * g1.y + b1.y;
  y[6] = (a1.z - mu) * rstd * g1.z + b1.z;
  y[7] = (a1.w - mu) * rstd * g1.w + b1.w;
  if (MODE == 0) {
    float m = 0.f;
    #pragma unroll
    for (int j = 0; j < 8; ++j) m = fmaxf(m, fabsf(y[j]));
    float bm = blockReduceMax(m, red);
    if (tid == 0) atomicMax(ambits, __float_as_uint(bm));
  } else {
    float sc = 127.f / fmaxf(__uint_as_float(*ambits), 1e-5f);
    signed char o[8];
    #pragma unroll
    for (int j = 0; j < 8; ++j) {
      float qv = rintf(y[j] * sc);
      qv = fminf(fmaxf(qv, -128.f), 127.f);
      o[j] = (signed char)(int)qv;
    }
    char4 q0; q0.x = o[0]; q0.y = o[1]; q0.z = o[2]; q0.w = o[3];
    char4 q1; q1.x = o[4]; q1.y = o[5]; q1.z = o[6]; q1.w = o[7];
    *(char4*)(xq + (size_t)row * DIM + tid * 4) = q0;
    *(char4*)(xq + (size_t)row * DIM + 1024 + tid * 4) = q1;
  }
}

// ---------------- int8 quantized GEMM, m97 structure: global_load_lds staging ----------------
// A: int8 activations [-128,127]; Bt: ternary int8 {-1,0,1} (row = output column).
// mfma_i32_16x16x64_i8: 2x K per instr vs bf16, exact i32 accumulation.
// OMODE: 0 = fp32 out, 1 = fp16 out
template<int OMODE>
__global__ __launch_bounds__(256) void gemm_bt(
    const signed char* __restrict__ A, const signed char* __restrict__ Bt,
    void* __restrict__ Cp0, const float* __restrict__ stats, int wi)
{
  const int tid = threadIdx.x;
  const int lane = tid & 63;
  const int w = tid >> 6;
  const int wm = w >> 1, wn = w & 1;
  const int quad = lane >> 4, l16 = lane & 15;
  const int bm = blockIdx.x * 128, bn = blockIdx.y * 128;

  // unpadded, contiguous row-major [128][128] i8 — required by global_load_lds lane scatter
  __shared__ __align__(16) signed char As[128 * 128];
  __shared__ __align__(16) signed char Bs[128 * 128];

  // per-chunk geometry: chunk c (1 KiB) = rows c*8..c*8+8; lane i -> row c*8+(i>>3), col (i&7)*16
  const int srow_off = lane >> 3;        // 0..7
  const int scol     = (lane & 7) * 16;  // bytes

  intx4 acc[4][4];
  #pragma unroll
  for (int i = 0; i < 4; ++i)
    #pragma unroll
    for (int j = 0; j < 4; ++j) acc[i][j] = {0, 0, 0, 0};

  for (int k0 = 0; k0 < DIM; k0 += 128) {
    #pragma unroll
    for (int i = 0; i < 4; ++i) {
      int c = i * 4 + w;                 // wave-uniform chunk id, 16 chunks = 128 rows
      int row = c * 8 + srow_off;
      gload_lds16(A  + (size_t)(bm + row) * DIM + k0 + scol, &As[c * 1024]);
      gload_lds16(Bt + (size_t)(bn + row) * DIM + k0 + scol, &Bs[c * 1024]);
    }
    __syncthreads();
    #pragma unroll
    for (int kc = 0; kc < 2; ++kc) {
      intx4 af[4], bf[4];
      #pragma unroll
      for (int i = 0; i < 4; ++i)
        af[i] = *(const intx4*)&As[(wm * 64 + i * 16 + l16) * 128 + kc * 64 + quad * 16];
      #pragma unroll
      for (int j = 0; j < 4; ++j)
        bf[j] = *(const intx4*)&Bs[(wn * 64 + j * 16 + l16) * 128 + kc * 64 + quad * 16];
      #pragma unroll
      for (int i = 0; i < 4; ++i)
        #pragma unroll
        for (int j = 0; j < 4; ++j)
          acc[i][j] = __builtin_amdgcn_mfma_i32_16x16x64_i8(af[i], bf[j], acc[i][j], 0, 0, 0);
    }
    __syncthreads();
  }

  const unsigned* am = (const unsigned*)(stats + 8);
  float scale = stats[4 + wi] * fmaxf(__uint_as_float(am[wi]), 1e-5f) * (1.f / 127.f);
  #pragma unroll
  for (int i = 0; i < 4; ++i)
    #pragma unroll
    for (int j = 0; j < 4; ++j)
      #pragma unroll
      for (int r = 0; r < 4; ++r) {
        int m = bm + wm * 64 + i * 16 + quad * 4 + r;
        int n = bn + wn * 64 + j * 16 + l16;
        size_t idx = (size_t)m * DIM + n;
        float v = (float)acc[i][j][r] * scale;
        if (OMODE == 0) ((float*)Cp0)[idx] = v;
        else            ((unsigned short*)Cp0)[idx] = f2h(v);
      }
}

// ---------------- rope (fp16; angle = head_index * inv; q gets (1/sqrt(128))*log2e folded) ----------------
__global__ __launch_bounds__(256) void rope_kernel(unsigned short* q, unsigned short* k)
{
  const float SC = 0.12751741769011063f;   // (1/sqrt(128)) * log2(e)
  int idx = blockIdx.x * 256 + threadIdx.x;
  int p = idx & 63;
  int h = (idx >> 6) & (HEADS - 1);
  int r = idx >> 10;
  float inv = exp2f((float)p * -0.20762050593046f);  // 10000^(-p/64)
  float ang = (float)h * inv;
  float sn, cs;
  __sincosf(ang, &sn, &cs);
  size_t base = (size_t)r * DIM + h * HDIM + 2 * p;
  {
    float a = h2f(q[base]), b = h2f(q[base + 1]);
    q[base]     = f2h((a * cs - b * sn) * SC);
    q[base + 1] = f2h((a * sn + b * cs) * SC);
  }
  {
    float a = h2f(k[base]), b = h2f(k[base + 1]);
    k[base]     = f2h(a * cs - b * sn);
    k[base + 1] = f2h(a * sn + b * cs);
  }
}

// ---------------- transpose V: [b*S+s][h*128+d] -> [(b*16+h)*128+d][s] ----------------
__global__ __launch_bounds__(256) void transpose_v(
    const unsigned short* __restrict__ vin, unsigned short* __restrict__ vout)
{
  __shared__ __align__(16) unsigned short t[64][72];
  const int tid = threadIdx.x;
  const int c0 = blockIdx.x * 64, r0 = blockIdx.y * 64;
  #pragma unroll
  for (int c = 0; c < 2; ++c) {
    int idx = c * 256 + tid;
    int row = idx >> 3, cb = (idx & 7) << 3;
    *(uint4*)&t[row][cb] = *(const uint4*)(vin + (size_t)(r0 + row) * DIM + c0 + cb);
  }
  __syncthreads();
  const int b = r0 >> 11, s0 = r0 & (SEQ - 1);
  const int h = c0 >> 7, d0 = c0 & (HDIM - 1);
  #pragma unroll
  for (int c = 0; c < 2; ++c) {
    int idx = c * 256 + tid;
    int drow = idx >> 3, sb = (idx & 7) << 3;
    union { unsigned short u[8]; uint4 v; } pk;
    #pragma unroll
    for (int j = 0; j < 8; ++j) pk.u[j] = t[sb + j][drow];
    *(uint4*)(vout + (size_t)((b * HEADS + h) * HDIM + d0 + drow) * SEQ + s0 + sb) = pk.v;
  }
}

// ---------------- flash attention: QBLK=64, 4 blocks/CU, XCD-chunked remap ----------------
// Q pre-scaled by (1/sqrt(128))*log2(e); softmax in exp2 domain; T13 defer-rescale.
// 1-D grid of 1024 blocks, remapped so XCD x (= id%8 round-robin) serves bh in [4x,4x+4):
// the 4 K/V panels (4 MB) fit that XCD's private L2 -> q-tile blocks share them as L2 hits.
// LDS 40960 B = exactly 160KiB/4 -> 4 blocks/CU. Swizzle byte ^= ((row&7)<<4) both sides.
__global__ __launch_bounds__(256, 4) void flash_attn(
    const unsigned short* __restrict__ qf, const unsigned short* __restrict__ kf,
    const unsigned short* __restrict__ vt, float* __restrict__ o)
{
  const int tid = threadIdx.x;
  const int lane = tid & 63;
  const int w = tid >> 6;
  const int quad = lane >> 4;
  const int l16 = lane & 15;
  // XCD-chunked decode: xcd = id&7, slot = id>>3; bh = xcd*4 + slot/32, qt = slot%32
  const int L = blockIdx.x;
  const int slot = L >> 3;
  const int bh = ((L & 7) << 2) | (slot >> 5);
  const int qt = slot & 31;
  const int b = bh >> 4;
  const int h = bh & 15;

  __shared__ __align__(16) char Ks[64 * 256];     // [key t][d] halves, swizzled (16384 B)
  __shared__ __align__(16) char Vs[128 * 128];    // [d][t] halves, swizzled (16384 B)
  __shared__ __align__(16) char Ps[4][16 * 128];  // per-wave [q][t] halves, swizzled (8192 B)

  // Q fragment (B-operand): wave owns 16 q-rows
  const size_t qbase = ((size_t)(b * SEQ + qt * 64 + w * 16 + l16)) * DIM + h * HDIM;
  short8 qa[4];
  #pragma unroll
  for (int kc = 0; kc < 4; ++kc)
    qa[kc] = *(const short8*)(qf + qbase + kc * 32 + quad * 8);

  float m_q = -INFINITY;
  float l_q = 0.f;
  floatx4 accO[8];                      // O^T: rows d=dt*16+quad*4+r, col q = l16
  #pragma unroll
  for (int i = 0; i < 8; ++i) accO[i] = {0.f, 0.f, 0.f, 0.f};

  const unsigned short* kg = kf + (size_t)(b * SEQ) * DIM + h * HDIM;
  const unsigned short* vg = vt + (size_t)bh * HDIM * SEQ;

  // register prefetch buffers (one K/V tile per block iteration)
  uint4 kreg[4], vreg[4];
  #pragma unroll
  for (int i = 0; i < 4; ++i) {
    int idx = i * 256 + tid;
    kreg[i] = *(const uint4*)(kg + (size_t)(idx >> 4) * DIM + (idx & 15) * 8);
    vreg[i] = *(const uint4*)(vg + (size_t)(idx >> 3) * SEQ + (idx & 7) * 8);
  }

  for (int kt = 0; kt < SEQ / 64; ++kt) {
    __syncthreads();                    // prior tile's LDS reads complete
    #pragma unroll
    for (int i = 0; i < 4; ++i) {
      int idx = i * 256 + tid;
      int kr = idx >> 4;
      *(uint4*)&Ks[(kr * 256 + (idx & 15) * 16) ^ ((kr & 7) << 4)] = kreg[i];
      int vr = idx >> 3;
      *(uint4*)&Vs[(vr * 128 + (idx & 7) * 16) ^ ((vr & 7) << 4)] = vreg[i];
    }
    __syncthreads();
    if (kt + 1 < SEQ / 64) {            // issue next tile's loads; latency hidden by compute
      #pragma unroll
      for (int i = 0; i < 4; ++i) {
        int idx = i * 256 + tid;
        kreg[i] = *(const uint4*)(kg + (size_t)((kt + 1) * 64 + (idx >> 4)) * DIM + (idx & 15) * 8);
        vreg[i] = *(const uint4*)(vg + (size_t)(idx >> 3) * SEQ + (kt + 1) * 64 + (idx & 7) * 8);
      }
    }

    // S^T = K Q'^T : lane q = l16, keys t = jt*16 + quad*4 + r
    float sreg[4][4];
    __builtin_amdgcn_s_setprio(1);
    #pragma unroll
    for (int jt = 0; jt < 4; ++jt) {
      floatx4 a0 = {0.f, 0.f, 0.f, 0.f};
      #pragma unroll
      for (int kc = 0; kc < 4; ++kc) {
        int kr = jt * 16 + l16;
        short8 kb = *(const short8*)&Ks[(kr * 256 + kc * 64 + quad * 16) ^ ((kr & 7) << 4)];
        a0 = __builtin_amdgcn_mfma_f32_16x16x32_f16(
            __builtin_bit_cast(half8, kb), __builtin_bit_cast(half8, qa[kc]), a0, 0, 0, 0);
      }
      #pragma unroll
      for (int r = 0; r < 4; ++r) sreg[jt][r] = a0[r];
    }
    __builtin_amdgcn_s_setprio(0);

    // per-lane online softmax (exp2 domain); T13 defer-rescale
    float mx = sreg[0][0];
    #pragma unroll
    for (int jt = 0; jt < 4; ++jt)
      #pragma unroll
      for (int r = 0; r < 4; ++r) mx = fmaxf(mx, sreg[jt][r]);
    mx = fmaxf(mx, __shfl_xor(mx, 16));
    mx = fmaxf(mx, __shfl_xor(mx, 32));
    int need = !__all(mx <= m_q + 8.f);   // wave-uniform
    float mnew, alpha;
    if (need) {
      mnew = fmaxf(m_q, mx);
      alpha = exp2f(m_q - mnew);
      m_q = mnew;
    } else {
      mnew = m_q;
      alpha = 1.f;
    }
    float ssum = 0.f;
    #pragma unroll
    for (int jt = 0; jt < 4; ++jt) {
      ushort4 pk;
      float p0 = exp2f(sreg[jt][0] - mnew);
      float p1 = exp2f(sreg[jt][1] - mnew);
      float p2 = exp2f(sreg[jt][2] - mnew);
      float p3 = exp2f(sreg[jt][3] - mnew);
      pk.x = f2h(p0); pk.y = f2h(p1); pk.z = f2h(p2); pk.w = f2h(p3);
      ssum += (p0 + p1) + (p2 + p3);
      *(ushort4*)&Ps[w][(l16 * 128 + jt * 32 + quad * 8) ^ ((l16 & 7) << 4)] = pk;
    }
    ssum += __shfl_xor(ssum, 16);
    ssum += __shfl_xor(ssum, 32);
    l_q = l_q * alpha + ssum;
    if (need) {
      #pragma unroll
      for (int dt = 0; dt < 8; ++dt)
        #pragma unroll
        for (int r = 0; r < 4; ++r) accO[dt][r] *= alpha;
    }

    // O^T = O^T + V^T P^T
    __builtin_amdgcn_s_setprio(1);
    #pragma unroll
    for (int kc = 0; kc < 2; ++kc) {
      short8 pf = *(const short8*)&Ps[w][(l16 * 128 + kc * 64 + quad * 16) ^ ((l16 & 7) << 4)];
      #pragma unroll
      for (int dt = 0; dt < 8; ++dt) {
        int vr = dt * 16 + l16;
        short8 vf = *(const short8*)&Vs[(vr * 128 + kc * 64 + quad * 16) ^ ((vr & 7) << 4)];
        accO[dt] = __builtin_amdgcn_mfma_f32_16x16x32_f16(
            __builtin_bit_cast(half8, vf), __builtin_bit_cast(half8, pf), accO[dt], 0, 0, 0);
      }
    }
    __builtin_amdgcn_s_setprio(0);
  }

  // epilogue: float4 stores, 16B per lane
  float invl = 1.0f / l_q;
  const size_t obase = (size_t)(b * SEQ + qt * 64 + w * 16 + l16) * DIM + h * HDIM;
  #pragma unroll
  for (int dt = 0; dt < 8; ++dt) {
    float4 ov;
    ov.x = accO[dt][0] * invl; ov.y = accO[dt][1] * invl;
    ov.z = accO[dt][2] * invl; ov.w = accO[dt][3] * invl;
    *(float4*)(o + obase + dt * 16 + quad * 4) = ov;
  }
}

// ---------------- host ----------------
extern "C" void kernel_launch(void* const* d_in, const int* in_sizes, int n_in,
                              void* d_out, int out_size, void* d_ws, size_t ws_size,
                              hipStream_t stream)
{
  (void)in_sizes; (void)n_in; (void)out_size; (void)ws_size;
  const float* x = (const float*)d_in[0];
  const float* w[4]; const float* g[4]; const float* bb[4];
  for (int i = 0; i < 4; ++i) {
    w[i]  = (const float*)d_in[1 + 3 * i];
    g[i]  = (const float*)d_in[2 + 3 * i];
    bb[i] = (const float*)d_in[3 + 3 * i];
  }

  char* base = (char*)d_ws;
  size_t off = 0;
  auto alloc = [&](size_t bytes) {
    char* p = base + off;
    off += (bytes + 255) & ~(size_t)255;
    return p;
  };
  const size_t ACTH = (size_t)NROWS * DIM * 2;  // 16-bit activation buffer (16 MB)
  const size_t ACT8 = (size_t)NROWS * DIM;      // 8-bit activation buffer (8 MB)
  float* stats          = (float*)alloc(64);
  float* part1          = (float*)alloc(4 * 1024 * sizeof(float));
  float* part2          = (float*)alloc(4 * 1024 * 2 * sizeof(float));
  signed char* tern     = (signed char*)alloc((size_t)4 * WN);
  signed char* xq0      = (signed char*)alloc(ACT8);
  signed char* xq1      = (signed char*)alloc(ACT8);
  signed char* xq2      = (signed char*)alloc(ACT8);
  unsigned short* qh    = (unsigned short*)alloc(ACTH);
  unsigned short* kh    = (unsigned short*)alloc(ACTH);
  unsigned short* vb    = (unsigned short*)alloc(ACTH);
  unsigned short* vtb   = (unsigned short*)alloc(ACTH);
  float* oat            = (float*)alloc((size_t)NROWS * DIM * sizeof(float));
  signed char* xqo = xq0;              // overlay: xq0 dead after the q GEMM
  unsigned* ambits = (unsigned*)(stats + 8);

  hipMemsetAsync(stats, 0, 64, stream);

  dim3 b256(256);
  w_abs_partial<<<dim3(1024, 4), b256, 0, stream>>>(w[0], w[1], w[2], w[3], part1);
  w_delta_final<<<4, b256, 0, stream>>>(part1, stats);
  w_maskquant<<<dim3(1024, 4), b256, 0, stream>>>(w[0], w[1], w[2], w[3], stats, part2, tern);
  w_alpha_final<<<4, b256, 0, stream>>>(part2, stats);

  ln_absmax3<<<NROWS, b256, 0, stream>>>(x, g[0], bb[0], g[1], bb[1], g[2], bb[2], ambits);
  ln_quant3<<<NROWS, b256, 0, stream>>>(x, g[0], bb[0], g[1], bb[1], g[2], bb[2], ambits,
                                        xq0, xq1, xq2);

  dim3 ggrid(NROWS / 128, DIM / 128);
  gemm_bt<1><<<ggrid, b256, 0, stream>>>(xq0, tern + (size_t)0 * WN, qh, stats, 0);
  gemm_bt<1><<<ggrid, b256, 0, stream>>>(xq1, tern + (size_t)1 * WN, kh, stats, 1);
  gemm_bt<1><<<ggrid, b256, 0, stream>>>(xq2, tern + (size_t)2 * WN, vb, stats, 2);

  rope_kernel<<<NROWS * 1024 / 256, b256, 0, stream>>>(qh, kh);
  transpose_v<<<dim3(DIM / 64, NROWS / 64), b256, 0, stream>>>(vb, vtb);
  flash_attn<<<dim3(32 * 32), b256, 0, stream>>>(qh, kh, vtb, oat);

  ln_kernel<0><<<NROWS, b256, 0, stream>>>(oat, g[3], bb[3], ambits + 3, nullptr);
  ln_kernel<1><<<NROWS, b256, 0, stream>>>(oat, g[3], bb[3], ambits + 3, xqo);
  gemm_bt<0><<<ggrid, b256, 0, stream>>>(xqo, tern + (size_t)3 * WN, (float*)d_out, stats, 3);
}

// Round 5
// 630.637 us; speedup vs baseline: 1.5097x; 1.4770x over previous
//
#include <hip/hip_runtime.h>
#include <math.h>

#define DIM 2048
#define NROWS 4096            // B*S
#define WN (DIM*DIM)
#define HEADS 16
#define HDIM 128
#define SEQ 2048

typedef __attribute__((ext_vector_type(8))) short short8;
typedef __attribute__((ext_vector_type(8))) _Float16 half8;
typedef __attribute__((ext_vector_type(4))) float floatx4;
typedef __attribute__((ext_vector_type(4))) int intx4;

__device__ __forceinline__ float bf2f(unsigned short u) {
  return __uint_as_float(((unsigned)u) << 16);
}
__device__ __forceinline__ unsigned short f2bf(float f) {
  unsigned x = __float_as_uint(f);
  x += 0x7FFFu + ((x >> 16) & 1u);   // RTNE
  return (unsigned short)(x >> 16);
}
__device__ __forceinline__ unsigned short f2h(float f) {
  _Float16 h = (_Float16)f;
  return __builtin_bit_cast(unsigned short, h);
}
__device__ __forceinline__ float h2f(unsigned short u) {
  _Float16 h = __builtin_bit_cast(_Float16, u);
  return (float)h;
}

// async global->LDS, 16B per lane; lds base must be wave-uniform (HW scatters lane i at +i*16)
__device__ __forceinline__ void gload_lds16(const void* g, void* l) {
  __builtin_amdgcn_global_load_lds(
      (const __attribute__((address_space(1))) unsigned int*)g,
      (__attribute__((address_space(3))) unsigned int*)l, 16, 0, 0);
}

__device__ __forceinline__ float blockReduceSum(float v, float* red) {
  int tid = threadIdx.x;
  red[tid] = v; __syncthreads();
  for (int s = 128; s > 0; s >>= 1) {
    if (tid < s) red[tid] += red[tid + s];
    __syncthreads();
  }
  float r = red[0]; __syncthreads();
  return r;
}
__device__ __forceinline__ float blockReduceMax(float v, float* red) {
  int tid = threadIdx.x;
  red[tid] = v; __syncthreads();
  for (int s = 128; s > 0; s >>= 1) {
    if (tid < s) red[tid] = fmaxf(red[tid], red[tid + s]);
    __syncthreads();
  }
  float r = red[0]; __syncthreads();
  return r;
}

__device__ __forceinline__ const float* pick_w(const float* a, const float* b,
                                               const float* c, const float* d, int i) {
  return i == 0 ? a : i == 1 ? b : i == 2 ? c : d;
}

// ---------------- weight stats ----------------
__global__ __launch_bounds__(256) void w_abs_partial(
    const float* w0, const float* w1, const float* w2, const float* w3, float* part)
{
  const float4* w4 = (const float4*)pick_w(w0, w1, w2, w3, blockIdx.y);
  float s = 0.f;
  for (int i = blockIdx.x * 256 + threadIdx.x; i < WN / 4; i += 1024 * 256) {
    float4 v = w4[i];
    s += fabsf(v.x) + fabsf(v.y) + fabsf(v.z) + fabsf(v.w);
  }
  __shared__ float red[256];
  float t = blockReduceSum(s, red);
  if (threadIdx.x == 0) part[blockIdx.y * 1024 + blockIdx.x] = t;
}

__global__ __launch_bounds__(256) void w_delta_final(const float* part, float* stats)
{
  float s = 0.f;
  for (int i = threadIdx.x; i < 1024; i += 256) s += part[blockIdx.x * 1024 + i];
  __shared__ float red[256];
  float t = blockReduceSum(s, red);
  if (threadIdx.x == 0) stats[blockIdx.x] = 0.7f * (t / (float)WN);
}

__device__ __forceinline__ signed char tq(float v, float delta) {
  if (fabsf(v) > delta) return (v > 0.f) ? (signed char)1 : (signed char)-1;
  return (signed char)0;
}

// fused: ternary-quantize weights (int8 {-1,0,1}) AND accumulate alpha partials
__global__ __launch_bounds__(256) void w_maskquant(
    const float* w0, const float* w1, const float* w2, const float* w3,
    const float* stats, float* part2, signed char* tern)
{
  int wi = blockIdx.y;
  const float4* w4 = (const float4*)pick_w(w0, w1, w2, w3, wi);
  float delta = stats[wi];
  char4* out = (char4*)(tern + (size_t)wi * WN);
  float s = 0.f, cnt = 0.f;
  for (int i = blockIdx.x * 256 + threadIdx.x; i < WN / 4; i += 1024 * 256) {
    float4 v = w4[i];
    char4 o;
    float a;
    a = fabsf(v.x); if (a > delta) { s += a; cnt += 1.f; } o.x = tq(v.x, delta);
    a = fabsf(v.y); if (a > delta) { s += a; cnt += 1.f; } o.y = tq(v.y, delta);
    a = fabsf(v.z); if (a > delta) { s += a; cnt += 1.f; } o.z = tq(v.z, delta);
    a = fabsf(v.w); if (a > delta) { s += a; cnt += 1.f; } o.w = tq(v.w, delta);
    out[i] = o;
  }
  __shared__ float red[256];
  float ts = blockReduceSum(s, red);
  float tc = blockReduceSum(cnt, red);
  if (threadIdx.x == 0) {
    part2[((size_t)blockIdx.y * 1024 + blockIdx.x) * 2]     = ts;
    part2[((size_t)blockIdx.y * 1024 + blockIdx.x) * 2 + 1] = tc;
  }
}

__global__ __launch_bounds__(256) void w_alpha_final(const float* part2, float* stats)
{
  float s = 0.f, c = 0.f;
  for (int i = threadIdx.x; i < 1024; i += 256) {
    s += part2[((size_t)blockIdx.x * 1024 + i) * 2];
    c += part2[((size_t)blockIdx.x * 1024 + i) * 2 + 1];
  }
  __shared__ float red[256];
  float ts = blockReduceSum(s, red);
  float tc = blockReduceSum(c, red);
  if (threadIdx.x == 0) stats[4 + blockIdx.x] = ts / fmaxf(tc, 1.f);
}

// ---------------- fused LN for q/k/v ----------------
__global__ __launch_bounds__(256) void ln_absmax3(
    const float* __restrict__ x,
    const float* __restrict__ g0, const float* __restrict__ b0,
    const float* __restrict__ g1, const float* __restrict__ b1,
    const float* __restrict__ g2, const float* __restrict__ b2,
    unsigned* __restrict__ ambits)
{
  const int row = blockIdx.x, tid = threadIdx.x;
  const float* xr = x + (size_t)row * DIM;
  float4 a0 = *(const float4*)(xr + tid * 4);
  float4 a1 = *(const float4*)(xr + 1024 + tid * 4);
  float s  = a0.x + a0.y + a0.z + a0.w + a1.x + a1.y + a1.z + a1.w;
  float sq = a0.x*a0.x + a0.y*a0.y + a0.z*a0.z + a0.w*a0.w
           + a1.x*a1.x + a1.y*a1.y + a1.z*a1.z + a1.w*a1.w;
  __shared__ float red[256];
  float ts = blockReduceSum(s, red);
  float tqq = blockReduceSum(sq, red);
  float mu = ts * (1.f / DIM);
  float var = tqq * (1.f / DIM) - mu * mu;
  float rstd = 1.f / sqrtf(var + 1e-5f);
  float yn[8];
  yn[0] = (a0.x - mu) * rstd; yn[1] = (a0.y - mu) * rstd;
  yn[2] = (a0.z - mu) * rstd; yn[3] = (a0.w - mu) * rstd;
  yn[4] = (a1.x - mu) * rstd; yn[5] = (a1.y - mu) * rstd;
  yn[6] = (a1.z - mu) * rstd; yn[7] = (a1.w - mu) * rstd;
  const float* gs[3] = {g0, g1, g2};
  const float* bs[3] = {b0, b1, b2};
  #pragma unroll
  for (int p = 0; p < 3; ++p) {
    float4 gg0 = *(const float4*)(gs[p] + tid * 4);
    float4 gg1 = *(const float4*)(gs[p] + 1024 + tid * 4);
    float4 bb0 = *(const float4*)(bs[p] + tid * 4);
    float4 bb1 = *(const float4*)(bs[p] + 1024 + tid * 4);
    float m = fabsf(yn[0] * gg0.x + bb0.x);
    m = fmaxf(m, fabsf(yn[1] * gg0.y + bb0.y));
    m = fmaxf(m, fabsf(yn[2] * gg0.z + bb0.z));
    m = fmaxf(m, fabsf(yn[3] * gg0.w + bb0.w));
    m = fmaxf(m, fabsf(yn[4] * gg1.x + bb1.x));
    m = fmaxf(m, fabsf(yn[5] * gg1.y + bb1.y));
    m = fmaxf(m, fabsf(yn[6] * gg1.z + bb1.z));
    m = fmaxf(m, fabsf(yn[7] * gg1.w + bb1.w));
    float bm = blockReduceMax(m, red);
    if (tid == 0) atomicMax(ambits + p, __float_as_uint(bm));
  }
}

__global__ __launch_bounds__(256) void ln_quant3(
    const float* __restrict__ x,
    const float* __restrict__ g0, const float* __restrict__ b0,
    const float* __restrict__ g1, const float* __restrict__ b1,
    const float* __restrict__ g2, const float* __restrict__ b2,
    const unsigned* __restrict__ ambits,
    signed char* __restrict__ xq0, signed char* __restrict__ xq1,
    signed char* __restrict__ xq2)
{
  const int row = blockIdx.x, tid = threadIdx.x;
  const float* xr = x + (size_t)row * DIM;
  float4 a0 = *(const float4*)(xr + tid * 4);
  float4 a1 = *(const float4*)(xr + 1024 + tid * 4);
  float s  = a0.x + a0.y + a0.z + a0.w + a1.x + a1.y + a1.z + a1.w;
  float sq = a0.x*a0.x + a0.y*a0.y + a0.z*a0.z + a0.w*a0.w
           + a1.x*a1.x + a1.y*a1.y + a1.z*a1.z + a1.w*a1.w;
  __shared__ float red[256];
  float ts = blockReduceSum(s, red);
  float tqq = blockReduceSum(sq, red);
  float mu = ts * (1.f / DIM);
  float var = tqq * (1.f / DIM) - mu * mu;
  float rstd = 1.f / sqrtf(var + 1e-5f);
  float yn[8];
  yn[0] = (a0.x - mu) * rstd; yn[1] = (a0.y - mu) * rstd;
  yn[2] = (a0.z - mu) * rstd; yn[3] = (a0.w - mu) * rstd;
  yn[4] = (a1.x - mu) * rstd; yn[5] = (a1.y - mu) * rstd;
  yn[6] = (a1.z - mu) * rstd; yn[7] = (a1.w - mu) * rstd;
  const float* gs[3] = {g0, g1, g2};
  const float* bs[3] = {b0, b1, b2};
  signed char* outs[3] = {xq0, xq1, xq2};
  #pragma unroll
  for (int p = 0; p < 3; ++p) {
    float4 gg0 = *(const float4*)(gs[p] + tid * 4);
    float4 gg1 = *(const float4*)(gs[p] + 1024 + tid * 4);
    float4 bb0 = *(const float4*)(bs[p] + tid * 4);
    float4 bb1 = *(const float4*)(bs[p] + 1024 + tid * 4);
    float y[8];
    y[0] = yn[0] * gg0.x + bb0.x; y[1] = yn[1] * gg0.y + bb0.y;
    y[2] = yn[2] * gg0.z + bb0.z; y[3] = yn[3] * gg0.w + bb0.w;
    y[4] = yn[4] * gg1.x + bb1.x; y[5] = yn[5] * gg1.y + bb1.y;
    y[6] = yn[6] * gg1.z + bb1.z; y[7] = yn[7] * gg1.w + bb1.w;
    float sc = 127.f / fmaxf(__uint_as_float(ambits[p]), 1e-5f);
    signed char o[8];
    #pragma unroll
    for (int j = 0; j < 8; ++j) {
      float qv = rintf(y[j] * sc);
      qv = fminf(fmaxf(qv, -128.f), 127.f);
      o[j] = (signed char)(int)qv;
    }
    char4 q0; q0.x = o[0]; q0.y = o[1]; q0.z = o[2]; q0.w = o[3];
    char4 q1; q1.x = o[4]; q1.y = o[5]; q1.z = o[6]; q1.w = o[7];
    *(char4*)(outs[p] + (size_t)row * DIM + tid * 4) = q0;
    *(char4*)(outs[p] + (size_t)row * DIM + 1024 + tid * 4) = q1;
  }
}

// ---------------- single-tensor LN (for the o projection) ----------------
template<int MODE>
__global__ __launch_bounds__(256) void ln_kernel(
    const float* __restrict__ x, const float* __restrict__ g, const float* __restrict__ bias,
    unsigned* __restrict__ ambits, signed char* __restrict__ xq)
{
  const int row = blockIdx.x, tid = threadIdx.x;
  const float* xr = x + (size_t)row * DIM;
  float4 a0 = *(const float4*)(xr + tid * 4);
  float4 a1 = *(const float4*)(xr + 1024 + tid * 4);
  float s  = a0.x + a0.y + a0.z + a0.w + a1.x + a1.y + a1.z + a1.w;
  float sq = a0.x*a0.x + a0.y*a0.y + a0.z*a0.z + a0.w*a0.w
           + a1.x*a1.x + a1.y*a1.y + a1.z*a1.z + a1.w*a1.w;
  __shared__ float red[256];
  float ts = blockReduceSum(s, red);
  float tqq = blockReduceSum(sq, red);
  float mu = ts * (1.f / DIM);
  float var = tqq * (1.f / DIM) - mu * mu;
  float rstd = 1.f / sqrtf(var + 1e-5f);
  float4 g0 = *(const float4*)(g + tid * 4);
  float4 g1 = *(const float4*)(g + 1024 + tid * 4);
  float4 b0 = *(const float4*)(bias + tid * 4);
  float4 b1 = *(const float4*)(bias + 1024 + tid * 4);
  float y[8];
  y[0] = (a0.x - mu) * rstd * g0.x + b0.x;
  y[1] = (a0.y - mu) * rstd * g0.y + b0.y;
  y[2] = (a0.z - mu) * rstd * g0.z + b0.z;
  y[3] = (a0.w - mu) * rstd * g0.w + b0.w;
  y[4] = (a1.x - mu) * rstd * g1.x + b1.x;
  y[5] = (a1.y - mu) * rstd * g1.y + b1.y;
  y[6] = (a1.z - mu) * rstd * g1.z + b1.z;
  y[7] = (a1.w - mu) * rstd * g1.w + b1.w;
  if (MODE == 0) {
    float m = 0.f;
    #pragma unroll
    for (int j = 0; j < 8; ++j) m = fmaxf(m, fabsf(y[j]));
    float bm = blockReduceMax(m, red);
    if (tid == 0) atomicMax(ambits, __float_as_uint(bm));
  } else {
    float sc = 127.f / fmaxf(__uint_as_float(*ambits), 1e-5f);
    signed char o[8];
    #pragma unroll
    for (int j = 0; j < 8; ++j) {
      float qv = rintf(y[j] * sc);
      qv = fminf(fmaxf(qv, -128.f), 127.f);
      o[j] = (signed char)(int)qv;
    }
    char4 q0; q0.x = o[0]; q0.y = o[1]; q0.z = o[2]; q0.w = o[3];
    char4 q1; q1.x = o[4]; q1.y = o[5]; q1.z = o[6]; q1.w = o[7];
    *(char4*)(xq + (size_t)row * DIM + tid * 4) = q0;
    *(char4*)(xq + (size_t)row * DIM + 1024 + tid * 4) = q1;
  }
}

// ---------------- int8 quantized GEMM, m97 structure: global_load_lds staging ----------------
// A: int8 activations [-128,127]; Bt: ternary int8 {-1,0,1} (row = output column).
// mfma_i32_16x16x64_i8: 2x K per instr vs bf16, exact i32 accumulation.
// OMODE: 0 = fp32 out, 1 = fp16 out
template<int OMODE>
__global__ __launch_bounds__(256) void gemm_bt(
    const signed char* __restrict__ A, const signed char* __restrict__ Bt,
    void* __restrict__ Cp0, const float* __restrict__ stats, int wi)
{
  const int tid = threadIdx.x;
  const int lane = tid & 63;
  const int w = tid >> 6;
  const int wm = w >> 1, wn = w & 1;
  const int quad = lane >> 4, l16 = lane & 15;
  const int bm = blockIdx.x * 128, bn = blockIdx.y * 128;

  // unpadded, contiguous row-major [128][128] i8 — required by global_load_lds lane scatter
  __shared__ __align__(16) signed char As[128 * 128];
  __shared__ __align__(16) signed char Bs[128 * 128];

  // per-chunk geometry: chunk c (1 KiB) = rows c*8..c*8+8; lane i -> row c*8+(i>>3), col (i&7)*16
  const int srow_off = lane >> 3;        // 0..7
  const int scol     = (lane & 7) * 16;  // bytes

  intx4 acc[4][4];
  #pragma unroll
  for (int i = 0; i < 4; ++i)
    #pragma unroll
    for (int j = 0; j < 4; ++j) acc[i][j] = {0, 0, 0, 0};

  for (int k0 = 0; k0 < DIM; k0 += 128) {
    #pragma unroll
    for (int i = 0; i < 4; ++i) {
      int c = i * 4 + w;                 // wave-uniform chunk id, 16 chunks = 128 rows
      int row = c * 8 + srow_off;
      gload_lds16(A  + (size_t)(bm + row) * DIM + k0 + scol, &As[c * 1024]);
      gload_lds16(Bt + (size_t)(bn + row) * DIM + k0 + scol, &Bs[c * 1024]);
    }
    __syncthreads();
    #pragma unroll
    for (int kc = 0; kc < 2; ++kc) {
      intx4 af[4], bf[4];
      #pragma unroll
      for (int i = 0; i < 4; ++i)
        af[i] = *(const intx4*)&As[(wm * 64 + i * 16 + l16) * 128 + kc * 64 + quad * 16];
      #pragma unroll
      for (int j = 0; j < 4; ++j)
        bf[j] = *(const intx4*)&Bs[(wn * 64 + j * 16 + l16) * 128 + kc * 64 + quad * 16];
      #pragma unroll
      for (int i = 0; i < 4; ++i)
        #pragma unroll
        for (int j = 0; j < 4; ++j)
          acc[i][j] = __builtin_amdgcn_mfma_i32_16x16x64_i8(af[i], bf[j], acc[i][j], 0, 0, 0);
    }
    __syncthreads();
  }

  const unsigned* am = (const unsigned*)(stats + 8);
  float scale = stats[4 + wi] * fmaxf(__uint_as_float(am[wi]), 1e-5f) * (1.f / 127.f);
  #pragma unroll
  for (int i = 0; i < 4; ++i)
    #pragma unroll
    for (int j = 0; j < 4; ++j)
      #pragma unroll
      for (int r = 0; r < 4; ++r) {
        int m = bm + wm * 64 + i * 16 + quad * 4 + r;
        int n = bn + wn * 64 + j * 16 + l16;
        size_t idx = (size_t)m * DIM + n;
        float v = (float)acc[i][j][r] * scale;
        if (OMODE == 0) ((float*)Cp0)[idx] = v;
        else            ((unsigned short*)Cp0)[idx] = f2h(v);
      }
}

// ---------------- rope (fp16; angle = head_index * inv; q gets (1/sqrt(128))*log2e folded) ----------------
__global__ __launch_bounds__(256) void rope_kernel(unsigned short* q, unsigned short* k)
{
  const float SC = 0.12751741769011063f;   // (1/sqrt(128)) * log2(e)
  int idx = blockIdx.x * 256 + threadIdx.x;
  int p = idx & 63;
  int h = (idx >> 6) & (HEADS - 1);
  int r = idx >> 10;
  float inv = exp2f((float)p * -0.20762050593046f);  // 10000^(-p/64)
  float ang = (float)h * inv;
  float sn, cs;
  __sincosf(ang, &sn, &cs);
  size_t base = (size_t)r * DIM + h * HDIM + 2 * p;
  {
    float a = h2f(q[base]), b = h2f(q[base + 1]);
    q[base]     = f2h((a * cs - b * sn) * SC);
    q[base + 1] = f2h((a * sn + b * cs) * SC);
  }
  {
    float a = h2f(k[base]), b = h2f(k[base + 1]);
    k[base]     = f2h(a * cs - b * sn);
    k[base + 1] = f2h(a * sn + b * cs);
  }
}

// ---------------- transpose V: [b*S+s][h*128+d] -> [(b*16+h)*128+d][s] ----------------
__global__ __launch_bounds__(256) void transpose_v(
    const unsigned short* __restrict__ vin, unsigned short* __restrict__ vout)
{
  __shared__ __align__(16) unsigned short t[64][72];
  const int tid = threadIdx.x;
  const int c0 = blockIdx.x * 64, r0 = blockIdx.y * 64;
  #pragma unroll
  for (int c = 0; c < 2; ++c) {
    int idx = c * 256 + tid;
    int row = idx >> 3, cb = (idx & 7) << 3;
    *(uint4*)&t[row][cb] = *(const uint4*)(vin + (size_t)(r0 + row) * DIM + c0 + cb);
  }
  __syncthreads();
  const int b = r0 >> 11, s0 = r0 & (SEQ - 1);
  const int h = c0 >> 7, d0 = c0 & (HDIM - 1);
  #pragma unroll
  for (int c = 0; c < 2; ++c) {
    int idx = c * 256 + tid;
    int drow = idx >> 3, sb = (idx & 7) << 3;
    union { unsigned short u[8]; uint4 v; } pk;
    #pragma unroll
    for (int j = 0; j < 8; ++j) pk.u[j] = t[sb + j][drow];
    *(uint4*)(vout + (size_t)((b * HEADS + h) * HDIM + d0 + drow) * SEQ + s0 + sb) = pk.v;
  }
}

// ---------------- flash attention: QBLK=64, 4 blocks/CU, gload_lds staging ----------------
// Q pre-scaled by (1/sqrt(128))*log2(e); softmax in exp2 domain; T13 defer-rescale.
// SPILL FIX (r4): no register K/V staging — global_load_lds DMA with PRE-SWIZZLED global
// source addresses (rule #21: LDS dest linear, source carries the involution). Live VGPRs
// ~80 < 128 cap at 4 blocks/CU, so no scratch. XCD-chunked remap: id%8 = XCD, 4 bh/XCD.
__global__ __launch_bounds__(256, 4) void flash_attn(
    const unsigned short* __restrict__ qf, const unsigned short* __restrict__ kf,
    const unsigned short* __restrict__ vt, float* __restrict__ o)
{
  const int tid = threadIdx.x;
  const int lane = tid & 63;
  const int w = tid >> 6;
  const int quad = lane >> 4;
  const int l16 = lane & 15;
  // XCD-chunked decode: xcd = id&7, slot = id>>3; bh = xcd*4 + slot/32, qt = slot%32
  const int L = blockIdx.x;
  const int slot = L >> 3;
  const int bh = ((L & 7) << 2) | (slot >> 5);
  const int qt = slot & 31;
  const int b = bh >> 4;
  const int h = bh & 15;

  __shared__ __align__(16) char Ks[64 * 256];     // [key t][d] halves; LDS[d]=Gtile[d^((d>>8&7)<<4)]
  __shared__ __align__(16) char Vs[128 * 128];    // [d][t] halves;    LDS[d]=Gtile[d^((d>>7&7)<<4)]
  __shared__ __align__(16) char Ps[4][16 * 128];  // per-wave [q][t] halves, swizzled (8192 B)

  // Q fragment (B-operand): wave owns 16 q-rows
  const size_t qbase = ((size_t)(b * SEQ + qt * 64 + w * 16 + l16)) * DIM + h * HDIM;
  short8 qa[4];
  #pragma unroll
  for (int kc = 0; kc < 4; ++kc)
    qa[kc] = *(const short8*)(qf + qbase + kc * 32 + quad * 8);

  float m_q = -INFINITY;
  float l_q = 0.f;
  floatx4 accO[8];                      // O^T: rows d=dt*16+quad*4+r, col q = l16
  #pragma unroll
  for (int i = 0; i < 8; ++i) accO[i] = {0.f, 0.f, 0.f, 0.f};

  const char* kg = (const char*)(kf + (size_t)(b * SEQ) * DIM + h * HDIM);
  const char* vg = (const char*)(vt + (size_t)bh * HDIM * SEQ);

  // per-lane pre-swizzled source offsets (bytes) for this wave's 4 chunks of K and V.
  // chunk c covers LDS bytes [c*1024, c*1024+1024); lane i lands at c*1024 + i*16.
  // K: dest d -> row r=d>>8, col cb=(d&255)^((r&7)<<4); source = r*(DIM*2) + cb.
  // V: dest d -> row r=d>>7, col cb=(d&127)^((r&7)<<4); source = r*(SEQ*2) + cb.
  int koff[4], voff[4];
  #pragma unroll
  for (int j = 0; j < 4; ++j) {
    int c = w * 4 + j;
    int rK = c * 4 + (lane >> 4);
    koff[j] = rK * (DIM * 2) + (((lane & 15) * 16) ^ ((rK & 7) << 4));
    int rV = c * 8 + (lane >> 3);
    voff[j] = rV * (SEQ * 2) + (((lane & 7) * 16) ^ ((rV & 7) << 4));
  }

  for (int kt = 0; kt < SEQ / 64; ++kt) {
    __syncthreads();                    // prior tile's LDS reads complete
    const char* kgb = kg + (size_t)kt * 64 * DIM * 2;   // key rows advance
    const char* vgb = vg + (size_t)kt * 128;            // value cols advance (bytes)
    #pragma unroll
    for (int j = 0; j < 4; ++j) {
      int c = w * 4 + j;
      gload_lds16(kgb + koff[j], &Ks[c * 1024]);
      gload_lds16(vgb + voff[j], &Vs[c * 1024]);
    }
    asm volatile("s_waitcnt vmcnt(0)" ::: "memory");
    __syncthreads();

    // S^T = K Q'^T : lane q = l16, keys t = jt*16 + quad*4 + r
    float sreg[4][4];
    __builtin_amdgcn_s_setprio(1);
    #pragma unroll
    for (int jt = 0; jt < 4; ++jt) {
      floatx4 a0 = {0.f, 0.f, 0.f, 0.f};
      #pragma unroll
      for (int kc = 0; kc < 4; ++kc) {
        int kr = jt * 16 + l16;
        short8 kb = *(const short8*)&Ks[(kr * 256 + kc * 64 + quad * 16) ^ ((kr & 7) << 4)];
        a0 = __builtin_amdgcn_mfma_f32_16x16x32_f16(
            __builtin_bit_cast(half8, kb), __builtin_bit_cast(half8, qa[kc]), a0, 0, 0, 0);
      }
      #pragma unroll
      for (int r = 0; r < 4; ++r) sreg[jt][r] = a0[r];
    }
    __builtin_amdgcn_s_setprio(0);

    // per-lane online softmax (exp2 domain); T13 defer-rescale
    float mx = sreg[0][0];
    #pragma unroll
    for (int jt = 0; jt < 4; ++jt)
      #pragma unroll
      for (int r = 0; r < 4; ++r) mx = fmaxf(mx, sreg[jt][r]);
    mx = fmaxf(mx, __shfl_xor(mx, 16));
    mx = fmaxf(mx, __shfl_xor(mx, 32));
    int need = !__all(mx <= m_q + 8.f);   // wave-uniform
    float mnew, alpha;
    if (need) {
      mnew = fmaxf(m_q, mx);
      alpha = exp2f(m_q - mnew);
      m_q = mnew;
    } else {
      mnew = m_q;
      alpha = 1.f;
    }
    float ssum = 0.f;
    #pragma unroll
    for (int jt = 0; jt < 4; ++jt) {
      ushort4 pk;
      float p0 = exp2f(sreg[jt][0] - mnew);
      float p1 = exp2f(sreg[jt][1] - mnew);
      float p2 = exp2f(sreg[jt][2] - mnew);
      float p3 = exp2f(sreg[jt][3] - mnew);
      pk.x = f2h(p0); pk.y = f2h(p1); pk.z = f2h(p2); pk.w = f2h(p3);
      ssum += (p0 + p1) + (p2 + p3);
      *(ushort4*)&Ps[w][(l16 * 128 + jt * 32 + quad * 8) ^ ((l16 & 7) << 4)] = pk;
    }
    ssum += __shfl_xor(ssum, 16);
    ssum += __shfl_xor(ssum, 32);
    l_q = l_q * alpha + ssum;
    if (need) {
      #pragma unroll
      for (int dt = 0; dt < 8; ++dt)
        #pragma unroll
        for (int r = 0; r < 4; ++r) accO[dt][r] *= alpha;
    }

    // O^T = O^T + V^T P^T
    __builtin_amdgcn_s_setprio(1);
    #pragma unroll
    for (int kc = 0; kc < 2; ++kc) {
      short8 pf = *(const short8*)&Ps[w][(l16 * 128 + kc * 64 + quad * 16) ^ ((l16 & 7) << 4)];
      #pragma unroll
      for (int dt = 0; dt < 8; ++dt) {
        int vr = dt * 16 + l16;
        short8 vf = *(const short8*)&Vs[(vr * 128 + kc * 64 + quad * 16) ^ ((vr & 7) << 4)];
        accO[dt] = __builtin_amdgcn_mfma_f32_16x16x32_f16(
            __builtin_bit_cast(half8, vf), __builtin_bit_cast(half8, pf), accO[dt], 0, 0, 0);
      }
    }
    __builtin_amdgcn_s_setprio(0);
  }

  // epilogue: float4 stores, 16B per lane
  float invl = 1.0f / l_q;
  const size_t obase = (size_t)(b * SEQ + qt * 64 + w * 16 + l16) * DIM + h * HDIM;
  #pragma unroll
  for (int dt = 0; dt < 8; ++dt) {
    float4 ov;
    ov.x = accO[dt][0] * invl; ov.y = accO[dt][1] * invl;
    ov.z = accO[dt][2] * invl; ov.w = accO[dt][3] * invl;
    *(float4*)(o + obase + dt * 16 + quad * 4) = ov;
  }
}

// ---------------- host ----------------
extern "C" void kernel_launch(void* const* d_in, const int* in_sizes, int n_in,
                              void* d_out, int out_size, void* d_ws, size_t ws_size,
                              hipStream_t stream)
{
  (void)in_sizes; (void)n_in; (void)out_size; (void)ws_size;
  const float* x = (const float*)d_in[0];
  const float* w[4]; const float* g[4]; const float* bb[4];
  for (int i = 0; i < 4; ++i) {
    w[i]  = (const float*)d_in[1 + 3 * i];
    g[i]  = (const float*)d_in[2 + 3 * i];
    bb[i] = (const float*)d_in[3 + 3 * i];
  }

  char* base = (char*)d_ws;
  size_t off = 0;
  auto alloc = [&](size_t bytes) {
    char* p = base + off;
    off += (bytes + 255) & ~(size_t)255;
    return p;
  };
  const size_t ACTH = (size_t)NROWS * DIM * 2;  // 16-bit activation buffer (16 MB)
  const size_t ACT8 = (size_t)NROWS * DIM;      // 8-bit activation buffer (8 MB)
  float* stats          = (float*)alloc(64);
  float* part1          = (float*)alloc(4 * 1024 * sizeof(float));
  float* part2          = (float*)alloc(4 * 1024 * 2 * sizeof(float));
  signed char* tern     = (signed char*)alloc((size_t)4 * WN);
  signed char* xq0      = (signed char*)alloc(ACT8);
  signed char* xq1      = (signed char*)alloc(ACT8);
  signed char* xq2      = (signed char*)alloc(ACT8);
  unsigned short* qh    = (unsigned short*)alloc(ACTH);
  unsigned short* kh    = (unsigned short*)alloc(ACTH);
  unsigned short* vb    = (unsigned short*)alloc(ACTH);
  unsigned short* vtb   = (unsigned short*)alloc(ACTH);
  float* oat            = (float*)alloc((size_t)NROWS * DIM * sizeof(float));
  signed char* xqo = xq0;              // overlay: xq0 dead after the q GEMM
  unsigned* ambits = (unsigned*)(stats + 8);

  hipMemsetAsync(stats, 0, 64, stream);

  dim3 b256(256);
  w_abs_partial<<<dim3(1024, 4), b256, 0, stream>>>(w[0], w[1], w[2], w[3], part1);
  w_delta_final<<<4, b256, 0, stream>>>(part1, stats);
  w_maskquant<<<dim3(1024, 4), b256, 0, stream>>>(w[0], w[1], w[2], w[3], stats, part2, tern);
  w_alpha_final<<<4, b256, 0, stream>>>(part2, stats);

  ln_absmax3<<<NROWS, b256, 0, stream>>>(x, g[0], bb[0], g[1], bb[1], g[2], bb[2], ambits);
  ln_quant3<<<NROWS, b256, 0, stream>>>(x, g[0], bb[0], g[1], bb[1], g[2], bb[2], ambits,
                                        xq0, xq1, xq2);

  dim3 ggrid(NROWS / 128, DIM / 128);
  gemm_bt<1><<<ggrid, b256, 0, stream>>>(xq0, tern + (size_t)0 * WN, qh, stats, 0);
  gemm_bt<1><<<ggrid, b256, 0, stream>>>(xq1, tern + (size_t)1 * WN, kh, stats, 1);
  gemm_bt<1><<<ggrid, b256, 0, stream>>>(xq2, tern + (size_t)2 * WN, vb, stats, 2);

  rope_kernel<<<NROWS * 1024 / 256, b256, 0, stream>>>(qh, kh);
  transpose_v<<<dim3(DIM / 64, NROWS / 64), b256, 0, stream>>>(vb, vtb);
  flash_attn<<<dim3(32 * 32), b256, 0, stream>>>(qh, kh, vtb, oat);

  ln_kernel<0><<<NROWS, b256, 0, stream>>>(oat, g[3], bb[3], ambits + 3, nullptr);
  ln_kernel<1><<<NROWS, b256, 0, stream>>>(oat, g[3], bb[3], ambits + 3, xqo);
  gemm_bt<0><<<ggrid, b256, 0, stream>>>(xqo, tern + (size_t)3 * WN, (float*)d_out, stats, 3);
}

// Round 6
// 461.454 us; speedup vs baseline: 2.0632x; 1.3666x over previous
//
#include <hip/hip_runtime.h>
#include <math.h>

#define DIM 2048
#define NROWS 4096            // B*S
#define WN (DIM*DIM)
#define HEADS 16
#define HDIM 128
#define SEQ 2048

typedef __attribute__((ext_vector_type(8))) short short8;
typedef __attribute__((ext_vector_type(8))) _Float16 half8;
typedef __attribute__((ext_vector_type(4))) float floatx4;
typedef __attribute__((ext_vector_type(4))) int intx4;

__device__ __forceinline__ float bf2f(unsigned short u) {
  return __uint_as_float(((unsigned)u) << 16);
}
__device__ __forceinline__ unsigned short f2bf(float f) {
  unsigned x = __float_as_uint(f);
  x += 0x7FFFu + ((x >> 16) & 1u);   // RTNE
  return (unsigned short)(x >> 16);
}
__device__ __forceinline__ unsigned short f2h(float f) {
  _Float16 h = (_Float16)f;
  return __builtin_bit_cast(unsigned short, h);
}
__device__ __forceinline__ float h2f(unsigned short u) {
  _Float16 h = __builtin_bit_cast(_Float16, u);
  return (float)h;
}

// async global->LDS, 16B per lane; lds base must be wave-uniform (HW scatters lane i at +i*16)
__device__ __forceinline__ void gload_lds16(const void* g, void* l) {
  __builtin_amdgcn_global_load_lds(
      (const __attribute__((address_space(1))) unsigned int*)g,
      (__attribute__((address_space(3))) unsigned int*)l, 16, 0, 0);
}

__device__ __forceinline__ float wredSum(float v) {
  #pragma unroll
  for (int o = 1; o < 64; o <<= 1) v += __shfl_xor(v, o);
  return v;
}
__device__ __forceinline__ float wredMax(float v) {
  #pragma unroll
  for (int o = 1; o < 64; o <<= 1) v = fmaxf(v, __shfl_xor(v, o));
  return v;
}

__device__ __forceinline__ float blockReduceSum(float v, float* red) {
  int tid = threadIdx.x;
  red[tid] = v; __syncthreads();
  for (int s = 128; s > 0; s >>= 1) {
    if (tid < s) red[tid] += red[tid + s];
    __syncthreads();
  }
  float r = red[0]; __syncthreads();
  return r;
}

__device__ __forceinline__ const float* pick_w(const float* a, const float* b,
                                               const float* c, const float* d, int i) {
  return i == 0 ? a : i == 1 ? b : i == 2 ? c : d;
}

// ---------------- weight stats ----------------
__global__ __launch_bounds__(256) void w_abs_partial(
    const float* w0, const float* w1, const float* w2, const float* w3, float* part)
{
  const float4* w4 = (const float4*)pick_w(w0, w1, w2, w3, blockIdx.y);
  float s = 0.f;
  for (int i = blockIdx.x * 256 + threadIdx.x; i < WN / 4; i += 1024 * 256) {
    float4 v = w4[i];
    s += fabsf(v.x) + fabsf(v.y) + fabsf(v.z) + fabsf(v.w);
  }
  __shared__ float red[256];
  float t = blockReduceSum(s, red);
  if (threadIdx.x == 0) part[blockIdx.y * 1024 + blockIdx.x] = t;
}

__global__ __launch_bounds__(256) void w_delta_final(const float* part, float* stats)
{
  float s = 0.f;
  for (int i = threadIdx.x; i < 1024; i += 256) s += part[blockIdx.x * 1024 + i];
  __shared__ float red[256];
  float t = blockReduceSum(s, red);
  if (threadIdx.x == 0) stats[blockIdx.x] = 0.7f * (t / (float)WN);
}

__device__ __forceinline__ signed char tq(float v, float delta) {
  if (fabsf(v) > delta) return (v > 0.f) ? (signed char)1 : (signed char)-1;
  return (signed char)0;
}

// fused: ternary-quantize weights (int8 {-1,0,1}) AND accumulate alpha partials
__global__ __launch_bounds__(256) void w_maskquant(
    const float* w0, const float* w1, const float* w2, const float* w3,
    const float* stats, float* part2, signed char* tern)
{
  int wi = blockIdx.y;
  const float4* w4 = (const float4*)pick_w(w0, w1, w2, w3, wi);
  float delta = stats[wi];
  char4* out = (char4*)(tern + (size_t)wi * WN);
  float s = 0.f, cnt = 0.f;
  for (int i = blockIdx.x * 256 + threadIdx.x; i < WN / 4; i += 1024 * 256) {
    float4 v = w4[i];
    char4 o;
    float a;
    a = fabsf(v.x); if (a > delta) { s += a; cnt += 1.f; } o.x = tq(v.x, delta);
    a = fabsf(v.y); if (a > delta) { s += a; cnt += 1.f; } o.y = tq(v.y, delta);
    a = fabsf(v.z); if (a > delta) { s += a; cnt += 1.f; } o.z = tq(v.z, delta);
    a = fabsf(v.w); if (a > delta) { s += a; cnt += 1.f; } o.w = tq(v.w, delta);
    out[i] = o;
  }
  __shared__ float red[256];
  float ts = blockReduceSum(s, red);
  float tc = blockReduceSum(cnt, red);
  if (threadIdx.x == 0) {
    part2[((size_t)blockIdx.y * 1024 + blockIdx.x) * 2]     = ts;
    part2[((size_t)blockIdx.y * 1024 + blockIdx.x) * 2 + 1] = tc;
  }
}

__global__ __launch_bounds__(256) void w_alpha_final(const float* part2, float* stats)
{
  float s = 0.f, c = 0.f;
  for (int i = threadIdx.x; i < 1024; i += 256) {
    s += part2[((size_t)blockIdx.x * 1024 + i) * 2];
    c += part2[((size_t)blockIdx.x * 1024 + i) * 2 + 1];
  }
  __shared__ float red[256];
  float ts = blockReduceSum(s, red);
  float tc = blockReduceSum(c, red);
  if (threadIdx.x == 0) stats[4 + blockIdx.x] = ts / fmaxf(tc, 1.f);
}

// ---------------- LN kernels: one WAVE per row, shuffle-only reductions, no atomics --------
// block = 4 waves = 4 rows; lane holds 32 elems (8x float4 at lane*4 + j*256).
__global__ __launch_bounds__(256) void ln_absmax3(
    const float* __restrict__ x,
    const float* __restrict__ g0, const float* __restrict__ b0,
    const float* __restrict__ g1, const float* __restrict__ b1,
    const float* __restrict__ g2, const float* __restrict__ b2,
    float* __restrict__ pmax)     // [3][NROWS] per-row maxima
{
  const int lane = threadIdx.x & 63;
  const int row = blockIdx.x * 4 + (threadIdx.x >> 6);
  const float* xr = x + (size_t)row * DIM;
  float4 a[8];
  float s = 0.f, sq = 0.f;
  #pragma unroll
  for (int j = 0; j < 8; ++j) {
    a[j] = *(const float4*)(xr + j * 256 + lane * 4);
    s  += a[j].x + a[j].y + a[j].z + a[j].w;
    sq += a[j].x*a[j].x + a[j].y*a[j].y + a[j].z*a[j].z + a[j].w*a[j].w;
  }
  s = wredSum(s); sq = wredSum(sq);
  float mu = s * (1.f / DIM);
  float var = sq * (1.f / DIM) - mu * mu;
  float rstd = 1.f / sqrtf(var + 1e-5f);
  const float* gs[3] = {g0, g1, g2};
  const float* bs[3] = {b0, b1, b2};
  #pragma unroll
  for (int p = 0; p < 3; ++p) {
    float m = 0.f;
    #pragma unroll
    for (int j = 0; j < 8; ++j) {
      float4 gg = *(const float4*)(gs[p] + j * 256 + lane * 4);
      float4 bb = *(const float4*)(bs[p] + j * 256 + lane * 4);
      m = fmaxf(m, fabsf((a[j].x - mu) * rstd * gg.x + bb.x));
      m = fmaxf(m, fabsf((a[j].y - mu) * rstd * gg.y + bb.y));
      m = fmaxf(m, fabsf((a[j].z - mu) * rstd * gg.z + bb.z));
      m = fmaxf(m, fabsf((a[j].w - mu) * rstd * gg.w + bb.w));
    }
    m = wredMax(m);
    if (lane == 0) pmax[(size_t)p * NROWS + row] = m;
  }
}

// one block per projection: reduce NROWS partial maxima -> ambits[p] (direct write, no atomic)
__global__ __launch_bounds__(256) void absmax_final(
    const float* __restrict__ pmax, unsigned* __restrict__ ambits)
{
  const float* src = pmax + (size_t)blockIdx.x * NROWS;
  float m = 0.f;
  for (int i = threadIdx.x; i < NROWS; i += 256) m = fmaxf(m, src[i]);
  m = wredMax(m);
  __shared__ float red[4];
  if ((threadIdx.x & 63) == 0) red[threadIdx.x >> 6] = m;
  __syncthreads();
  if (threadIdx.x == 0)
    ambits[blockIdx.x] = __float_as_uint(fmaxf(fmaxf(red[0], red[1]), fmaxf(red[2], red[3])));
}

__global__ __launch_bounds__(256) void ln_quant3(
    const float* __restrict__ x,
    const float* __restrict__ g0, const float* __restrict__ b0,
    const float* __restrict__ g1, const float* __restrict__ b1,
    const float* __restrict__ g2, const float* __restrict__ b2,
    const unsigned* __restrict__ ambits,
    signed char* __restrict__ xq0, signed char* __restrict__ xq1,
    signed char* __restrict__ xq2)
{
  const int lane = threadIdx.x & 63;
  const int row = blockIdx.x * 4 + (threadIdx.x >> 6);
  const float* xr = x + (size_t)row * DIM;
  float4 a[8];
  float s = 0.f, sq = 0.f;
  #pragma unroll
  for (int j = 0; j < 8; ++j) {
    a[j] = *(const float4*)(xr + j * 256 + lane * 4);
    s  += a[j].x + a[j].y + a[j].z + a[j].w;
    sq += a[j].x*a[j].x + a[j].y*a[j].y + a[j].z*a[j].z + a[j].w*a[j].w;
  }
  s = wredSum(s); sq = wredSum(sq);
  float mu = s * (1.f / DIM);
  float var = sq * (1.f / DIM) - mu * mu;
  float rstd = 1.f / sqrtf(var + 1e-5f);
  const float* gs[3] = {g0, g1, g2};
  const float* bs[3] = {b0, b1, b2};
  signed char* outs[3] = {xq0, xq1, xq2};
  #pragma unroll
  for (int p = 0; p < 3; ++p) {
    float sc = 127.f / fmaxf(__uint_as_float(ambits[p]), 1e-5f);
    #pragma unroll
    for (int j = 0; j < 8; ++j) {
      float4 gg = *(const float4*)(gs[p] + j * 256 + lane * 4);
      float4 bb = *(const float4*)(bs[p] + j * 256 + lane * 4);
      float y0 = (a[j].x - mu) * rstd * gg.x + bb.x;
      float y1 = (a[j].y - mu) * rstd * gg.y + bb.y;
      float y2 = (a[j].z - mu) * rstd * gg.z + bb.z;
      float y3 = (a[j].w - mu) * rstd * gg.w + bb.w;
      char4 q;
      q.x = (signed char)(int)fminf(fmaxf(rintf(y0 * sc), -128.f), 127.f);
      q.y = (signed char)(int)fminf(fmaxf(rintf(y1 * sc), -128.f), 127.f);
      q.z = (signed char)(int)fminf(fmaxf(rintf(y2 * sc), -128.f), 127.f);
      q.w = (signed char)(int)fminf(fmaxf(rintf(y3 * sc), -128.f), 127.f);
      *(char4*)(outs[p] + (size_t)row * DIM + j * 256 + lane * 4) = q;
    }
  }
}

// ---------------- single-tensor LN (o projection), wave-per-row ----------------
// MODE 0: per-row absmax -> pmax (then absmax_final). MODE 1: quantize with ambits.
template<int MODE>
__global__ __launch_bounds__(256) void ln_kernel(
    const float* __restrict__ x, const float* __restrict__ g, const float* __restrict__ bias,
    const unsigned* __restrict__ ambits, float* __restrict__ pmax,
    signed char* __restrict__ xq)
{
  const int lane = threadIdx.x & 63;
  const int row = blockIdx.x * 4 + (threadIdx.x >> 6);
  const float* xr = x + (size_t)row * DIM;
  float4 a[8];
  float s = 0.f, sq = 0.f;
  #pragma unroll
  for (int j = 0; j < 8; ++j) {
    a[j] = *(const float4*)(xr + j * 256 + lane * 4);
    s  += a[j].x + a[j].y + a[j].z + a[j].w;
    sq += a[j].x*a[j].x + a[j].y*a[j].y + a[j].z*a[j].z + a[j].w*a[j].w;
  }
  s = wredSum(s); sq = wredSum(sq);
  float mu = s * (1.f / DIM);
  float var = sq * (1.f / DIM) - mu * mu;
  float rstd = 1.f / sqrtf(var + 1e-5f);
  if (MODE == 0) {
    float m = 0.f;
    #pragma unroll
    for (int j = 0; j < 8; ++j) {
      float4 gg = *(const float4*)(g + j * 256 + lane * 4);
      float4 bb = *(const float4*)(bias + j * 256 + lane * 4);
      m = fmaxf(m, fabsf((a[j].x - mu) * rstd * gg.x + bb.x));
      m = fmaxf(m, fabsf((a[j].y - mu) * rstd * gg.y + bb.y));
      m = fmaxf(m, fabsf((a[j].z - mu) * rstd * gg.z + bb.z));
      m = fmaxf(m, fabsf((a[j].w - mu) * rstd * gg.w + bb.w));
    }
    m = wredMax(m);
    if (lane == 0) pmax[row] = m;
  } else {
    float sc = 127.f / fmaxf(__uint_as_float(*ambits), 1e-5f);
    #pragma unroll
    for (int j = 0; j < 8; ++j) {
      float4 gg = *(const float4*)(g + j * 256 + lane * 4);
      float4 bb = *(const float4*)(bias + j * 256 + lane * 4);
      float y0 = (a[j].x - mu) * rstd * gg.x + bb.x;
      float y1 = (a[j].y - mu) * rstd * gg.y + bb.y;
      float y2 = (a[j].z - mu) * rstd * gg.z + bb.z;
      float y3 = (a[j].w - mu) * rstd * gg.w + bb.w;
      char4 q;
      q.x = (signed char)(int)fminf(fmaxf(rintf(y0 * sc), -128.f), 127.f);
      q.y = (signed char)(int)fminf(fmaxf(rintf(y1 * sc), -128.f), 127.f);
      q.z = (signed char)(int)fminf(fmaxf(rintf(y2 * sc), -128.f), 127.f);
      q.w = (signed char)(int)fminf(fmaxf(rintf(y3 * sc), -128.f), 127.f);
      *(char4*)(xq + (size_t)row * DIM + j * 256 + lane * 4) = q;
    }
  }
}

// ---------------- int8 quantized GEMM, m97 structure: global_load_lds staging ----------------
// A: int8 activations [-128,127]; Bt: ternary int8 {-1,0,1} (row = output column).
// mfma_i32_16x16x64_i8: 2x K per instr vs bf16, exact i32 accumulation.
// OMODE: 0 = fp32 out, 1 = fp16 out
template<int OMODE>
__global__ __launch_bounds__(256) void gemm_bt(
    const signed char* __restrict__ A, const signed char* __restrict__ Bt,
    void* __restrict__ Cp0, const float* __restrict__ stats, int wi)
{
  const int tid = threadIdx.x;
  const int lane = tid & 63;
  const int w = tid >> 6;
  const int wm = w >> 1, wn = w & 1;
  const int quad = lane >> 4, l16 = lane & 15;
  const int bm = blockIdx.x * 128, bn = blockIdx.y * 128;

  // unpadded, contiguous row-major [128][128] i8 — required by global_load_lds lane scatter
  __shared__ __align__(16) signed char As[128 * 128];
  __shared__ __align__(16) signed char Bs[128 * 128];

  // per-chunk geometry: chunk c (1 KiB) = rows c*8..c*8+8; lane i -> row c*8+(i>>3), col (i&7)*16
  const int srow_off = lane >> 3;        // 0..7
  const int scol     = (lane & 7) * 16;  // bytes

  intx4 acc[4][4];
  #pragma unroll
  for (int i = 0; i < 4; ++i)
    #pragma unroll
    for (int j = 0; j < 4; ++j) acc[i][j] = {0, 0, 0, 0};

  for (int k0 = 0; k0 < DIM; k0 += 128) {
    #pragma unroll
    for (int i = 0; i < 4; ++i) {
      int c = i * 4 + w;                 // wave-uniform chunk id, 16 chunks = 128 rows
      int row = c * 8 + srow_off;
      gload_lds16(A  + (size_t)(bm + row) * DIM + k0 + scol, &As[c * 1024]);
      gload_lds16(Bt + (size_t)(bn + row) * DIM + k0 + scol, &Bs[c * 1024]);
    }
    __syncthreads();
    #pragma unroll
    for (int kc = 0; kc < 2; ++kc) {
      intx4 af[4], bf[4];
      #pragma unroll
      for (int i = 0; i < 4; ++i)
        af[i] = *(const intx4*)&As[(wm * 64 + i * 16 + l16) * 128 + kc * 64 + quad * 16];
      #pragma unroll
      for (int j = 0; j < 4; ++j)
        bf[j] = *(const intx4*)&Bs[(wn * 64 + j * 16 + l16) * 128 + kc * 64 + quad * 16];
      #pragma unroll
      for (int i = 0; i < 4; ++i)
        #pragma unroll
        for (int j = 0; j < 4; ++j)
          acc[i][j] = __builtin_amdgcn_mfma_i32_16x16x64_i8(af[i], bf[j], acc[i][j], 0, 0, 0);
    }
    __syncthreads();
  }

  const unsigned* am = (const unsigned*)(stats + 8);
  float scale = stats[4 + wi] * fmaxf(__uint_as_float(am[wi]), 1e-5f) * (1.f / 127.f);
  #pragma unroll
  for (int i = 0; i < 4; ++i)
    #pragma unroll
    for (int j = 0; j < 4; ++j)
      #pragma unroll
      for (int r = 0; r < 4; ++r) {
        int m = bm + wm * 64 + i * 16 + quad * 4 + r;
        int n = bn + wn * 64 + j * 16 + l16;
        size_t idx = (size_t)m * DIM + n;
        float v = (float)acc[i][j][r] * scale;
        if (OMODE == 0) ((float*)Cp0)[idx] = v;
        else            ((unsigned short*)Cp0)[idx] = f2h(v);
      }
}

// ---------------- rope (fp16; angle = head_index * inv; q gets (1/sqrt(128))*log2e folded) ----------------
__global__ __launch_bounds__(256) void rope_kernel(unsigned short* q, unsigned short* k)
{
  const float SC = 0.12751741769011063f;   // (1/sqrt(128)) * log2(e)
  int idx = blockIdx.x * 256 + threadIdx.x;
  int p = idx & 63;
  int h = (idx >> 6) & (HEADS - 1);
  int r = idx >> 10;
  float inv = exp2f((float)p * -0.20762050593046f);  // 10000^(-p/64)
  float ang = (float)h * inv;
  float sn, cs;
  __sincosf(ang, &sn, &cs);
  size_t base = (size_t)r * DIM + h * HDIM + 2 * p;
  {
    float a = h2f(q[base]), b = h2f(q[base + 1]);
    q[base]     = f2h((a * cs - b * sn) * SC);
    q[base + 1] = f2h((a * sn + b * cs) * SC);
  }
  {
    float a = h2f(k[base]), b = h2f(k[base + 1]);
    k[base]     = f2h(a * cs - b * sn);
    k[base + 1] = f2h(a * sn + b * cs);
  }
}

// ---------------- transpose V: [b*S+s][h*128+d] -> [(b*16+h)*128+d][s] ----------------
__global__ __launch_bounds__(256) void transpose_v(
    const unsigned short* __restrict__ vin, unsigned short* __restrict__ vout)
{
  __shared__ __align__(16) unsigned short t[64][72];
  const int tid = threadIdx.x;
  const int c0 = blockIdx.x * 64, r0 = blockIdx.y * 64;
  #pragma unroll
  for (int c = 0; c < 2; ++c) {
    int idx = c * 256 + tid;
    int row = idx >> 3, cb = (idx & 7) << 3;
    *(uint4*)&t[row][cb] = *(const uint4*)(vin + (size_t)(r0 + row) * DIM + c0 + cb);
  }
  __syncthreads();
  const int b = r0 >> 11, s0 = r0 & (SEQ - 1);
  const int h = c0 >> 7, d0 = c0 & (HDIM - 1);
  #pragma unroll
  for (int c = 0; c < 2; ++c) {
    int idx = c * 256 + tid;
    int drow = idx >> 3, sb = (idx & 7) << 3;
    union { unsigned short u[8]; uint4 v; } pk;
    #pragma unroll
    for (int j = 0; j < 8; ++j) pk.u[j] = t[sb + j][drow];
    *(uint4*)(vout + (size_t)((b * HEADS + h) * HDIM + d0 + drow) * SEQ + s0 + sb) = pk.v;
  }
}

// ---------------- flash attention: QBLK=64, 4 blocks/CU, gload_lds staging ----------------
// Q pre-scaled by (1/sqrt(128))*log2(e); softmax in exp2 domain; T13 defer-rescale.
// No register K/V staging — global_load_lds DMA with PRE-SWIZZLED global source addresses
// (rule #21: LDS dest linear, source carries the involution). XCD-chunked remap: id%8 = XCD.
__global__ __launch_bounds__(256, 4) void flash_attn(
    const unsigned short* __restrict__ qf, const unsigned short* __restrict__ kf,
    const unsigned short* __restrict__ vt, float* __restrict__ o)
{
  const int tid = threadIdx.x;
  const int lane = tid & 63;
  const int w = tid >> 6;
  const int quad = lane >> 4;
  const int l16 = lane & 15;
  // XCD-chunked decode: xcd = id&7, slot = id>>3; bh = xcd*4 + slot/32, qt = slot%32
  const int L = blockIdx.x;
  const int slot = L >> 3;
  const int bh = ((L & 7) << 2) | (slot >> 5);
  const int qt = slot & 31;
  const int b = bh >> 4;
  const int h = bh & 15;

  __shared__ __align__(16) char Ks[64 * 256];     // [key t][d] halves; LDS[d]=Gtile[d^((d>>8&7)<<4)]
  __shared__ __align__(16) char Vs[128 * 128];    // [d][t] halves;    LDS[d]=Gtile[d^((d>>7&7)<<4)]
  __shared__ __align__(16) char Ps[4][16 * 128];  // per-wave [q][t] halves, swizzled (8192 B)

  // Q fragment (B-operand): wave owns 16 q-rows
  const size_t qbase = ((size_t)(b * SEQ + qt * 64 + w * 16 + l16)) * DIM + h * HDIM;
  short8 qa[4];
  #pragma unroll
  for (int kc = 0; kc < 4; ++kc)
    qa[kc] = *(const short8*)(qf + qbase + kc * 32 + quad * 8);

  float m_q = -INFINITY;
  float l_q = 0.f;
  floatx4 accO[8];                      // O^T: rows d=dt*16+quad*4+r, col q = l16
  #pragma unroll
  for (int i = 0; i < 8; ++i) accO[i] = {0.f, 0.f, 0.f, 0.f};

  const char* kg = (const char*)(kf + (size_t)(b * SEQ) * DIM + h * HDIM);
  const char* vg = (const char*)(vt + (size_t)bh * HDIM * SEQ);

  // per-lane pre-swizzled source offsets (bytes) for this wave's 4 chunks of K and V.
  // chunk c covers LDS bytes [c*1024, c*1024+1024); lane i lands at c*1024 + i*16.
  // K: dest d -> row r=d>>8, col cb=(d&255)^((r&7)<<4); source = r*(DIM*2) + cb.
  // V: dest d -> row r=d>>7, col cb=(d&127)^((r&7)<<4); source = r*(SEQ*2) + cb.
  int koff[4], voff[4];
  #pragma unroll
  for (int j = 0; j < 4; ++j) {
    int c = w * 4 + j;
    int rK = c * 4 + (lane >> 4);
    koff[j] = rK * (DIM * 2) + (((lane & 15) * 16) ^ ((rK & 7) << 4));
    int rV = c * 8 + (lane >> 3);
    voff[j] = rV * (SEQ * 2) + (((lane & 7) * 16) ^ ((rV & 7) << 4));
  }

  for (int kt = 0; kt < SEQ / 64; ++kt) {
    __syncthreads();                    // prior tile's LDS reads complete
    const char* kgb = kg + (size_t)kt * 64 * DIM * 2;   // key rows advance
    const char* vgb = vg + (size_t)kt * 128;            // value cols advance (bytes)
    #pragma unroll
    for (int j = 0; j < 4; ++j) {
      int c = w * 4 + j;
      gload_lds16(kgb + koff[j], &Ks[c * 1024]);
      gload_lds16(vgb + voff[j], &Vs[c * 1024]);
    }
    asm volatile("s_waitcnt vmcnt(0)" ::: "memory");
    __syncthreads();

    // S^T = K Q'^T : lane q = l16, keys t = jt*16 + quad*4 + r
    float sreg[4][4];
    __builtin_amdgcn_s_setprio(1);
    #pragma unroll
    for (int jt = 0; jt < 4; ++jt) {
      floatx4 a0 = {0.f, 0.f, 0.f, 0.f};
      #pragma unroll
      for (int kc = 0; kc < 4; ++kc) {
        int kr = jt * 16 + l16;
        short8 kb = *(const short8*)&Ks[(kr * 256 + kc * 64 + quad * 16) ^ ((kr & 7) << 4)];
        a0 = __builtin_amdgcn_mfma_f32_16x16x32_f16(
            __builtin_bit_cast(half8, kb), __builtin_bit_cast(half8, qa[kc]), a0, 0, 0, 0);
      }
      #pragma unroll
      for (int r = 0; r < 4; ++r) sreg[jt][r] = a0[r];
    }
    __builtin_amdgcn_s_setprio(0);

    // per-lane online softmax (exp2 domain); T13 defer-rescale
    float mx = sreg[0][0];
    #pragma unroll
    for (int jt = 0; jt < 4; ++jt)
      #pragma unroll
      for (int r = 0; r < 4; ++r) mx = fmaxf(mx, sreg[jt][r]);
    mx = fmaxf(mx, __shfl_xor(mx, 16));
    mx = fmaxf(mx, __shfl_xor(mx, 32));
    int need = !__all(mx <= m_q + 8.f);   // wave-uniform
    float mnew, alpha;
    if (need) {
      mnew = fmaxf(m_q, mx);
      alpha = exp2f(m_q - mnew);
      m_q = mnew;
    } else {
      mnew = m_q;
      alpha = 1.f;
    }
    float ssum = 0.f;
    #pragma unroll
    for (int jt = 0; jt < 4; ++jt) {
      ushort4 pk;
      float p0 = exp2f(sreg[jt][0] - mnew);
      float p1 = exp2f(sreg[jt][1] - mnew);
      float p2 = exp2f(sreg[jt][2] - mnew);
      float p3 = exp2f(sreg[jt][3] - mnew);
      pk.x = f2h(p0); pk.y = f2h(p1); pk.z = f2h(p2); pk.w = f2h(p3);
      ssum += (p0 + p1) + (p2 + p3);
      *(ushort4*)&Ps[w][(l16 * 128 + jt * 32 + quad * 8) ^ ((l16 & 7) << 4)] = pk;
    }
    ssum += __shfl_xor(ssum, 16);
    ssum += __shfl_xor(ssum, 32);
    l_q = l_q * alpha + ssum;
    if (need) {
      #pragma unroll
      for (int dt = 0; dt < 8; ++dt)
        #pragma unroll
        for (int r = 0; r < 4; ++r) accO[dt][r] *= alpha;
    }

    // O^T = O^T + V^T P^T
    __builtin_amdgcn_s_setprio(1);
    #pragma unroll
    for (int kc = 0; kc < 2; ++kc) {
      short8 pf = *(const short8*)&Ps[w][(l16 * 128 + kc * 64 + quad * 16) ^ ((l16 & 7) << 4)];
      #pragma unroll
      for (int dt = 0; dt < 8; ++dt) {
        int vr = dt * 16 + l16;
        short8 vf = *(const short8*)&Vs[(vr * 128 + kc * 64 + quad * 16) ^ ((vr & 7) << 4)];
        accO[dt] = __builtin_amdgcn_mfma_f32_16x16x32_f16(
            __builtin_bit_cast(half8, vf), __builtin_bit_cast(half8, pf), accO[dt], 0, 0, 0);
      }
    }
    __builtin_amdgcn_s_setprio(0);
  }

  // epilogue: float4 stores, 16B per lane
  float invl = 1.0f / l_q;
  const size_t obase = (size_t)(b * SEQ + qt * 64 + w * 16 + l16) * DIM + h * HDIM;
  #pragma unroll
  for (int dt = 0; dt < 8; ++dt) {
    float4 ov;
    ov.x = accO[dt][0] * invl; ov.y = accO[dt][1] * invl;
    ov.z = accO[dt][2] * invl; ov.w = accO[dt][3] * invl;
    *(float4*)(o + obase + dt * 16 + quad * 4) = ov;
  }
}

// ---------------- host ----------------
extern "C" void kernel_launch(void* const* d_in, const int* in_sizes, int n_in,
                              void* d_out, int out_size, void* d_ws, size_t ws_size,
                              hipStream_t stream)
{
  (void)in_sizes; (void)n_in; (void)out_size; (void)ws_size;
  const float* x = (const float*)d_in[0];
  const float* w[4]; const float* g[4]; const float* bb[4];
  for (int i = 0; i < 4; ++i) {
    w[i]  = (const float*)d_in[1 + 3 * i];
    g[i]  = (const float*)d_in[2 + 3 * i];
    bb[i] = (const float*)d_in[3 + 3 * i];
  }

  char* base = (char*)d_ws;
  size_t off = 0;
  auto alloc = [&](size_t bytes) {
    char* p = base + off;
    off += (bytes + 255) & ~(size_t)255;
    return p;
  };
  const size_t ACTH = (size_t)NROWS * DIM * 2;  // 16-bit activation buffer (16 MB)
  const size_t ACT8 = (size_t)NROWS * DIM;      // 8-bit activation buffer (8 MB)
  float* stats          = (float*)alloc(64);
  float* part1          = (float*)alloc(4 * 1024 * sizeof(float));
  float* part2          = (float*)alloc(4 * 1024 * 2 * sizeof(float));
  float* pmax           = (float*)alloc((size_t)4 * NROWS * sizeof(float));
  signed char* tern     = (signed char*)alloc((size_t)4 * WN);
  signed char* xq0      = (signed char*)alloc(ACT8);
  signed char* xq1      = (signed char*)alloc(ACT8);
  signed char* xq2      = (signed char*)alloc(ACT8);
  unsigned short* qh    = (unsigned short*)alloc(ACTH);
  unsigned short* kh    = (unsigned short*)alloc(ACTH);
  unsigned short* vb    = (unsigned short*)alloc(ACTH);
  unsigned short* vtb   = (unsigned short*)alloc(ACTH);
  float* oat            = (float*)alloc((size_t)NROWS * DIM * sizeof(float));
  signed char* xqo = xq0;              // overlay: xq0 dead after the q GEMM
  unsigned* ambits = (unsigned*)(stats + 8);

  hipMemsetAsync(stats, 0, 64, stream);

  dim3 b256(256);
  w_abs_partial<<<dim3(1024, 4), b256, 0, stream>>>(w[0], w[1], w[2], w[3], part1);
  w_delta_final<<<4, b256, 0, stream>>>(part1, stats);
  w_maskquant<<<dim3(1024, 4), b256, 0, stream>>>(w[0], w[1], w[2], w[3], stats, part2, tern);
  w_alpha_final<<<4, b256, 0, stream>>>(part2, stats);

  ln_absmax3<<<NROWS / 4, b256, 0, stream>>>(x, g[0], bb[0], g[1], bb[1], g[2], bb[2], pmax);
  absmax_final<<<3, b256, 0, stream>>>(pmax, ambits);
  ln_quant3<<<NROWS / 4, b256, 0, stream>>>(x, g[0], bb[0], g[1], bb[1], g[2], bb[2], ambits,
                                            xq0, xq1, xq2);

  dim3 ggrid(NROWS / 128, DIM / 128);
  gemm_bt<1><<<ggrid, b256, 0, stream>>>(xq0, tern + (size_t)0 * WN, qh, stats, 0);
  gemm_bt<1><<<ggrid, b256, 0, stream>>>(xq1, tern + (size_t)1 * WN, kh, stats, 1);
  gemm_bt<1><<<ggrid, b256, 0, stream>>>(xq2, tern + (size_t)2 * WN, vb, stats, 2);

  rope_kernel<<<NROWS * 1024 / 256, b256, 0, stream>>>(qh, kh);
  transpose_v<<<dim3(DIM / 64, NROWS / 64), b256, 0, stream>>>(vb, vtb);
  flash_attn<<<dim3(32 * 32), b256, 0, stream>>>(qh, kh, vtb, oat);

  ln_kernel<0><<<NROWS / 4, b256, 0, stream>>>(oat, g[3], bb[3], nullptr,
                                               pmax + (size_t)3 * NROWS, nullptr);
  absmax_final<<<1, b256, 0, stream>>>(pmax + (size_t)3 * NROWS, ambits + 3);
  ln_kernel<1><<<NROWS / 4, b256, 0, stream>>>(oat, g[3], bb[3], ambits + 3, nullptr, xqo);
  gemm_bt<0><<<ggrid, b256, 0, stream>>>(xqo, tern + (size_t)3 * WN, (float*)d_out, stats, 3);
}

// Round 8
// 442.624 us; speedup vs baseline: 2.1510x; 1.0425x over previous
//
#include <hip/hip_runtime.h>
#include <math.h>

#define DIM 2048
#define NROWS 4096            // B*S
#define WN (DIM*DIM)
#define HEADS 16
#define HDIM 128
#define SEQ 2048

typedef __attribute__((ext_vector_type(8))) short short8;
typedef __attribute__((ext_vector_type(8))) _Float16 half8;
typedef __attribute__((ext_vector_type(4))) float floatx4;
typedef __attribute__((ext_vector_type(4))) int intx4;

__device__ __forceinline__ unsigned short f2h(float f) {
  _Float16 h = (_Float16)f;
  return __builtin_bit_cast(unsigned short, h);
}
__device__ __forceinline__ float h2f(unsigned short u) {
  _Float16 h = __builtin_bit_cast(_Float16, u);
  return (float)h;
}

// async global->LDS, 16B per lane; lds base must be wave-uniform (HW scatters lane i at +i*16)
__device__ __forceinline__ void gload_lds16(const void* g, void* l) {
  __builtin_amdgcn_global_load_lds(
      (const __attribute__((address_space(1))) unsigned int*)g,
      (__attribute__((address_space(3))) unsigned int*)l, 16, 0, 0);
}

__device__ __forceinline__ float wredSum(float v) {
  #pragma unroll
  for (int o = 1; o < 64; o <<= 1) v += __shfl_xor(v, o);
  return v;
}
__device__ __forceinline__ float wredMax(float v) {
  #pragma unroll
  for (int o = 1; o < 64; o <<= 1) v = fmaxf(v, __shfl_xor(v, o));
  return v;
}

__device__ __forceinline__ float blockReduceSum(float v, float* red) {
  int tid = threadIdx.x;
  red[tid] = v; __syncthreads();
  for (int s = 128; s > 0; s >>= 1) {
    if (tid < s) red[tid] += red[tid + s];
    __syncthreads();
  }
  float r = red[0]; __syncthreads();
  return r;
}

__device__ __forceinline__ const float* pick_w(const float* a, const float* b,
                                               const float* c, const float* d, int i) {
  return i == 0 ? a : i == 1 ? b : i == 2 ? c : d;
}

// ---------------- weight stats ----------------
__global__ __launch_bounds__(256) void w_abs_partial(
    const float* w0, const float* w1, const float* w2, const float* w3, float* part)
{
  const float4* w4 = (const float4*)pick_w(w0, w1, w2, w3, blockIdx.y);
  float s = 0.f;
  for (int i = blockIdx.x * 256 + threadIdx.x; i < WN / 4; i += 1024 * 256) {
    float4 v = w4[i];
    s += fabsf(v.x) + fabsf(v.y) + fabsf(v.z) + fabsf(v.w);
  }
  __shared__ float red[256];
  float t = blockReduceSum(s, red);
  if (threadIdx.x == 0) part[blockIdx.y * 1024 + blockIdx.x] = t;
}

__global__ __launch_bounds__(256) void w_delta_final(const float* part, float* stats)
{
  float s = 0.f;
  for (int i = threadIdx.x; i < 1024; i += 256) s += part[blockIdx.x * 1024 + i];
  __shared__ float red[256];
  float t = blockReduceSum(s, red);
  if (threadIdx.x == 0) stats[blockIdx.x] = 0.7f * (t / (float)WN);
}

__device__ __forceinline__ signed char tq(float v, float delta) {
  if (fabsf(v) > delta) return (v > 0.f) ? (signed char)1 : (signed char)-1;
  return (signed char)0;
}

// fused: ternary-quantize weights (int8 {-1,0,1}) AND accumulate alpha partials
__global__ __launch_bounds__(256) void w_maskquant(
    const float* w0, const float* w1, const float* w2, const float* w3,
    const float* stats, float* part2, signed char* tern)
{
  int wi = blockIdx.y;
  const float4* w4 = (const float4*)pick_w(w0, w1, w2, w3, wi);
  float delta = stats[wi];
  char4* out = (char4*)(tern + (size_t)wi * WN);
  float s = 0.f, cnt = 0.f;
  for (int i = blockIdx.x * 256 + threadIdx.x; i < WN / 4; i += 1024 * 256) {
    float4 v = w4[i];
    char4 o;
    float a;
    a = fabsf(v.x); if (a > delta) { s += a; cnt += 1.f; } o.x = tq(v.x, delta);
    a = fabsf(v.y); if (a > delta) { s += a; cnt += 1.f; } o.y = tq(v.y, delta);
    a = fabsf(v.z); if (a > delta) { s += a; cnt += 1.f; } o.z = tq(v.z, delta);
    a = fabsf(v.w); if (a > delta) { s += a; cnt += 1.f; } o.w = tq(v.w, delta);
    out[i] = o;
  }
  __shared__ float red[256];
  float ts = blockReduceSum(s, red);
  float tc = blockReduceSum(cnt, red);
  if (threadIdx.x == 0) {
    part2[((size_t)blockIdx.y * 1024 + blockIdx.x) * 2]     = ts;
    part2[((size_t)blockIdx.y * 1024 + blockIdx.x) * 2 + 1] = tc;
  }
}

__global__ __launch_bounds__(256) void w_alpha_final(const float* part2, float* stats)
{
  float s = 0.f, c = 0.f;
  for (int i = threadIdx.x; i < 1024; i += 256) {
    s += part2[((size_t)blockIdx.x * 1024 + i) * 2];
    c += part2[((size_t)blockIdx.x * 1024 + i) * 2 + 1];
  }
  __shared__ float red[256];
  float ts = blockReduceSum(s, red);
  float tc = blockReduceSum(c, red);
  if (threadIdx.x == 0) stats[4 + blockIdx.x] = ts / fmaxf(tc, 1.f);
}

// ---------------- LN kernels: one WAVE per row, shuffle-only reductions, no atomics --------
__global__ __launch_bounds__(256) void ln_absmax3(
    const float* __restrict__ x,
    const float* __restrict__ g0, const float* __restrict__ b0,
    const float* __restrict__ g1, const float* __restrict__ b1,
    const float* __restrict__ g2, const float* __restrict__ b2,
    float* __restrict__ pmax)     // [3][NROWS] per-row maxima
{
  const int lane = threadIdx.x & 63;
  const int row = blockIdx.x * 4 + (threadIdx.x >> 6);
  const float* xr = x + (size_t)row * DIM;
  float4 a[8];
  float s = 0.f, sq = 0.f;
  #pragma unroll
  for (int j = 0; j < 8; ++j) {
    a[j] = *(const float4*)(xr + j * 256 + lane * 4);
    s  += a[j].x + a[j].y + a[j].z + a[j].w;
    sq += a[j].x*a[j].x + a[j].y*a[j].y + a[j].z*a[j].z + a[j].w*a[j].w;
  }
  s = wredSum(s); sq = wredSum(sq);
  float mu = s * (1.f / DIM);
  float var = sq * (1.f / DIM) - mu * mu;
  float rstd = 1.f / sqrtf(var + 1e-5f);
  const float* gs[3] = {g0, g1, g2};
  const float* bs[3] = {b0, b1, b2};
  #pragma unroll
  for (int p = 0; p < 3; ++p) {
    float m = 0.f;
    #pragma unroll
    for (int j = 0; j < 8; ++j) {
      float4 gg = *(const float4*)(gs[p] + j * 256 + lane * 4);
      float4 bb = *(const float4*)(bs[p] + j * 256 + lane * 4);
      m = fmaxf(m, fabsf((a[j].x - mu) * rstd * gg.x + bb.x));
      m = fmaxf(m, fabsf((a[j].y - mu) * rstd * gg.y + bb.y));
      m = fmaxf(m, fabsf((a[j].z - mu) * rstd * gg.z + bb.z));
      m = fmaxf(m, fabsf((a[j].w - mu) * rstd * gg.w + bb.w));
    }
    m = wredMax(m);
    if (lane == 0) pmax[(size_t)p * NROWS + row] = m;
  }
}

// one block per projection: reduce NROWS partial maxima -> ambits[p] (direct write, no atomic)
__global__ __launch_bounds__(256) void absmax_final(
    const float* __restrict__ pmax, unsigned* __restrict__ ambits)
{
  const float* src = pmax + (size_t)blockIdx.x * NROWS;
  float m = 0.f;
  for (int i = threadIdx.x; i < NROWS; i += 256) m = fmaxf(m, src[i]);
  m = wredMax(m);
  __shared__ float red[4];
  if ((threadIdx.x & 63) == 0) red[threadIdx.x >> 6] = m;
  __syncthreads();
  if (threadIdx.x == 0)
    ambits[blockIdx.x] = __float_as_uint(fmaxf(fmaxf(red[0], red[1]), fmaxf(red[2], red[3])));
}

__global__ __launch_bounds__(256) void ln_quant3(
    const float* __restrict__ x,
    const float* __restrict__ g0, const float* __restrict__ b0,
    const float* __restrict__ g1, const float* __restrict__ b1,
    const float* __restrict__ g2, const float* __restrict__ b2,
    const unsigned* __restrict__ ambits,
    signed char* __restrict__ xq0, signed char* __restrict__ xq1,
    signed char* __restrict__ xq2)
{
  const int lane = threadIdx.x & 63;
  const int row = blockIdx.x * 4 + (threadIdx.x >> 6);
  const float* xr = x + (size_t)row * DIM;
  float4 a[8];
  float s = 0.f, sq = 0.f;
  #pragma unroll
  for (int j = 0; j < 8; ++j) {
    a[j] = *(const float4*)(xr + j * 256 + lane * 4);
    s  += a[j].x + a[j].y + a[j].z + a[j].w;
    sq += a[j].x*a[j].x + a[j].y*a[j].y + a[j].z*a[j].z + a[j].w*a[j].w;
  }
  s = wredSum(s); sq = wredSum(sq);
  float mu = s * (1.f / DIM);
  float var = sq * (1.f / DIM) - mu * mu;
  float rstd = 1.f / sqrtf(var + 1e-5f);
  const float* gs[3] = {g0, g1, g2};
  const float* bs[3] = {b0, b1, b2};
  signed char* outs[3] = {xq0, xq1, xq2};
  #pragma unroll
  for (int p = 0; p < 3; ++p) {
    float sc = 127.f / fmaxf(__uint_as_float(ambits[p]), 1e-5f);
    #pragma unroll
    for (int j = 0; j < 8; ++j) {
      float4 gg = *(const float4*)(gs[p] + j * 256 + lane * 4);
      float4 bb = *(const float4*)(bs[p] + j * 256 + lane * 4);
      float y0 = (a[j].x - mu) * rstd * gg.x + bb.x;
      float y1 = (a[j].y - mu) * rstd * gg.y + bb.y;
      float y2 = (a[j].z - mu) * rstd * gg.z + bb.z;
      float y3 = (a[j].w - mu) * rstd * gg.w + bb.w;
      char4 q;
      q.x = (signed char)(int)fminf(fmaxf(rintf(y0 * sc), -128.f), 127.f);
      q.y = (signed char)(int)fminf(fmaxf(rintf(y1 * sc), -128.f), 127.f);
      q.z = (signed char)(int)fminf(fmaxf(rintf(y2 * sc), -128.f), 127.f);
      q.w = (signed char)(int)fminf(fmaxf(rintf(y3 * sc), -128.f), 127.f);
      *(char4*)(outs[p] + (size_t)row * DIM + j * 256 + lane * 4) = q;
    }
  }
}

// ---------------- single-tensor LN (o projection), wave-per-row ----------------
template<int MODE>
__global__ __launch_bounds__(256) void ln_kernel(
    const float* __restrict__ x, const float* __restrict__ g, const float* __restrict__ bias,
    const unsigned* __restrict__ ambits, float* __restrict__ pmax,
    signed char* __restrict__ xq)
{
  const int lane = threadIdx.x & 63;
  const int row = blockIdx.x * 4 + (threadIdx.x >> 6);
  const float* xr = x + (size_t)row * DIM;
  float4 a[8];
  float s = 0.f, sq = 0.f;
  #pragma unroll
  for (int j = 0; j < 8; ++j) {
    a[j] = *(const float4*)(xr + j * 256 + lane * 4);
    s  += a[j].x + a[j].y + a[j].z + a[j].w;
    sq += a[j].x*a[j].x + a[j].y*a[j].y + a[j].z*a[j].z + a[j].w*a[j].w;
  }
  s = wredSum(s); sq = wredSum(sq);
  float mu = s * (1.f / DIM);
  float var = sq * (1.f / DIM) - mu * mu;
  float rstd = 1.f / sqrtf(var + 1e-5f);
  if (MODE == 0) {
    float m = 0.f;
    #pragma unroll
    for (int j = 0; j < 8; ++j) {
      float4 gg = *(const float4*)(g + j * 256 + lane * 4);
      float4 bb = *(const float4*)(bias + j * 256 + lane * 4);
      m = fmaxf(m, fabsf((a[j].x - mu) * rstd * gg.x + bb.x));
      m = fmaxf(m, fabsf((a[j].y - mu) * rstd * gg.y + bb.y));
      m = fmaxf(m, fabsf((a[j].z - mu) * rstd * gg.z + bb.z));
      m = fmaxf(m, fabsf((a[j].w - mu) * rstd * gg.w + bb.w));
    }
    m = wredMax(m);
    if (lane == 0) pmax[row] = m;
  } else {
    float sc = 127.f / fmaxf(__uint_as_float(*ambits), 1e-5f);
    #pragma unroll
    for (int j = 0; j < 8; ++j) {
      float4 gg = *(const float4*)(g + j * 256 + lane * 4);
      float4 bb = *(const float4*)(bias + j * 256 + lane * 4);
      float y0 = (a[j].x - mu) * rstd * gg.x + bb.x;
      float y1 = (a[j].y - mu) * rstd * gg.y + bb.y;
      float y2 = (a[j].z - mu) * rstd * gg.z + bb.z;
      float y3 = (a[j].w - mu) * rstd * gg.w + bb.w;
      char4 q;
      q.x = (signed char)(int)fminf(fmaxf(rintf(y0 * sc), -128.f), 127.f);
      q.y = (signed char)(int)fminf(fmaxf(rintf(y1 * sc), -128.f), 127.f);
      q.z = (signed char)(int)fminf(fmaxf(rintf(y2 * sc), -128.f), 127.f);
      q.w = (signed char)(int)fminf(fmaxf(rintf(y3 * sc), -128.f), 127.f);
      *(char4*)(xq + (size_t)row * DIM + j * 256 + lane * 4) = q;
    }
  }
}

// ---------------- merged QKV int8 GEMM (z = projection), m97 structure ----------------
// z==0/1: fp16 C store (q/k). z==2: transposed fp16 epilogue via LDS -> vt layout
// [(b*16+h)*128+d][s]  (replaces the separate transpose_v kernel).
__global__ __launch_bounds__(256) void gemm_qkv(
    const signed char* __restrict__ A0, const signed char* __restrict__ A1,
    const signed char* __restrict__ A2, const signed char* __restrict__ Bt0,
    unsigned short* __restrict__ C0, unsigned short* __restrict__ C1,
    unsigned short* __restrict__ C2t, const float* __restrict__ stats)
{
  const int tid = threadIdx.x;
  const int lane = tid & 63;
  const int w = tid >> 6;
  const int wm = w >> 1, wn = w & 1;
  const int quad = lane >> 4, l16 = lane & 15;
  const int bm = blockIdx.x * 128, bn = blockIdx.y * 128;
  const int z = blockIdx.z;

  const signed char* A  = z == 0 ? A0 : z == 1 ? A1 : A2;
  const signed char* Bt = Bt0 + (size_t)z * WN;

  // single 32 KB staging buffer (As | Bs); reused by the transposed epilogue for z==2
  __shared__ __align__(16) signed char smem[2 * 128 * 128];
  signed char* As = smem;
  signed char* Bs = smem + 128 * 128;

  const int srow_off = lane >> 3;        // 0..7
  const int scol     = (lane & 7) * 16;  // bytes

  intx4 acc[4][4];
  #pragma unroll
  for (int i = 0; i < 4; ++i)
    #pragma unroll
    for (int j = 0; j < 4; ++j) acc[i][j] = {0, 0, 0, 0};

  for (int k0 = 0; k0 < DIM; k0 += 128) {
    #pragma unroll
    for (int i = 0; i < 4; ++i) {
      int c = i * 4 + w;                 // wave-uniform chunk id, 16 chunks = 128 rows
      int row = c * 8 + srow_off;
      gload_lds16(A  + (size_t)(bm + row) * DIM + k0 + scol, &As[c * 1024]);
      gload_lds16(Bt + (size_t)(bn + row) * DIM + k0 + scol, &Bs[c * 1024]);
    }
    __syncthreads();
    #pragma unroll
    for (int kc = 0; kc < 2; ++kc) {
      intx4 af[4], bf[4];
      #pragma unroll
      for (int i = 0; i < 4; ++i)
        af[i] = *(const intx4*)&As[(wm * 64 + i * 16 + l16) * 128 + kc * 64 + quad * 16];
      #pragma unroll
      for (int j = 0; j < 4; ++j)
        bf[j] = *(const intx4*)&Bs[(wn * 64 + j * 16 + l16) * 128 + kc * 64 + quad * 16];
      #pragma unroll
      for (int i = 0; i < 4; ++i)
        #pragma unroll
        for (int j = 0; j < 4; ++j)
          acc[i][j] = __builtin_amdgcn_mfma_i32_16x16x64_i8(af[i], bf[j], acc[i][j], 0, 0, 0);
    }
    __syncthreads();
  }

  const unsigned* am = (const unsigned*)(stats + 8);
  float scale = stats[4 + z] * fmaxf(__uint_as_float(am[z]), 1e-5f) * (1.f / 127.f);

  if (z < 2) {
    unsigned short* Cp = z == 0 ? C0 : C1;
    #pragma unroll
    for (int i = 0; i < 4; ++i)
      #pragma unroll
      for (int j = 0; j < 4; ++j)
        #pragma unroll
        for (int r = 0; r < 4; ++r) {
          int m = bm + wm * 64 + i * 16 + quad * 4 + r;
          int n = bn + wn * 64 + j * 16 + l16;
          Cp[(size_t)m * DIM + n] = f2h((float)acc[i][j][r] * scale);
        }
  } else {
    // transposed epilogue: smem := tileT[d][s] fp16, XOR-swizzled; then coalesced store
    #pragma unroll
    for (int i = 0; i < 4; ++i)
      #pragma unroll
      for (int j = 0; j < 4; ++j)
        #pragma unroll
        for (int r = 0; r < 4; ++r) {
          int s = wm * 64 + i * 16 + quad * 4 + r;   // local m (= seq)
          int d = wn * 64 + j * 16 + l16;            // local n (= head dim)
          int byte = (d * 256 + s * 2) ^ ((d & 7) << 4);
          *(unsigned short*)(smem + byte) = f2h((float)acc[i][j][r] * scale);
        }
    __syncthreads();
    const int b = bm >> 11;                // batch (SEQ = 2048 rows per batch)
    const int s_base = bm & (SEQ - 1);
    const int h = blockIdx.y;              // bn covers exactly one head (128 cols)
    const int sc = (tid & 15) * 8;         // halves within a d-row
    #pragma unroll
    for (int pass = 0; pass < 8; ++pass) {
      int d = (tid >> 4) + pass * 16;
      int byte = (d * 256 + sc * 2) ^ ((d & 7) << 4);
      *(uint4*)(C2t + ((size_t)(b * HEADS + h) * HDIM + d) * SEQ + s_base + sc) =
          *(const uint4*)(smem + byte);
    }
  }
}

// ---------------- O-projection int8 GEMM (fp32 out), m97 structure ----------------
__global__ __launch_bounds__(256) void gemm_bt(
    const signed char* __restrict__ A, const signed char* __restrict__ Bt,
    float* __restrict__ Cp, const float* __restrict__ stats, int wi)
{
  const int tid = threadIdx.x;
  const int lane = tid & 63;
  const int w = tid >> 6;
  const int wm = w >> 1, wn = w & 1;
  const int quad = lane >> 4, l16 = lane & 15;
  const int bm = blockIdx.x * 128, bn = blockIdx.y * 128;

  __shared__ __align__(16) signed char As[128 * 128];
  __shared__ __align__(16) signed char Bs[128 * 128];

  const int srow_off = lane >> 3;
  const int scol     = (lane & 7) * 16;

  intx4 acc[4][4];
  #pragma unroll
  for (int i = 0; i < 4; ++i)
    #pragma unroll
    for (int j = 0; j < 4; ++j) acc[i][j] = {0, 0, 0, 0};

  for (int k0 = 0; k0 < DIM; k0 += 128) {
    #pragma unroll
    for (int i = 0; i < 4; ++i) {
      int c = i * 4 + w;
      int row = c * 8 + srow_off;
      gload_lds16(A  + (size_t)(bm + row) * DIM + k0 + scol, &As[c * 1024]);
      gload_lds16(Bt + (size_t)(bn + row) * DIM + k0 + scol, &Bs[c * 1024]);
    }
    __syncthreads();
    #pragma unroll
    for (int kc = 0; kc < 2; ++kc) {
      intx4 af[4], bf[4];
      #pragma unroll
      for (int i = 0; i < 4; ++i)
        af[i] = *(const intx4*)&As[(wm * 64 + i * 16 + l16) * 128 + kc * 64 + quad * 16];
      #pragma unroll
      for (int j = 0; j < 4; ++j)
        bf[j] = *(const intx4*)&Bs[(wn * 64 + j * 16 + l16) * 128 + kc * 64 + quad * 16];
      #pragma unroll
      for (int i = 0; i < 4; ++i)
        #pragma unroll
        for (int j = 0; j < 4; ++j)
          acc[i][j] = __builtin_amdgcn_mfma_i32_16x16x64_i8(af[i], bf[j], acc[i][j], 0, 0, 0);
    }
    __syncthreads();
  }

  const unsigned* am = (const unsigned*)(stats + 8);
  float scale = stats[4 + wi] * fmaxf(__uint_as_float(am[wi]), 1e-5f) * (1.f / 127.f);
  #pragma unroll
  for (int i = 0; i < 4; ++i)
    #pragma unroll
    for (int j = 0; j < 4; ++j)
      #pragma unroll
      for (int r = 0; r < 4; ++r) {
        int m = bm + wm * 64 + i * 16 + quad * 4 + r;
        int n = bn + wn * 64 + j * 16 + l16;
        Cp[(size_t)m * DIM + n] = (float)acc[i][j][r] * scale;
      }
}

// ---------------- rope (fp16; angle = head_index * inv; q gets (1/sqrt(128))*log2e folded) ----------------
__global__ __launch_bounds__(256) void rope_kernel(unsigned short* q, unsigned short* k)
{
  const float SC = 0.12751741769011063f;   // (1/sqrt(128)) * log2(e)
  int idx = blockIdx.x * 256 + threadIdx.x;
  int p = idx & 63;
  int h = (idx >> 6) & (HEADS - 1);
  int r = idx >> 10;
  float inv = exp2f((float)p * -0.20762050593046f);  // 10000^(-p/64)
  float ang = (float)h * inv;
  float sn, cs;
  __sincosf(ang, &sn, &cs);
  size_t base = (size_t)r * DIM + h * HDIM + 2 * p;
  {
    float a = h2f(q[base]), b = h2f(q[base + 1]);
    q[base]     = f2h((a * cs - b * sn) * SC);
    q[base + 1] = f2h((a * sn + b * cs) * SC);
  }
  {
    float a = h2f(k[base]), b = h2f(k[base + 1]);
    k[base]     = f2h(a * cs - b * sn);
    k[base + 1] = f2h(a * sn + b * cs);
  }
}

// ---------------- flash attention: QBLK=64, 4 blocks/CU, gload_lds staging ----------------
// Q pre-scaled by (1/sqrt(128))*log2(e); softmax in exp2 domain; T13 defer-rescale.
// global_load_lds DMA with PRE-SWIZZLED global source addresses (rule #21).
// XCD-chunked remap: id%8 = XCD, 4 bh/XCD (K/V panels fit the 4MB private L2).
__global__ __launch_bounds__(256, 4) void flash_attn(
    const unsigned short* __restrict__ qf, const unsigned short* __restrict__ kf,
    const unsigned short* __restrict__ vt, float* __restrict__ o)
{
  const int tid = threadIdx.x;
  const int lane = tid & 63;
  const int w = tid >> 6;
  const int quad = lane >> 4;
  const int l16 = lane & 15;
  const int L = blockIdx.x;
  const int slot = L >> 3;
  const int bh = ((L & 7) << 2) | (slot >> 5);
  const int qt = slot & 31;
  const int b = bh >> 4;
  const int h = bh & 15;

  __shared__ __align__(16) char Ks[64 * 256];     // [key t][d] halves; swizzled via source
  __shared__ __align__(16) char Vs[128 * 128];    // [d][t] halves;    swizzled via source
  __shared__ __align__(16) char Ps[4][16 * 128];  // per-wave [q][t] halves, swizzled

  const size_t qbase = ((size_t)(b * SEQ + qt * 64 + w * 16 + l16)) * DIM + h * HDIM;
  short8 qa[4];
  #pragma unroll
  for (int kc = 0; kc < 4; ++kc)
    qa[kc] = *(const short8*)(qf + qbase + kc * 32 + quad * 8);

  float m_q = -INFINITY;
  float l_q = 0.f;
  floatx4 accO[8];
  #pragma unroll
  for (int i = 0; i < 8; ++i) accO[i] = {0.f, 0.f, 0.f, 0.f};

  const char* kg = (const char*)(kf + (size_t)(b * SEQ) * DIM + h * HDIM);
  const char* vg = (const char*)(vt + (size_t)bh * HDIM * SEQ);

  int koff[4], voff[4];
  #pragma unroll
  for (int j = 0; j < 4; ++j) {
    int c = w * 4 + j;
    int rK = c * 4 + (lane >> 4);
    koff[j] = rK * (DIM * 2) + (((lane & 15) * 16) ^ ((rK & 7) << 4));
    int rV = c * 8 + (lane >> 3);
    voff[j] = rV * (SEQ * 2) + (((lane & 7) * 16) ^ ((rV & 7) << 4));
  }

  for (int kt = 0; kt < SEQ / 64; ++kt) {
    __syncthreads();
    const char* kgb = kg + (size_t)kt * 64 * DIM * 2;
    const char* vgb = vg + (size_t)kt * 128;
    #pragma unroll
    for (int j = 0; j < 4; ++j) {
      int c = w * 4 + j;
      gload_lds16(kgb + koff[j], &Ks[c * 1024]);
      gload_lds16(vgb + voff[j], &Vs[c * 1024]);
    }
    asm volatile("s_waitcnt vmcnt(0)" ::: "memory");
    __syncthreads();

    float sreg[4][4];
    __builtin_amdgcn_s_setprio(1);
    #pragma unroll
    for (int jt = 0; jt < 4; ++jt) {
      floatx4 a0 = {0.f, 0.f, 0.f, 0.f};
      #pragma unroll
      for (int kc = 0; kc < 4; ++kc) {
        int kr = jt * 16 + l16;
        short8 kb = *(const short8*)&Ks[(kr * 256 + kc * 64 + quad * 16) ^ ((kr & 7) << 4)];
        a0 = __builtin_amdgcn_mfma_f32_16x16x32_f16(
            __builtin_bit_cast(half8, kb), __builtin_bit_cast(half8, qa[kc]), a0, 0, 0, 0);
      }
      #pragma unroll
      for (int r = 0; r < 4; ++r) sreg[jt][r] = a0[r];
    }
    __builtin_amdgcn_s_setprio(0);

    float mx = sreg[0][0];
    #pragma unroll
    for (int jt = 0; jt < 4; ++jt)
      #pragma unroll
      for (int r = 0; r < 4; ++r) mx = fmaxf(mx, sreg[jt][r]);
    mx = fmaxf(mx, __shfl_xor(mx, 16));
    mx = fmaxf(mx, __shfl_xor(mx, 32));
    int need = !__all(mx <= m_q + 8.f);
    float mnew, alpha;
    if (need) {
      mnew = fmaxf(m_q, mx);
      alpha = exp2f(m_q - mnew);
      m_q = mnew;
    } else {
      mnew = m_q;
      alpha = 1.f;
    }
    float ssum = 0.f;
    #pragma unroll
    for (int jt = 0; jt < 4; ++jt) {
      ushort4 pk;
      float p0 = exp2f(sreg[jt][0] - mnew);
      float p1 = exp2f(sreg[jt][1] - mnew);
      float p2 = exp2f(sreg[jt][2] - mnew);
      float p3 = exp2f(sreg[jt][3] - mnew);
      pk.x = f2h(p0); pk.y = f2h(p1); pk.z = f2h(p2); pk.w = f2h(p3);
      ssum += (p0 + p1) + (p2 + p3);
      *(ushort4*)&Ps[w][(l16 * 128 + jt * 32 + quad * 8) ^ ((l16 & 7) << 4)] = pk;
    }
    ssum += __shfl_xor(ssum, 16);
    ssum += __shfl_xor(ssum, 32);
    l_q = l_q * alpha + ssum;
    if (need) {
      #pragma unroll
      for (int dt = 0; dt < 8; ++dt)
        #pragma unroll
        for (int r = 0; r < 4; ++r) accO[dt][r] *= alpha;
    }

    __builtin_amdgcn_s_setprio(1);
    #pragma unroll
    for (int kc = 0; kc < 2; ++kc) {
      short8 pf = *(const short8*)&Ps[w][(l16 * 128 + kc * 64 + quad * 16) ^ ((l16 & 7) << 4)];
      #pragma unroll
      for (int dt = 0; dt < 8; ++dt) {
        int vr = dt * 16 + l16;
        short8 vf = *(const short8*)&Vs[(vr * 128 + kc * 64 + quad * 16) ^ ((vr & 7) << 4)];
        accO[dt] = __builtin_amdgcn_mfma_f32_16x16x32_f16(
            __builtin_bit_cast(half8, vf), __builtin_bit_cast(half8, pf), accO[dt], 0, 0, 0);
      }
    }
    __builtin_amdgcn_s_setprio(0);
  }

  float invl = 1.0f / l_q;
  const size_t obase = (size_t)(b * SEQ + qt * 64 + w * 16 + l16) * DIM + h * HDIM;
  #pragma unroll
  for (int dt = 0; dt < 8; ++dt) {
    float4 ov;
    ov.x = accO[dt][0] * invl; ov.y = accO[dt][1] * invl;
    ov.z = accO[dt][2] * invl; ov.w = accO[dt][3] * invl;
    *(float4*)(o + obase + dt * 16 + quad * 4) = ov;
  }
}

// ---------------- host ----------------
extern "C" void kernel_launch(void* const* d_in, const int* in_sizes, int n_in,
                              void* d_out, int out_size, void* d_ws, size_t ws_size,
                              hipStream_t stream)
{
  (void)in_sizes; (void)n_in; (void)out_size; (void)ws_size;
  const float* x = (const float*)d_in[0];
  const float* w[4]; const float* g[4]; const float* bb[4];
  for (int i = 0; i < 4; ++i) {
    w[i]  = (const float*)d_in[1 + 3 * i];
    g[i]  = (const float*)d_in[2 + 3 * i];
    bb[i] = (const float*)d_in[3 + 3 * i];
  }

  char* base = (char*)d_ws;
  size_t off = 0;
  auto alloc = [&](size_t bytes) {
    char* p = base + off;
    off += (bytes + 255) & ~(size_t)255;
    return p;
  };
  const size_t ACTH = (size_t)NROWS * DIM * 2;  // 16-bit activation buffer (16 MB)
  const size_t ACT8 = (size_t)NROWS * DIM;      // 8-bit activation buffer (8 MB)
  float* stats          = (float*)alloc(64);
  float* part1          = (float*)alloc(4 * 1024 * sizeof(float));
  float* part2          = (float*)alloc(4 * 1024 * 2 * sizeof(float));
  float* pmax           = (float*)alloc((size_t)4 * NROWS * sizeof(float));
  signed char* tern     = (signed char*)alloc((size_t)4 * WN);
  signed char* xq0      = (signed char*)alloc(ACT8);
  signed char* xq1      = (signed char*)alloc(ACT8);
  signed char* xq2      = (signed char*)alloc(ACT8);
  unsigned short* qh    = (unsigned short*)alloc(ACTH);
  unsigned short* kh    = (unsigned short*)alloc(ACTH);
  unsigned short* vtb   = (unsigned short*)alloc(ACTH);
  float* oat            = (float*)alloc((size_t)NROWS * DIM * sizeof(float));
  signed char* xqo = xq0;              // overlay: xq0 dead after the q GEMM
  unsigned* ambits = (unsigned*)(stats + 8);

  hipMemsetAsync(stats, 0, 64, stream);

  dim3 b256(256);
  w_abs_partial<<<dim3(1024, 4), b256, 0, stream>>>(w[0], w[1], w[2], w[3], part1);
  w_delta_final<<<4, b256, 0, stream>>>(part1, stats);
  w_maskquant<<<dim3(1024, 4), b256, 0, stream>>>(w[0], w[1], w[2], w[3], stats, part2, tern);
  w_alpha_final<<<4, b256, 0, stream>>>(part2, stats);

  ln_absmax3<<<NROWS / 4, b256, 0, stream>>>(x, g[0], bb[0], g[1], bb[1], g[2], bb[2], pmax);
  absmax_final<<<3, b256, 0, stream>>>(pmax, ambits);
  ln_quant3<<<NROWS / 4, b256, 0, stream>>>(x, g[0], bb[0], g[1], bb[1], g[2], bb[2], ambits,
                                            xq0, xq1, xq2);

  gemm_qkv<<<dim3(NROWS / 128, DIM / 128, 3), b256, 0, stream>>>(
      xq0, xq1, xq2, tern, qh, kh, vtb, stats);

  rope_kernel<<<NROWS * 1024 / 256, b256, 0, stream>>>(qh, kh);
  flash_attn<<<dim3(32 * 32), b256, 0, stream>>>(qh, kh, vtb, oat);

  ln_kernel<0><<<NROWS / 4, b256, 0, stream>>>(oat, g[3], bb[3], nullptr,
                                               pmax + (size_t)3 * NROWS, nullptr);
  absmax_final<<<1, b256, 0, stream>>>(pmax + (size_t)3 * NROWS, ambits + 3);
  ln_kernel<1><<<NROWS / 4, b256, 0, stream>>>(oat, g[3], bb[3], ambits + 3, nullptr, xqo);
  gemm_bt<<<dim3(NROWS / 128, DIM / 128), b256, 0, stream>>>(
      xqo, tern + (size_t)3 * WN, (float*)d_out, stats, 3);
}

// Round 11
// 429.836 us; speedup vs baseline: 2.2150x; 1.0298x over previous
//
#include <hip/hip_runtime.h>
#include <math.h>

#define DIM 2048
#define NROWS 4096            // B*S
#define WN (DIM*DIM)
#define HEADS 16
#define HDIM 128
#define SEQ 2048

typedef __attribute__((ext_vector_type(8))) short short8;
typedef __attribute__((ext_vector_type(8))) _Float16 half8;
typedef __attribute__((ext_vector_type(4))) float floatx4;
typedef __attribute__((ext_vector_type(4))) int intx4;

__device__ __forceinline__ unsigned short f2h(float f) {
  _Float16 h = (_Float16)f;
  return __builtin_bit_cast(unsigned short, h);
}
__device__ __forceinline__ float h2f(unsigned short u) {
  _Float16 h = __builtin_bit_cast(_Float16, u);
  return (float)h;
}
// packed f32x2 -> f16x2 (RTZ) as a single u32
__device__ __forceinline__ unsigned pkh2(float a, float b) {
  return __builtin_bit_cast(unsigned, __builtin_amdgcn_cvt_pkrtz(a, b));
}

// async global->LDS, 16B per lane; lds base must be wave-uniform (HW scatters lane i at +i*16)
__device__ __forceinline__ void gload_lds16(const void* g, void* l) {
  __builtin_amdgcn_global_load_lds(
      (const __attribute__((address_space(1))) unsigned int*)g,
      (__attribute__((address_space(3))) unsigned int*)l, 16, 0, 0);
}

__device__ __forceinline__ float wredSum(float v) {
  #pragma unroll
  for (int o = 1; o < 64; o <<= 1) v += __shfl_xor(v, o);
  return v;
}
__device__ __forceinline__ float wredMax(float v) {
  #pragma unroll
  for (int o = 1; o < 64; o <<= 1) v = fmaxf(v, __shfl_xor(v, o));
  return v;
}

__device__ __forceinline__ float blockReduceSum(float v, float* red) {
  int tid = threadIdx.x;
  red[tid] = v; __syncthreads();
  for (int s = 128; s > 0; s >>= 1) {
    if (tid < s) red[tid] += red[tid + s];
    __syncthreads();
  }
  float r = red[0]; __syncthreads();
  return r;
}

__device__ __forceinline__ const float* pick_w(const float* a, const float* b,
                                               const float* c, const float* d, int i) {
  return i == 0 ? a : i == 1 ? b : i == 2 ? c : d;
}

// ---------------- weight stats ----------------
__global__ __launch_bounds__(256) void w_abs_partial(
    const float* w0, const float* w1, const float* w2, const float* w3, float* part)
{
  const float4* w4 = (const float4*)pick_w(w0, w1, w2, w3, blockIdx.y);
  float s = 0.f;
  for (int i = blockIdx.x * 256 + threadIdx.x; i < WN / 4; i += 1024 * 256) {
    float4 v = w4[i];
    s += fabsf(v.x) + fabsf(v.y) + fabsf(v.z) + fabsf(v.w);
  }
  __shared__ float red[256];
  float t = blockReduceSum(s, red);
  if (threadIdx.x == 0) part[blockIdx.y * 1024 + blockIdx.x] = t;
}

__global__ __launch_bounds__(256) void w_delta_final(const float* part, float* stats)
{
  float s = 0.f;
  for (int i = threadIdx.x; i < 1024; i += 256) s += part[blockIdx.x * 1024 + i];
  __shared__ float red[256];
  float t = blockReduceSum(s, red);
  if (threadIdx.x == 0) stats[blockIdx.x] = 0.7f * (t / (float)WN);
}

__device__ __forceinline__ signed char tq(float v, float delta) {
  if (fabsf(v) > delta) return (v > 0.f) ? (signed char)1 : (signed char)-1;
  return (signed char)0;
}

// fused: ternary-quantize weights (int8 {-1,0,1}) AND accumulate alpha partials
__global__ __launch_bounds__(256) void w_maskquant(
    const float* w0, const float* w1, const float* w2, const float* w3,
    const float* stats, float* part2, signed char* tern)
{
  int wi = blockIdx.y;
  const float4* w4 = (const float4*)pick_w(w0, w1, w2, w3, wi);
  float delta = stats[wi];
  char4* out = (char4*)(tern + (size_t)wi * WN);
  float s = 0.f, cnt = 0.f;
  for (int i = blockIdx.x * 256 + threadIdx.x; i < WN / 4; i += 1024 * 256) {
    float4 v = w4[i];
    char4 o;
    float a;
    a = fabsf(v.x); if (a > delta) { s += a; cnt += 1.f; } o.x = tq(v.x, delta);
    a = fabsf(v.y); if (a > delta) { s += a; cnt += 1.f; } o.y = tq(v.y, delta);
    a = fabsf(v.z); if (a > delta) { s += a; cnt += 1.f; } o.z = tq(v.z, delta);
    a = fabsf(v.w); if (a > delta) { s += a; cnt += 1.f; } o.w = tq(v.w, delta);
    out[i] = o;
  }
  __shared__ float red[256];
  float ts = blockReduceSum(s, red);
  float tc = blockReduceSum(cnt, red);
  if (threadIdx.x == 0) {
    part2[((size_t)blockIdx.y * 1024 + blockIdx.x) * 2]     = ts;
    part2[((size_t)blockIdx.y * 1024 + blockIdx.x) * 2 + 1] = tc;
  }
}

__global__ __launch_bounds__(256) void w_alpha_final(const float* part2, float* stats)
{
  float s = 0.f, c = 0.f;
  for (int i = threadIdx.x; i < 1024; i += 256) {
    s += part2[((size_t)blockIdx.x * 1024 + i) * 2];
    c += part2[((size_t)blockIdx.x * 1024 + i) * 2 + 1];
  }
  __shared__ float red[256];
  float ts = blockReduceSum(s, red);
  float tc = blockReduceSum(c, red);
  if (threadIdx.x == 0) stats[4 + blockIdx.x] = ts / fmaxf(tc, 1.f);
}

// ---------------- LN kernels: one WAVE per row, shuffle-only reductions, no atomics --------
__global__ __launch_bounds__(256) void ln_absmax3(
    const float* __restrict__ x,
    const float* __restrict__ g0, const float* __restrict__ b0,
    const float* __restrict__ g1, const float* __restrict__ b1,
    const float* __restrict__ g2, const float* __restrict__ b2,
    float* __restrict__ pmax)     // [3][NROWS] per-row maxima
{
  const int lane = threadIdx.x & 63;
  const int row = blockIdx.x * 4 + (threadIdx.x >> 6);
  const float* xr = x + (size_t)row * DIM;
  float4 a[8];
  float s = 0.f, sq = 0.f;
  #pragma unroll
  for (int j = 0; j < 8; ++j) {
    a[j] = *(const float4*)(xr + j * 256 + lane * 4);
    s  += a[j].x + a[j].y + a[j].z + a[j].w;
    sq += a[j].x*a[j].x + a[j].y*a[j].y + a[j].z*a[j].z + a[j].w*a[j].w;
  }
  s = wredSum(s); sq = wredSum(sq);
  float mu = s * (1.f / DIM);
  float var = sq * (1.f / DIM) - mu * mu;
  float rstd = 1.f / sqrtf(var + 1e-5f);
  const float* gs[3] = {g0, g1, g2};
  const float* bs[3] = {b0, b1, b2};
  #pragma unroll
  for (int p = 0; p < 3; ++p) {
    float m = 0.f;
    #pragma unroll
    for (int j = 0; j < 8; ++j) {
      float4 gg = *(const float4*)(gs[p] + j * 256 + lane * 4);
      float4 bb = *(const float4*)(bs[p] + j * 256 + lane * 4);
      m = fmaxf(m, fabsf((a[j].x - mu) * rstd * gg.x + bb.x));
      m = fmaxf(m, fabsf((a[j].y - mu) * rstd * gg.y + bb.y));
      m = fmaxf(m, fabsf((a[j].z - mu) * rstd * gg.z + bb.z));
      m = fmaxf(m, fabsf((a[j].w - mu) * rstd * gg.w + bb.w));
    }
    m = wredMax(m);
    if (lane == 0) pmax[(size_t)p * NROWS + row] = m;
  }
}

// one block per projection: reduce NROWS partial maxima -> ambits[p] (direct write, no atomic)
__global__ __launch_bounds__(256) void absmax_final(
    const float* __restrict__ pmax, unsigned* __restrict__ ambits)
{
  const float* src = pmax + (size_t)blockIdx.x * NROWS;
  float m = 0.f;
  for (int i = threadIdx.x; i < NROWS; i += 256) m = fmaxf(m, src[i]);
  m = wredMax(m);
  __shared__ float red[4];
  if ((threadIdx.x & 63) == 0) red[threadIdx.x >> 6] = m;
  __syncthreads();
  if (threadIdx.x == 0)
    ambits[blockIdx.x] = __float_as_uint(fmaxf(fmaxf(red[0], red[1]), fmaxf(red[2], red[3])));
}

__global__ __launch_bounds__(256) void ln_quant3(
    const float* __restrict__ x,
    const float* __restrict__ g0, const float* __restrict__ b0,
    const float* __restrict__ g1, const float* __restrict__ b1,
    const float* __restrict__ g2, const float* __restrict__ b2,
    const unsigned* __restrict__ ambits,
    signed char* __restrict__ xq0, signed char* __restrict__ xq1,
    signed char* __restrict__ xq2)
{
  const int lane = threadIdx.x & 63;
  const int row = blockIdx.x * 4 + (threadIdx.x >> 6);
  const float* xr = x + (size_t)row * DIM;
  float4 a[8];
  float s = 0.f, sq = 0.f;
  #pragma unroll
  for (int j = 0; j < 8; ++j) {
    a[j] = *(const float4*)(xr + j * 256 + lane * 4);
    s  += a[j].x + a[j].y + a[j].z + a[j].w;
    sq += a[j].x*a[j].x + a[j].y*a[j].y + a[j].z*a[j].z + a[j].w*a[j].w;
  }
  s = wredSum(s); sq = wredSum(sq);
  float mu = s * (1.f / DIM);
  float var = sq * (1.f / DIM) - mu * mu;
  float rstd = 1.f / sqrtf(var + 1e-5f);
  const float* gs[3] = {g0, g1, g2};
  const float* bs[3] = {b0, b1, b2};
  signed char* outs[3] = {xq0, xq1, xq2};
  #pragma unroll
  for (int p = 0; p < 3; ++p) {
    float sc = 127.f / fmaxf(__uint_as_float(ambits[p]), 1e-5f);
    #pragma unroll
    for (int j = 0; j < 8; ++j) {
      float4 gg = *(const float4*)(gs[p] + j * 256 + lane * 4);
      float4 bb = *(const float4*)(bs[p] + j * 256 + lane * 4);
      float y0 = (a[j].x - mu) * rstd * gg.x + bb.x;
      float y1 = (a[j].y - mu) * rstd * gg.y + bb.y;
      float y2 = (a[j].z - mu) * rstd * gg.z + bb.z;
      float y3 = (a[j].w - mu) * rstd * gg.w + bb.w;
      char4 q;
      q.x = (signed char)(int)fminf(fmaxf(rintf(y0 * sc), -128.f), 127.f);
      q.y = (signed char)(int)fminf(fmaxf(rintf(y1 * sc), -128.f), 127.f);
      q.z = (signed char)(int)fminf(fmaxf(rintf(y2 * sc), -128.f), 127.f);
      q.w = (signed char)(int)fminf(fmaxf(rintf(y3 * sc), -128.f), 127.f);
      *(char4*)(outs[p] + (size_t)row * DIM + j * 256 + lane * 4) = q;
    }
  }
}

// ---------------- single-tensor LN (o projection), wave-per-row ----------------
template<int MODE>
__global__ __launch_bounds__(256) void ln_kernel(
    const float* __restrict__ x, const float* __restrict__ g, const float* __restrict__ bias,
    const unsigned* __restrict__ ambits, float* __restrict__ pmax,
    signed char* __restrict__ xq)
{
  const int lane = threadIdx.x & 63;
  const int row = blockIdx.x * 4 + (threadIdx.x >> 6);
  const float* xr = x + (size_t)row * DIM;
  float4 a[8];
  float s = 0.f, sq = 0.f;
  #pragma unroll
  for (int j = 0; j < 8; ++j) {
    a[j] = *(const float4*)(xr + j * 256 + lane * 4);
    s  += a[j].x + a[j].y + a[j].z + a[j].w;
    sq += a[j].x*a[j].x + a[j].y*a[j].y + a[j].z*a[j].z + a[j].w*a[j].w;
  }
  s = wredSum(s); sq = wredSum(sq);
  float mu = s * (1.f / DIM);
  float var = sq * (1.f / DIM) - mu * mu;
  float rstd = 1.f / sqrtf(var + 1e-5f);
  if (MODE == 0) {
    float m = 0.f;
    #pragma unroll
    for (int j = 0; j < 8; ++j) {
      float4 gg = *(const float4*)(g + j * 256 + lane * 4);
      float4 bb = *(const float4*)(bias + j * 256 + lane * 4);
      m = fmaxf(m, fabsf((a[j].x - mu) * rstd * gg.x + bb.x));
      m = fmaxf(m, fabsf((a[j].y - mu) * rstd * gg.y + bb.y));
      m = fmaxf(m, fabsf((a[j].z - mu) * rstd * gg.z + bb.z));
      m = fmaxf(m, fabsf((a[j].w - mu) * rstd * gg.w + bb.w));
    }
    m = wredMax(m);
    if (lane == 0) pmax[row] = m;
  } else {
    float sc = 127.f / fmaxf(__uint_as_float(*ambits), 1e-5f);
    #pragma unroll
    for (int j = 0; j < 8; ++j) {
      float4 gg = *(const float4*)(g + j * 256 + lane * 4);
      float4 bb = *(const float4*)(bias + j * 256 + lane * 4);
      float y0 = (a[j].x - mu) * rstd * gg.x + bb.x;
      float y1 = (a[j].y - mu) * rstd * gg.y + bb.y;
      float y2 = (a[j].z - mu) * rstd * gg.z + bb.z;
      float y3 = (a[j].w - mu) * rstd * gg.w + bb.w;
      char4 q;
      q.x = (signed char)(int)fminf(fmaxf(rintf(y0 * sc), -128.f), 127.f);
      q.y = (signed char)(int)fminf(fmaxf(rintf(y1 * sc), -128.f), 127.f);
      q.z = (signed char)(int)fminf(fmaxf(rintf(y2 * sc), -128.f), 127.f);
      q.w = (signed char)(int)fminf(fmaxf(rintf(y3 * sc), -128.f), 127.f);
      *(char4*)(xq + (size_t)row * DIM + j * 256 + lane * 4) = q;
    }
  }
}

// ---------------- merged QKV int8 GEMM (z = projection), m97 structure ----------------
// z==0/1: fp16 C store (q/k). z==2: transposed fp16 epilogue via LDS -> vt layout
// [(b*16+h)*128+d][s]  (replaces the separate transpose_v kernel).
__global__ __launch_bounds__(256) void gemm_qkv(
    const signed char* __restrict__ A0, const signed char* __restrict__ A1,
    const signed char* __restrict__ A2, const signed char* __restrict__ Bt0,
    unsigned short* __restrict__ C0, unsigned short* __restrict__ C1,
    unsigned short* __restrict__ C2t, const float* __restrict__ stats)
{
  const int tid = threadIdx.x;
  const int lane = tid & 63;
  const int w = tid >> 6;
  const int wm = w >> 1, wn = w & 1;
  const int quad = lane >> 4, l16 = lane & 15;
  const int bm = blockIdx.x * 128, bn = blockIdx.y * 128;
  const int z = blockIdx.z;

  const signed char* A  = z == 0 ? A0 : z == 1 ? A1 : A2;
  const signed char* Bt = Bt0 + (size_t)z * WN;

  // single 32 KB staging buffer (As | Bs); reused by the transposed epilogue for z==2
  __shared__ __align__(16) signed char smem[2 * 128 * 128];
  signed char* As = smem;
  signed char* Bs = smem + 128 * 128;

  const int srow_off = lane >> 3;        // 0..7
  const int scol     = (lane & 7) * 16;  // bytes

  intx4 acc[4][4];
  #pragma unroll
  for (int i = 0; i < 4; ++i)
    #pragma unroll
    for (int j = 0; j < 4; ++j) acc[i][j] = {0, 0, 0, 0};

  for (int k0 = 0; k0 < DIM; k0 += 128) {
    #pragma unroll
    for (int i = 0; i < 4; ++i) {
      int c = i * 4 + w;                 // wave-uniform chunk id, 16 chunks = 128 rows
      int row = c * 8 + srow_off;
      gload_lds16(A  + (size_t)(bm + row) * DIM + k0 + scol, &As[c * 1024]);
      gload_lds16(Bt + (size_t)(bn + row) * DIM + k0 + scol, &Bs[c * 1024]);
    }
    __syncthreads();
    #pragma unroll
    for (int kc = 0; kc < 2; ++kc) {
      intx4 af[4], bf[4];
      #pragma unroll
      for (int i = 0; i < 4; ++i)
        af[i] = *(const intx4*)&As[(wm * 64 + i * 16 + l16) * 128 + kc * 64 + quad * 16];
      #pragma unroll
      for (int j = 0; j < 4; ++j)
        bf[j] = *(const intx4*)&Bs[(wn * 64 + j * 16 + l16) * 128 + kc * 64 + quad * 16];
      #pragma unroll
      for (int i = 0; i < 4; ++i)
        #pragma unroll
        for (int j = 0; j < 4; ++j)
          acc[i][j] = __builtin_amdgcn_mfma_i32_16x16x64_i8(af[i], bf[j], acc[i][j], 0, 0, 0);
    }
    __syncthreads();
  }

  const unsigned* am = (const unsigned*)(stats + 8);
  float scale = stats[4 + z] * fmaxf(__uint_as_float(am[z]), 1e-5f) * (1.f / 127.f);

  if (z < 2) {
    unsigned short* Cp = z == 0 ? C0 : C1;
    #pragma unroll
    for (int i = 0; i < 4; ++i)
      #pragma unroll
      for (int j = 0; j < 4; ++j)
        #pragma unroll
        for (int r = 0; r < 4; ++r) {
          int m = bm + wm * 64 + i * 16 + quad * 4 + r;
          int n = bn + wn * 64 + j * 16 + l16;
          Cp[(size_t)m * DIM + n] = f2h((float)acc[i][j][r] * scale);
        }
  } else {
    // transposed epilogue: smem := tileT[d][s] fp16, XOR-swizzled; then coalesced store
    #pragma unroll
    for (int i = 0; i < 4; ++i)
      #pragma unroll
      for (int j = 0; j < 4; ++j)
        #pragma unroll
        for (int r = 0; r < 4; ++r) {
          int s = wm * 64 + i * 16 + quad * 4 + r;   // local m (= seq)
          int d = wn * 64 + j * 16 + l16;            // local n (= head dim)
          int byte = (d * 256 + s * 2) ^ ((d & 7) << 4);
          *(unsigned short*)(smem + byte) = f2h((float)acc[i][j][r] * scale);
        }
    __syncthreads();
    const int b = bm >> 11;                // batch (SEQ = 2048 rows per batch)
    const int s_base = bm & (SEQ - 1);
    const int h = blockIdx.y;              // bn covers exactly one head (128 cols)
    const int sc = (tid & 15) * 8;         // halves within a d-row
    #pragma unroll
    for (int pass = 0; pass < 8; ++pass) {
      int d = (tid >> 4) + pass * 16;
      int byte = (d * 256 + sc * 2) ^ ((d & 7) << 4);
      *(uint4*)(C2t + ((size_t)(b * HEADS + h) * HDIM + d) * SEQ + s_base + sc) =
          *(const uint4*)(smem + byte);
    }
  }
}

// ---------------- O-projection int8 GEMM (fp32 out), m97 structure ----------------
__global__ __launch_bounds__(256) void gemm_bt(
    const signed char* __restrict__ A, const signed char* __restrict__ Bt,
    float* __restrict__ Cp, const float* __restrict__ stats, int wi)
{
  const int tid = threadIdx.x;
  const int lane = tid & 63;
  const int w = tid >> 6;
  const int wm = w >> 1, wn = w & 1;
  const int quad = lane >> 4, l16 = lane & 15;
  const int bm = blockIdx.x * 128, bn = blockIdx.y * 128;

  __shared__ __align__(16) signed char As[128 * 128];
  __shared__ __align__(16) signed char Bs[128 * 128];

  const int srow_off = lane >> 3;
  const int scol     = (lane & 7) * 16;

  intx4 acc[4][4];
  #pragma unroll
  for (int i = 0; i < 4; ++i)
    #pragma unroll
    for (int j = 0; j < 4; ++j) acc[i][j] = {0, 0, 0, 0};

  for (int k0 = 0; k0 < DIM; k0 += 128) {
    #pragma unroll
    for (int i = 0; i < 4; ++i) {
      int c = i * 4 + w;
      int row = c * 8 + srow_off;
      gload_lds16(A  + (size_t)(bm + row) * DIM + k0 + scol, &As[c * 1024]);
      gload_lds16(Bt + (size_t)(bn + row) * DIM + k0 + scol, &Bs[c * 1024]);
    }
    __syncthreads();
    #pragma unroll
    for (int kc = 0; kc < 2; ++kc) {
      intx4 af[4], bf[4];
      #pragma unroll
      for (int i = 0; i < 4; ++i)
        af[i] = *(const intx4*)&As[(wm * 64 + i * 16 + l16) * 128 + kc * 64 + quad * 16];
      #pragma unroll
      for (int j = 0; j < 4; ++j)
        bf[j] = *(const intx4*)&Bs[(wn * 64 + j * 16 + l16) * 128 + kc * 64 + quad * 16];
      #pragma unroll
      for (int i = 0; i < 4; ++i)
        #pragma unroll
        for (int j = 0; j < 4; ++j)
          acc[i][j] = __builtin_amdgcn_mfma_i32_16x16x64_i8(af[i], bf[j], acc[i][j], 0, 0, 0);
    }
    __syncthreads();
  }

  const unsigned* am = (const unsigned*)(stats + 8);
  float scale = stats[4 + wi] * fmaxf(__uint_as_float(am[wi]), 1e-5f) * (1.f / 127.f);
  #pragma unroll
  for (int i = 0; i < 4; ++i)
    #pragma unroll
    for (int j = 0; j < 4; ++j)
      #pragma unroll
      for (int r = 0; r < 4; ++r) {
        int m = bm + wm * 64 + i * 16 + quad * 4 + r;
        int n = bn + wn * 64 + j * 16 + l16;
        Cp[(size_t)m * DIM + n] = (float)acc[i][j][r] * scale;
      }
}

// ---------------- rope (fp16; angle = head_index * inv; q gets (1/sqrt(128))*log2e folded) ----------------
__global__ __launch_bounds__(256) void rope_kernel(unsigned short* q, unsigned short* k)
{
  const float SC = 0.12751741769011063f;   // (1/sqrt(128)) * log2(e)
  int idx = blockIdx.x * 256 + threadIdx.x;
  int p = idx & 63;
  int h = (idx >> 6) & (HEADS - 1);
  int r = idx >> 10;
  float inv = exp2f((float)p * -0.20762050593046f);  // 10000^(-p/64)
  float ang = (float)h * inv;
  float sn, cs;
  __sincosf(ang, &sn, &cs);
  size_t base = (size_t)r * DIM + h * HDIM + 2 * p;
  {
    float a = h2f(q[base]), b = h2f(q[base + 1]);
    q[base]     = f2h((a * cs - b * sn) * SC);
    q[base + 1] = f2h((a * sn + b * cs) * SC);
  }
  {
    float a = h2f(k[base]), b = h2f(k[base + 1]);
    k[base]     = f2h(a * cs - b * sn);
    k[base + 1] = f2h(a * sn + b * cs);
  }
}

// ---------------- flash attention: QBLK=128 (2 Q-fragments/wave), gload_lds staging -------
// Q pre-scaled by (1/sqrt(128))*log2(e); softmax in exp2 domain; T13 defer-rescale.
// Staging cost (8 gloads + vmcnt(0) + 2 barriers per 64-key tile) amortized over 2x MFMA.
// global_load_lds DMA with PRE-SWIZZLED global source addresses (rule #21).
// XCD-chunked remap: id%8 = XCD, 4 bh/XCD. Grid 512 = 2 blocks/CU; LDS 48KB.
__global__ __launch_bounds__(256, 2) void flash_attn(
    const unsigned short* __restrict__ qf, const unsigned short* __restrict__ kf,
    const unsigned short* __restrict__ vt, float* __restrict__ o)
{
  const int tid = threadIdx.x;
  const int lane = tid & 63;
  const int w = tid >> 6;
  const int quad = lane >> 4;
  const int l16 = lane & 15;
  // XCD-chunked decode: xcd = id&7, slot = id>>3; bh = xcd*4 + slot/16, qt = slot%16
  const int L = blockIdx.x;
  const int slot = L >> 3;
  const int bh = ((L & 7) << 2) | (slot >> 4);
  const int qt = slot & 15;
  const int b = bh >> 4;
  const int h = bh & 15;

  __shared__ __align__(16) char Ks[64 * 256];     // [key t][d] halves; swizzled via source
  __shared__ __align__(16) char Vs[128 * 128];    // [d][t] halves;    swizzled via source
  __shared__ __align__(16) char Ps[4][32 * 128];  // per-wave [q 0..31][t] halves, swizzled

  // Q fragments (B-operand): wave owns 32 q-rows, two 16-row fragments
  const size_t qbase = ((size_t)(b * SEQ + qt * 128 + w * 32 + l16)) * DIM + h * HDIM;
  short8 qa[2][4];
  #pragma unroll
  for (int f = 0; f < 2; ++f)
    #pragma unroll
    for (int kc = 0; kc < 4; ++kc)
      qa[f][kc] = *(const short8*)(qf + qbase + (size_t)f * 16 * DIM + kc * 32 + quad * 8);

  float m_q[2] = {-INFINITY, -INFINITY};
  float l_q[2] = {0.f, 0.f};
  floatx4 accO0[8], accO1[8];           // O^T: rows d=dt*16+quad*4+r, col q = f*16+l16
  #pragma unroll
  for (int i = 0; i < 8; ++i) { accO0[i] = {0.f, 0.f, 0.f, 0.f}; accO1[i] = {0.f, 0.f, 0.f, 0.f}; }

  const char* kg = (const char*)(kf + (size_t)(b * SEQ) * DIM + h * HDIM);
  const char* vg = (const char*)(vt + (size_t)bh * HDIM * SEQ);

  // per-lane pre-swizzled source offsets (bytes) for this wave's 4 chunks of K and V.
  int koff[4], voff[4];
  #pragma unroll
  for (int j = 0; j < 4; ++j) {
    int c = w * 4 + j;
    int rK = c * 4 + (lane >> 4);
    koff[j] = rK * (DIM * 2) + (((lane & 15) * 16) ^ ((rK & 7) << 4));
    int rV = c * 8 + (lane >> 3);
    voff[j] = rV * (SEQ * 2) + (((lane & 7) * 16) ^ ((rV & 7) << 4));
  }

  for (int kt = 0; kt < SEQ / 64; ++kt) {
    __syncthreads();                    // prior tile's LDS reads complete
    const char* kgb = kg + (size_t)kt * 64 * DIM * 2;   // key rows advance
    const char* vgb = vg + (size_t)kt * 128;            // value cols advance (bytes)
    #pragma unroll
    for (int j = 0; j < 4; ++j) {
      int c = w * 4 + j;
      gload_lds16(kgb + koff[j], &Ks[c * 1024]);
      gload_lds16(vgb + voff[j], &Vs[c * 1024]);
    }
    asm volatile("s_waitcnt vmcnt(0)" ::: "memory");
    __syncthreads();

    // S^T = K Q'^T : lane q = f*16+l16, keys t = jt*16 + quad*4 + r
    float sreg[2][4][4];
    __builtin_amdgcn_s_setprio(1);
    #pragma unroll
    for (int jt = 0; jt < 4; ++jt) {
      floatx4 a0 = {0.f, 0.f, 0.f, 0.f}, a1 = {0.f, 0.f, 0.f, 0.f};
      #pragma unroll
      for (int kc = 0; kc < 4; ++kc) {
        int kr = jt * 16 + l16;
        short8 kb = *(const short8*)&Ks[(kr * 256 + kc * 64 + quad * 16) ^ ((kr & 7) << 4)];
        a0 = __builtin_amdgcn_mfma_f32_16x16x32_f16(
            __builtin_bit_cast(half8, kb), __builtin_bit_cast(half8, qa[0][kc]), a0, 0, 0, 0);
        a1 = __builtin_amdgcn_mfma_f32_16x16x32_f16(
            __builtin_bit_cast(half8, kb), __builtin_bit_cast(half8, qa[1][kc]), a1, 0, 0, 0);
      }
      #pragma unroll
      for (int r = 0; r < 4; ++r) { sreg[0][jt][r] = a0[r]; sreg[1][jt][r] = a1[r]; }
    }
    __builtin_amdgcn_s_setprio(0);

    // per-lane online softmax (exp2 domain); T13 defer-rescale; cvt_pkrtz packing
    float alpha[2]; int need[2];
    #pragma unroll
    for (int f = 0; f < 2; ++f) {
      float mx = sreg[f][0][0];
      #pragma unroll
      for (int jt = 0; jt < 4; ++jt)
        #pragma unroll
        for (int r = 0; r < 4; ++r) mx = fmaxf(mx, sreg[f][jt][r]);
      mx = fmaxf(mx, __shfl_xor(mx, 16));
      mx = fmaxf(mx, __shfl_xor(mx, 32));
      need[f] = !__all(mx <= m_q[f] + 8.f);   // wave-uniform
      float mnew;
      if (need[f]) {
        mnew = fmaxf(m_q[f], mx);
        alpha[f] = exp2f(m_q[f] - mnew);
        m_q[f] = mnew;
      } else {
        mnew = m_q[f];
        alpha[f] = 1.f;
      }
      float ssum = 0.f;
      #pragma unroll
      for (int jt = 0; jt < 4; ++jt) {
        float p0 = exp2f(sreg[f][jt][0] - mnew);
        float p1 = exp2f(sreg[f][jt][1] - mnew);
        float p2 = exp2f(sreg[f][jt][2] - mnew);
        float p3 = exp2f(sreg[f][jt][3] - mnew);
        uint2 pk2;
        pk2.x = pkh2(p0, p1);
        pk2.y = pkh2(p2, p3);
        ssum += (p0 + p1) + (p2 + p3);
        *(uint2*)&Ps[w][((f * 16 + l16) * 128 + jt * 32 + quad * 8) ^ ((l16 & 7) << 4)] = pk2;
      }
      ssum += __shfl_xor(ssum, 16);
      ssum += __shfl_xor(ssum, 32);
      l_q[f] = l_q[f] * alpha[f] + ssum;
    }
    if (need[0]) {
      #pragma unroll
      for (int dt = 0; dt < 8; ++dt)
        #pragma unroll
        for (int r = 0; r < 4; ++r) accO0[dt][r] *= alpha[0];
    }
    if (need[1]) {
      #pragma unroll
      for (int dt = 0; dt < 8; ++dt)
        #pragma unroll
        for (int r = 0; r < 4; ++r) accO1[dt][r] *= alpha[1];
    }

    // O^T = O^T + V^T P^T : vf read once, used by both fragments
    __builtin_amdgcn_s_setprio(1);
    #pragma unroll
    for (int kc = 0; kc < 2; ++kc) {
      short8 pf0 = *(const short8*)&Ps[w][(l16 * 128 + kc * 64 + quad * 16) ^ ((l16 & 7) << 4)];
      short8 pf1 = *(const short8*)&Ps[w][((16 + l16) * 128 + kc * 64 + quad * 16) ^ ((l16 & 7) << 4)];
      #pragma unroll
      for (int dt = 0; dt < 8; ++dt) {
        int vr = dt * 16 + l16;
        short8 vf = *(const short8*)&Vs[(vr * 128 + kc * 64 + quad * 16) ^ ((vr & 7) << 4)];
        accO0[dt] = __builtin_amdgcn_mfma_f32_16x16x32_f16(
            __builtin_bit_cast(half8, vf), __builtin_bit_cast(half8, pf0), accO0[dt], 0, 0, 0);
        accO1[dt] = __builtin_amdgcn_mfma_f32_16x16x32_f16(
            __builtin_bit_cast(half8, vf), __builtin_bit_cast(half8, pf1), accO1[dt], 0, 0, 0);
      }
    }
    __builtin_amdgcn_s_setprio(0);
  }

  // epilogue: float4 stores, 16B per lane
  #pragma unroll
  for (int f = 0; f < 2; ++f) {
    float invl = 1.0f / l_q[f];
    const size_t obase = (size_t)(b * SEQ + qt * 128 + w * 32 + f * 16 + l16) * DIM + h * HDIM;
    #pragma unroll
    for (int dt = 0; dt < 8; ++dt) {
      floatx4 acc = f == 0 ? accO0[dt] : accO1[dt];
      float4 ov;
      ov.x = acc[0] * invl; ov.y = acc[1] * invl;
      ov.z = acc[2] * invl; ov.w = acc[3] * invl;
      *(float4*)(o + obase + dt * 16 + quad * 4) = ov;
    }
  }
}

// ---------------- host ----------------
extern "C" void kernel_launch(void* const* d_in, const int* in_sizes, int n_in,
                              void* d_out, int out_size, void* d_ws, size_t ws_size,
                              hipStream_t stream)
{
  (void)in_sizes; (void)n_in; (void)out_size; (void)ws_size;
  const float* x = (const float*)d_in[0];
  const float* w[4]; const float* g[4]; const float* bb[4];
  for (int i = 0; i < 4; ++i) {
    w[i]  = (const float*)d_in[1 + 3 * i];
    g[i]  = (const float*)d_in[2 + 3 * i];
    bb[i] = (const float*)d_in[3 + 3 * i];
  }

  char* base = (char*)d_ws;
  size_t off = 0;
  auto alloc = [&](size_t bytes) {
    char* p = base + off;
    off += (bytes + 255) & ~(size_t)255;
    return p;
  };
  const size_t ACTH = (size_t)NROWS * DIM * 2;  // 16-bit activation buffer (16 MB)
  const size_t ACT8 = (size_t)NROWS * DIM;      // 8-bit activation buffer (8 MB)
  float* stats          = (float*)alloc(64);
  float* part1          = (float*)alloc(4 * 1024 * sizeof(float));
  float* part2          = (float*)alloc(4 * 1024 * 2 * sizeof(float));
  float* pmax           = (float*)alloc((size_t)4 * NROWS * sizeof(float));
  signed char* tern     = (signed char*)alloc((size_t)4 * WN);
  signed char* xq0      = (signed char*)alloc(ACT8);
  signed char* xq1      = (signed char*)alloc(ACT8);
  signed char* xq2      = (signed char*)alloc(ACT8);
  unsigned short* qh    = (unsigned short*)alloc(ACTH);
  unsigned short* kh    = (unsigned short*)alloc(ACTH);
  unsigned short* vtb   = (unsigned short*)alloc(ACTH);
  float* oat            = (float*)alloc((size_t)NROWS * DIM * sizeof(float));
  signed char* xqo = xq0;              // overlay: xq0 dead after the q GEMM
  unsigned* ambits = (unsigned*)(stats + 8);

  hipMemsetAsync(stats, 0, 64, stream);

  dim3 b256(256);
  w_abs_partial<<<dim3(1024, 4), b256, 0, stream>>>(w[0], w[1], w[2], w[3], part1);
  w_delta_final<<<4, b256, 0, stream>>>(part1, stats);
  w_maskquant<<<dim3(1024, 4), b256, 0, stream>>>(w[0], w[1], w[2], w[3], stats, part2, tern);
  w_alpha_final<<<4, b256, 0, stream>>>(part2, stats);

  ln_absmax3<<<NROWS / 4, b256, 0, stream>>>(x, g[0], bb[0], g[1], bb[1], g[2], bb[2], pmax);
  absmax_final<<<3, b256, 0, stream>>>(pmax, ambits);
  ln_quant3<<<NROWS / 4, b256, 0, stream>>>(x, g[0], bb[0], g[1], bb[1], g[2], bb[2], ambits,
                                            xq0, xq1, xq2);

  gemm_qkv<<<dim3(NROWS / 128, DIM / 128, 3), b256, 0, stream>>>(
      xq0, xq1, xq2, tern, qh, kh, vtb, stats);

  rope_kernel<<<NROWS * 1024 / 256, b256, 0, stream>>>(qh, kh);
  flash_attn<<<dim3(16 * 32), b256, 0, stream>>>(qh, kh, vtb, oat);

  ln_kernel<0><<<NROWS / 4, b256, 0, stream>>>(oat, g[3], bb[3], nullptr,
                                               pmax + (size_t)3 * NROWS, nullptr);
  absmax_final<<<1, b256, 0, stream>>>(pmax + (size_t)3 * NROWS, ambits + 3);
  ln_kernel<1><<<NROWS / 4, b256, 0, stream>>>(oat, g[3], bb[3], ambits + 3, nullptr, xqo);
  gemm_bt<<<dim3(NROWS / 128, DIM / 128), b256, 0, stream>>>(
      xqo, tern + (size_t)3 * WN, (float*)d_out, stats, 3);
}